// Round 2
// baseline (3177.680 us; speedup 1.0000x reference)
//
#include <hip/hip_runtime.h>

static constexpr int NB      = 16;
static constexpr int NPTS    = 4096;
static constexpr int NPOINTS = 1024;
static constexpr int NSAMP   = 32;
static constexpr int CIN0    = 67;   // 3 + 64
static constexpr int C0      = 64;
static constexpr int C1      = 64;
static constexpr int C2      = 128;
static constexpr size_t MROWS = (size_t)NB * NPOINTS * NSAMP; // 524288
#define RAD2 0.16f
#define BN_EPS 0.001f

__device__ __forceinline__ float4 uld4(const float* __restrict__ p) {
    return *(const float4* __restrict__)p;
}

// ---------------------------------------------------------------------------
// FPS: one block per batch, 1024 threads, 4 points/thread in registers.
// Non-contracted fp32 ops to match the NumPy reference bit-exactly on indices.
// ---------------------------------------------------------------------------
__global__ __launch_bounds__(1024) void fps_kernel(const float* __restrict__ xyz,
                                                   float* __restrict__ out_newxyz)
{
    __shared__ float sx[NPTS], sy[NPTS], sz[NPTS];
    __shared__ float red_v[16];
    __shared__ int   red_i[16];
    __shared__ int   sfar;

    const int b    = blockIdx.x;
    const int tid  = threadIdx.x;
    const int lane = tid & 63;
    const int wid  = tid >> 6;

    const float* base = xyz + (size_t)b * NPTS * 3;
    for (int i = tid; i < NPTS; i += 1024) {
        sx[i] = base[i * 3 + 0];
        sy[i] = base[i * 3 + 1];
        sz[i] = base[i * 3 + 2];
    }
    __syncthreads();

    float px[4], py[4], pz[4], dd[4];
#pragma unroll
    for (int j = 0; j < 4; ++j) {
        const int i = tid + j * 1024;
        px[j] = sx[i]; py[j] = sy[i]; pz[j] = sz[i];
        dd[j] = 1e10f;
    }

    int far = 0;
    for (int it = 0; it < NPOINTS; ++it) {
        const float fx = sx[far], fy = sy[far], fz = sz[far];
        if (tid == 0) {
            float* o = out_newxyz + ((size_t)b * NPOINTS + it) * 3;
            o[0] = fx; o[1] = fy; o[2] = fz;
        }
        float bv = -1.0f; int bi = 0x7fffffff;
#pragma unroll
        for (int j = 0; j < 4; ++j) {
            const float dx = __fsub_rn(px[j], fx);
            const float dy = __fsub_rn(py[j], fy);
            const float dz = __fsub_rn(pz[j], fz);
            const float d  = __fadd_rn(__fadd_rn(__fmul_rn(dx, dx), __fmul_rn(dy, dy)),
                                       __fmul_rn(dz, dz));
            dd[j] = fminf(dd[j], d);
            if (dd[j] > bv) { bv = dd[j]; bi = tid + j * 1024; }
        }
#pragma unroll
        for (int off = 32; off > 0; off >>= 1) {
            const float ov = __shfl_down(bv, (unsigned)off, 64);
            const int   oi = __shfl_down(bi, (unsigned)off, 64);
            if (ov > bv || (ov == bv && oi < bi)) { bv = ov; bi = oi; }
        }
        if (lane == 0) { red_v[wid] = bv; red_i[wid] = bi; }
        __syncthreads();
        if (wid == 0) {
            float v = (lane < 16) ? red_v[lane] : -1.0f;
            int   i = (lane < 16) ? red_i[lane] : 0x7fffffff;
#pragma unroll
            for (int off = 8; off > 0; off >>= 1) {
                const float ov = __shfl_down(v, (unsigned)off, 64);
                const int   oi = __shfl_down(i, (unsigned)off, 64);
                if (ov > v || (ov == v && oi < i)) { v = ov; i = oi; }
            }
            if (lane == 0) sfar = i;
        }
        __syncthreads();
        far = sfar;
    }
}

// ---------------------------------------------------------------------------
// Ball query: one wave per center. Ordered first-32 via ballot+prefix popcount.
// Writes float indices directly to the output buffer (read back by passes).
// ---------------------------------------------------------------------------
__global__ __launch_bounds__(256) void ball_kernel(const float* __restrict__ xyz,
                                                   const float* __restrict__ newxyz,
                                                   float* __restrict__ out_idx_f)
{
    __shared__ int sel[4][NSAMP];
    const int tid  = threadIdx.x;
    const int lane = tid & 63;
    const int widx = tid >> 6;
    const int w = blockIdx.x * 4 + widx;   // center id, 0..16383
    const int b = w >> 10;

    const float cx = newxyz[(size_t)w * 3 + 0];
    const float cy = newxyz[(size_t)w * 3 + 1];
    const float cz = newxyz[(size_t)w * 3 + 2];
    const float* base = xyz + (size_t)b * NPTS * 3;

    int total = 0;
    for (int c = 0; c < NPTS / 64 && total < NSAMP; ++c) {
        const int n = c * 64 + lane;
        const float dx = __fsub_rn(cx, base[n * 3 + 0]);
        const float dy = __fsub_rn(cy, base[n * 3 + 1]);
        const float dz = __fsub_rn(cz, base[n * 3 + 2]);
        const float d2 = __fadd_rn(__fadd_rn(__fmul_rn(dx, dx), __fmul_rn(dy, dy)),
                                   __fmul_rn(dz, dz));
        const bool pred = d2 < RAD2;
        const unsigned long long mask = __ballot(pred);
        if (pred) {
            const int pos = total + (int)__popcll(mask & ((1ull << lane) - 1ull));
            if (pos < NSAMP) sel[widx][pos] = n;
        }
        total += (int)__popcll(mask);
    }
    __syncthreads();
    if (lane < NSAMP) {
        const int first = sel[widx][0];
        const int v = (lane < total) ? sel[widx][lane] : first;
        out_idx_f[(size_t)w * NSAMP + lane] = (float)v;
    }
}

// ---------------------------------------------------------------------------
// Wave reduce of 4 (sum, sumsq) pairs into a wave's LDS stats slot.
// ---------------------------------------------------------------------------
__device__ __forceinline__ void stats4(float a0, float a1, float a2, float a3,
                                       float* sa, int lane)
{
    float q0 = a0*a0, q1 = a1*a1, q2 = a2*a2, q3 = a3*a3;
#pragma unroll
    for (int off = 32; off > 0; off >>= 1) {
        a0 += __shfl_down(a0, (unsigned)off, 64); q0 += __shfl_down(q0, (unsigned)off, 64);
        a1 += __shfl_down(a1, (unsigned)off, 64); q1 += __shfl_down(q1, (unsigned)off, 64);
        a2 += __shfl_down(a2, (unsigned)off, 64); q2 += __shfl_down(q2, (unsigned)off, 64);
        a3 += __shfl_down(a3, (unsigned)off, 64); q3 += __shfl_down(q3, (unsigned)off, 64);
    }
    if (lane == 0) {
        sa[0] += a0; sa[1] += q0; sa[2] += a1; sa[3] += q1;
        sa[4] += a2; sa[5] += q2; sa[6] += a3; sa[7] += q3;
    }
}

// ---------------------------------------------------------------------------
// Recompute pass. PHASE: 0 = stats of y0, 1 = stats of y1, 2 = stats of y2,
// 3 = final output (bn2+relu+max over samples).
// One row per thread, block 128. All W reads are lane-uniform (scalar loads).
// xld is a per-thread private LDS column (k-major), no barriers needed.
// ---------------------------------------------------------------------------
template<int PHASE>
__global__ __launch_bounds__(128) void pass_kernel(
    const float* __restrict__ xyz, const float* __restrict__ points,
    const float* __restrict__ newxyz, const float* __restrict__ idxf,
    const float* __restrict__ W0, const float* __restrict__ b0,
    const float* __restrict__ W1, const float* __restrict__ b1,
    const float* __restrict__ W2, const float* __restrict__ b2,
    const float* __restrict__ ss0, const float* __restrict__ ss1,
    const float* __restrict__ ss2,
    float* __restrict__ gstats, float* __restrict__ out_np)
{
    constexpr int CS = (PHASE == 2) ? C2 : C0;
    __shared__ float xld[(PHASE >= 1) ? (64 * 128) : 1];
    __shared__ float sacc[2][2 * CS];

    const int tid  = threadIdx.x;
    const int lane = tid & 63;
    const int wv   = tid >> 6;

    if constexpr (PHASE <= 2) {
        for (int j = tid; j < 2 * 2 * CS; j += 128) (&sacc[0][0])[j] = 0.f;
        __syncthreads();
    }

    const int r  = blockIdx.x * 128 + tid;
    const int i  = (int)idxf[r];
    const int bb = r >> 15;
    const int pp = (r >> 5) & 1023;

    // gather input row x[67] = (xyz[b,i]-newxyz[b,p] | points[b,i])
    float x[CIN0];
    {
        const float* pz = xyz + ((size_t)bb * NPTS + i) * 3;
        const float* nz = newxyz + ((size_t)bb * NPOINTS + pp) * 3;
        x[0] = pz[0] - nz[0];
        x[1] = pz[1] - nz[1];
        x[2] = pz[2] - nz[2];
        const float4* p4 = (const float4*)(points + ((size_t)bb * NPTS + i) * 64);
#pragma unroll
        for (int j = 0; j < 16; ++j) {
            const float4 v = p4[j];
            x[3+4*j+0] = v.x; x[3+4*j+1] = v.y; x[3+4*j+2] = v.z; x[3+4*j+3] = v.w;
        }
    }

    // ---- layer 0 ----
#pragma unroll 1
    for (int oc = 0; oc < 16; ++oc) {
        const float4 bv = uld4(b0 + 4*oc);
        float a0 = bv.x, a1 = bv.y, a2 = bv.z, a3 = bv.w;
#pragma unroll
        for (int k = 0; k < CIN0; ++k) {
            const float4 w4 = uld4(W0 + k*64 + 4*oc);
            a0 = fmaf(x[k], w4.x, a0); a1 = fmaf(x[k], w4.y, a1);
            a2 = fmaf(x[k], w4.z, a2); a3 = fmaf(x[k], w4.w, a3);
        }
        if constexpr (PHASE == 0) {
            stats4(a0, a1, a2, a3, &sacc[wv][8*oc], lane);
        } else {
            const float s0 = ss0[4*oc+0], s1 = ss0[4*oc+1], s2 = ss0[4*oc+2], s3 = ss0[4*oc+3];
            const float h0 = ss0[64+4*oc+0], h1 = ss0[64+4*oc+1], h2 = ss0[64+4*oc+2], h3 = ss0[64+4*oc+3];
            xld[(4*oc+0)*128 + tid] = fmaxf(0.f, fmaf(a0, s0, h0));
            xld[(4*oc+1)*128 + tid] = fmaxf(0.f, fmaf(a1, s1, h1));
            xld[(4*oc+2)*128 + tid] = fmaxf(0.f, fmaf(a2, s2, h2));
            xld[(4*oc+3)*128 + tid] = fmaxf(0.f, fmaf(a3, s3, h3));
        }
    }

    // ---- layer 1 (stats only) ----
    if constexpr (PHASE == 1) {
#pragma unroll 1
        for (int oc = 0; oc < 16; ++oc) {
            const float4 bv = uld4(b1 + 4*oc);
            float a0 = bv.x, a1 = bv.y, a2 = bv.z, a3 = bv.w;
#pragma unroll
            for (int k = 0; k < 64; ++k) {
                const float xk = xld[k*128 + tid];
                const float4 w4 = uld4(W1 + k*64 + 4*oc);
                a0 = fmaf(xk, w4.x, a0); a1 = fmaf(xk, w4.y, a1);
                a2 = fmaf(xk, w4.z, a2); a3 = fmaf(xk, w4.w, a3);
            }
            stats4(a0, a1, a2, a3, &sacc[wv][8*oc], lane);
        }
    }

    // ---- layers 1+2 fused ----
    if constexpr (PHASE >= 2) {
        float acc2[C2];
#pragma unroll
        for (int o = 0; o < C2; o += 4) {
            const float4 bv = uld4(b2 + o);
            acc2[o] = bv.x; acc2[o+1] = bv.y; acc2[o+2] = bv.z; acc2[o+3] = bv.w;
        }
#pragma unroll 1
        for (int oc = 0; oc < 16; ++oc) {
            const float4 bv = uld4(b1 + 4*oc);
            float a0 = bv.x, a1 = bv.y, a2 = bv.z, a3 = bv.w;
#pragma unroll
            for (int k = 0; k < 64; ++k) {
                const float xk = xld[k*128 + tid];
                const float4 w4 = uld4(W1 + k*64 + 4*oc);
                a0 = fmaf(xk, w4.x, a0); a1 = fmaf(xk, w4.y, a1);
                a2 = fmaf(xk, w4.z, a2); a3 = fmaf(xk, w4.w, a3);
            }
            const float xc0 = fmaxf(0.f, fmaf(a0, ss1[4*oc+0], ss1[64+4*oc+0]));
            const float xc1 = fmaxf(0.f, fmaf(a1, ss1[4*oc+1], ss1[64+4*oc+1]));
            const float xc2 = fmaxf(0.f, fmaf(a2, ss1[4*oc+2], ss1[64+4*oc+2]));
            const float xc3 = fmaxf(0.f, fmaf(a3, ss1[4*oc+3], ss1[64+4*oc+3]));
#pragma unroll
            for (int o = 0; o < C2; o += 4) {
                const float4 wA = uld4(W2 + (4*oc+0)*C2 + o);
                const float4 wB = uld4(W2 + (4*oc+1)*C2 + o);
                const float4 wC = uld4(W2 + (4*oc+2)*C2 + o);
                const float4 wD = uld4(W2 + (4*oc+3)*C2 + o);
                acc2[o+0] = fmaf(xc0, wA.x, fmaf(xc1, wB.x, fmaf(xc2, wC.x, fmaf(xc3, wD.x, acc2[o+0]))));
                acc2[o+1] = fmaf(xc0, wA.y, fmaf(xc1, wB.y, fmaf(xc2, wC.y, fmaf(xc3, wD.y, acc2[o+1]))));
                acc2[o+2] = fmaf(xc0, wA.z, fmaf(xc1, wB.z, fmaf(xc2, wC.z, fmaf(xc3, wD.z, acc2[o+2]))));
                acc2[o+3] = fmaf(xc0, wA.w, fmaf(xc1, wB.w, fmaf(xc2, wC.w, fmaf(xc3, wD.w, acc2[o+3]))));
            }
        }

        if constexpr (PHASE == 2) {
#pragma unroll
            for (int o = 0; o < C2; ++o) {
                float s = acc2[o];
                float q = s * s;
#pragma unroll
                for (int off = 32; off > 0; off >>= 1) {
                    s += __shfl_down(s, (unsigned)off, 64);
                    q += __shfl_down(q, (unsigned)off, 64);
                }
                if (lane == 0) { sacc[wv][2*o] += s; sacc[wv][2*o+1] += q; }
            }
        } else {
            const int g = r >> 5;
#pragma unroll
            for (int o = 0; o < C2; ++o) {
                float v = fmaxf(0.f, fmaf(acc2[o], ss2[o], ss2[C2+o]));
#pragma unroll
                for (int off = 16; off > 0; off >>= 1)
                    v = fmaxf(v, __shfl_down(v, (unsigned)off, 32));
                if ((tid & 31) == 0) out_np[(size_t)g * C2 + o] = v;
            }
        }
    }

    if constexpr (PHASE <= 2) {
        __syncthreads();
        for (int j = tid; j < 2 * CS; j += 128)
            atomicAdd(&gstats[j], sacc[0][j] + sacc[1][j]);
    }
}

// ---------------------------------------------------------------------------
// BN scale/shift from raw sums.
// ---------------------------------------------------------------------------
template<int C>
__global__ void ss_kernel(const float* __restrict__ gs, const float* __restrict__ g,
                          const float* __restrict__ be, float* __restrict__ ss)
{
    const int o = threadIdx.x;
    const float inv  = 1.0f / (float)MROWS;
    const float mean = gs[2*o] * inv;
    const float var  = fmaxf(0.f, gs[2*o+1] * inv - mean * mean);
    const float sc   = g[o] / sqrtf(var + BN_EPS);
    ss[o]     = sc;
    ss[C + o] = fmaf(-mean, sc, be[o]);
}

__global__ void zero_kernel(float* __restrict__ p) { p[threadIdx.x] = 0.f; }

extern "C" void kernel_launch(void* const* d_in, const int* in_sizes, int n_in,
                              void* d_out, int out_size, void* d_ws, size_t ws_size,
                              hipStream_t stream)
{
    (void)in_sizes; (void)n_in; (void)out_size; (void)ws_size;
    const float* xyz    = (const float*)d_in[0];
    const float* points = (const float*)d_in[1];
    const float* W0  = (const float*)d_in[2];
    const float* b0  = (const float*)d_in[3];
    const float* g0  = (const float*)d_in[4];
    const float* be0 = (const float*)d_in[5];
    const float* W1  = (const float*)d_in[6];
    const float* b1  = (const float*)d_in[7];
    const float* g1  = (const float*)d_in[8];
    const float* be1 = (const float*)d_in[9];
    const float* W2  = (const float*)d_in[10];
    const float* b2  = (const float*)d_in[11];
    const float* g2  = (const float*)d_in[12];
    const float* be2 = (const float*)d_in[13];

    float* out = (float*)d_out;
    float* out_newxyz = out;                                    // 16*1024*3
    float* out_newpts = out + (size_t)NB * NPOINTS * 3;         // 16*1024*128
    float* out_idx    = out_newpts + (size_t)NB * NPOINTS * C2; // 16*1024*32 (float idx)

    // workspace: < 8 KB total
    float* wsf = (float*)d_ws;
    float* gs0 = wsf + 0;    // 128
    float* gs1 = wsf + 128;  // 128
    float* gs2 = wsf + 256;  // 256
    float* ss0 = wsf + 512;  // 128
    float* ss1 = wsf + 640;  // 128
    float* ss2 = wsf + 768;  // 256

    zero_kernel<<<1, 512, 0, stream>>>(wsf);
    fps_kernel<<<NB, 1024, 0, stream>>>(xyz, out_newxyz);
    ball_kernel<<<(NB * NPOINTS) / 4, 256, 0, stream>>>(xyz, out_newxyz, out_idx);

    const int grid = (int)(MROWS / 128);  // 4096

    pass_kernel<0><<<grid, 128, 0, stream>>>(xyz, points, out_newxyz, out_idx,
                                             W0, b0, W1, b1, W2, b2,
                                             ss0, ss1, ss2, gs0, nullptr);
    ss_kernel<C0><<<1, C0, 0, stream>>>(gs0, g0, be0, ss0);

    pass_kernel<1><<<grid, 128, 0, stream>>>(xyz, points, out_newxyz, out_idx,
                                             W0, b0, W1, b1, W2, b2,
                                             ss0, ss1, ss2, gs1, nullptr);
    ss_kernel<C1><<<1, C1, 0, stream>>>(gs1, g1, be1, ss1);

    pass_kernel<2><<<grid, 128, 0, stream>>>(xyz, points, out_newxyz, out_idx,
                                             W0, b0, W1, b1, W2, b2,
                                             ss0, ss1, ss2, gs2, nullptr);
    ss_kernel<C2><<<1, C2, 0, stream>>>(gs2, g2, be2, ss2);

    pass_kernel<3><<<grid, 128, 0, stream>>>(xyz, points, out_newxyz, out_idx,
                                             W0, b0, W1, b1, W2, b2,
                                             ss0, ss1, ss2, nullptr, out_newpts);
}

// Round 3
// 2347.231 us; speedup vs baseline: 1.3538x; 1.3538x over previous
//
#include <hip/hip_runtime.h>

static constexpr int NB      = 16;
static constexpr int NPTS    = 4096;
static constexpr int NPOINTS = 1024;
static constexpr int NSAMP   = 32;
static constexpr int CIN0    = 67;   // 3 + 64
static constexpr int C0      = 64;
static constexpr int C1      = 64;
static constexpr int C2      = 128;
static constexpr size_t MROWS = (size_t)NB * NPOINTS * NSAMP; // 524288
#define RAD2 0.16f
#define BN_EPS 0.001f

__device__ __forceinline__ float4 uld4(const float* __restrict__ p) {
    return *(const float4* __restrict__)p;
}

// ---------------------------------------------------------------------------
// FPS v2: one block of 256 threads per batch, 16 points/thread in registers.
// One barrier per iteration: per-wave shuffle argmax -> lane0 writes slot ->
// barrier -> ALL threads redundantly reduce the 4 slots (identical result),
// double-buffered slots remove the second barrier.
// Non-contracted fp32 ops to match the NumPy reference bit-exactly on indices.
// ---------------------------------------------------------------------------
__global__ __launch_bounds__(256) void fps_kernel(const float* __restrict__ xyz,
                                                  float* __restrict__ out_newxyz)
{
    __shared__ float sx[NPTS], sy[NPTS], sz[NPTS];
    __shared__ float redv[2][4];
    __shared__ int   redi[2][4];

    const int b    = blockIdx.x;
    const int tid  = threadIdx.x;
    const int lane = tid & 63;
    const int wv   = tid >> 6;

    const float* base = xyz + (size_t)b * NPTS * 3;
    for (int i = tid; i < NPTS; i += 256) {
        sx[i] = base[i * 3 + 0];
        sy[i] = base[i * 3 + 1];
        sz[i] = base[i * 3 + 2];
    }
    __syncthreads();

    float px[16], py[16], pz[16], dd[16];
#pragma unroll
    for (int j = 0; j < 16; ++j) {
        const int i = tid + j * 256;
        px[j] = sx[i]; py[j] = sy[i]; pz[j] = sz[i];
        dd[j] = 1e10f;
    }

    float fx = sx[0], fy = sy[0], fz = sz[0];
#pragma unroll 1
    for (int it = 0; it < NPOINTS; ++it) {
        if (tid == 0) {
            float* o = out_newxyz + ((size_t)b * NPOINTS + it) * 3;
            o[0] = fx; o[1] = fy; o[2] = fz;
        }
        float bv = -1.0f; int bi = 0;
#pragma unroll
        for (int j = 0; j < 16; ++j) {
            const float dx = __fsub_rn(px[j], fx);
            const float dy = __fsub_rn(py[j], fy);
            const float dz = __fsub_rn(pz[j], fz);
            const float d  = __fadd_rn(__fadd_rn(__fmul_rn(dx, dx), __fmul_rn(dy, dy)),
                                       __fmul_rn(dz, dz));
            dd[j] = fminf(dd[j], d);
            if (dd[j] > bv) { bv = dd[j]; bi = tid + j * 256; } // j asc => idx asc
        }
        // wave argmax, smallest-index tie-break
#pragma unroll
        for (int off = 32; off > 0; off >>= 1) {
            const float ov = __shfl_down(bv, (unsigned)off, 64);
            const int   oi = __shfl_down(bi, (unsigned)off, 64);
            if (ov > bv || (ov == bv && oi < bi)) { bv = ov; bi = oi; }
        }
        const int pb = it & 1;
        if (lane == 0) { redv[pb][wv] = bv; redi[pb][wv] = bi; }
        __syncthreads();
        // all threads redundantly reduce 4 slots -> identical winner
        float cv = redv[pb][0]; int ci = redi[pb][0];
#pragma unroll
        for (int w = 1; w < 4; ++w) {
            const float ov = redv[pb][w]; const int oi = redi[pb][w];
            if (ov > cv || (ov == cv && oi < ci)) { cv = ov; ci = oi; }
        }
        fx = sx[ci]; fy = sy[ci]; fz = sz[ci];
    }
}

// ---------------------------------------------------------------------------
// Ball query: one wave per center. Ordered first-32 via ballot+prefix popcount.
// ---------------------------------------------------------------------------
__global__ __launch_bounds__(256) void ball_kernel(const float* __restrict__ xyz,
                                                   const float* __restrict__ newxyz,
                                                   float* __restrict__ out_idx_f)
{
    __shared__ int sel[4][NSAMP];
    const int tid  = threadIdx.x;
    const int lane = tid & 63;
    const int widx = tid >> 6;
    const int w = blockIdx.x * 4 + widx;   // center id, 0..16383
    const int b = w >> 10;

    const float cx = newxyz[(size_t)w * 3 + 0];
    const float cy = newxyz[(size_t)w * 3 + 1];
    const float cz = newxyz[(size_t)w * 3 + 2];
    const float* base = xyz + (size_t)b * NPTS * 3;

    int total = 0;
    for (int c = 0; c < NPTS / 64 && total < NSAMP; ++c) {
        const int n = c * 64 + lane;
        const float dx = __fsub_rn(cx, base[n * 3 + 0]);
        const float dy = __fsub_rn(cy, base[n * 3 + 1]);
        const float dz = __fsub_rn(cz, base[n * 3 + 2]);
        const float d2 = __fadd_rn(__fadd_rn(__fmul_rn(dx, dx), __fmul_rn(dy, dy)),
                                   __fmul_rn(dz, dz));
        const bool pred = d2 < RAD2;
        const unsigned long long mask = __ballot(pred);
        if (pred) {
            const int pos = total + (int)__popcll(mask & ((1ull << lane) - 1ull));
            if (pos < NSAMP) sel[widx][pos] = n;
        }
        total += (int)__popcll(mask);
    }
    __syncthreads();
    if (lane < NSAMP) {
        const int first = sel[widx][0];
        const int v = (lane < total) ? sel[widx][lane] : first;
        out_idx_f[(size_t)w * NSAMP + lane] = (float)v;
    }
}

// ---------------------------------------------------------------------------
// Wave reduce of 4 (sum, sumsq) pairs into a wave's LDS stats slot.
// ---------------------------------------------------------------------------
__device__ __forceinline__ void stats4(float a0, float a1, float a2, float a3,
                                       float* sa, int lane)
{
    float q0 = a0*a0, q1 = a1*a1, q2 = a2*a2, q3 = a3*a3;
#pragma unroll
    for (int off = 32; off > 0; off >>= 1) {
        a0 += __shfl_down(a0, (unsigned)off, 64); q0 += __shfl_down(q0, (unsigned)off, 64);
        a1 += __shfl_down(a1, (unsigned)off, 64); q1 += __shfl_down(q1, (unsigned)off, 64);
        a2 += __shfl_down(a2, (unsigned)off, 64); q2 += __shfl_down(q2, (unsigned)off, 64);
        a3 += __shfl_down(a3, (unsigned)off, 64); q3 += __shfl_down(q3, (unsigned)off, 64);
    }
    if (lane == 0) {
        sa[0] += a0; sa[1] += q0; sa[2] += a1; sa[3] += q1;
        sa[4] += a2; sa[5] += q2; sa[6] += a3; sa[7] += q3;
    }
}

// ---------------------------------------------------------------------------
// P precompute: P[b,n,:] = points[b,n,:] . W0[3:,:]  (layer-0 dedup).
// One row per thread; W0 reads lane-uniform (scalar loads).
// ---------------------------------------------------------------------------
__global__ __launch_bounds__(256) void preP_kernel(const float* __restrict__ points,
                                                   const float* __restrict__ W0,
                                                   float* __restrict__ P)
{
    const int r = blockIdx.x * 256 + threadIdx.x;   // 0..65535
    const float4* pr = (const float4*)(points + (size_t)r * 64);
    float x[64];
#pragma unroll
    for (int j = 0; j < 16; ++j) {
        const float4 v = pr[j];
        x[4*j+0] = v.x; x[4*j+1] = v.y; x[4*j+2] = v.z; x[4*j+3] = v.w;
    }
    float acc[64];
#pragma unroll
    for (int o = 0; o < 64; ++o) acc[o] = 0.f;
#pragma unroll 2
    for (int k = 0; k < 64; ++k) {
        const float xk = x[k];
#pragma unroll
        for (int oc = 0; oc < 16; ++oc) {
            const float4 w4 = uld4(W0 + (3 + k) * 64 + 4 * oc);
            acc[4*oc+0] = fmaf(xk, w4.x, acc[4*oc+0]);
            acc[4*oc+1] = fmaf(xk, w4.y, acc[4*oc+1]);
            acc[4*oc+2] = fmaf(xk, w4.z, acc[4*oc+2]);
            acc[4*oc+3] = fmaf(xk, w4.w, acc[4*oc+3]);
        }
    }
    float4* po = (float4*)(P + (size_t)r * 64);
#pragma unroll
    for (int oc = 0; oc < 16; ++oc)
        po[oc] = make_float4(acc[4*oc+0], acc[4*oc+1], acc[4*oc+2], acc[4*oc+3]);
}

// ---------------------------------------------------------------------------
// P-path pass. PHASE: 0 = stats y0, 1 = stats y1, 2 = stats y2, 3 = output.
// Layer0 is 3 FMAs + P[i] add per channel. Activations register-resident.
// ---------------------------------------------------------------------------
template<int PHASE>
__global__ __launch_bounds__(128, 2) void passP_kernel(
    const float* __restrict__ xyz, const float* __restrict__ P,
    const float* __restrict__ newxyz, const float* __restrict__ idxf,
    const float* __restrict__ W0, const float* __restrict__ b0,
    const float* __restrict__ W1, const float* __restrict__ b1,
    const float* __restrict__ W2, const float* __restrict__ b2,
    const float* __restrict__ ss0, const float* __restrict__ ss1,
    const float* __restrict__ ss2,
    float* __restrict__ gstats, float* __restrict__ out_np)
{
    constexpr int CS = (PHASE == 2) ? C2 : C0;
    __shared__ float sacc[2][2 * CS];

    const int tid  = threadIdx.x;
    const int lane = tid & 63;
    const int wv   = tid >> 6;

    if constexpr (PHASE <= 2) {
        for (int j = tid; j < 4 * CS; j += 128) (&sacc[0][0])[j] = 0.f;
        __syncthreads();
    }

    const int r  = blockIdx.x * 128 + tid;
    const int i  = (int)idxf[r];
    const int bb = r >> 15;
    const int pp = (r >> 5) & 1023;

    const float* pz = xyz + ((size_t)bb * NPTS + i) * 3;
    const float* nz = newxyz + ((size_t)bb * NPOINTS + pp) * 3;
    const float r0 = pz[0] - nz[0];
    const float r1 = pz[1] - nz[1];
    const float r2 = pz[2] - nz[2];
    const float4* prow = (const float4*)(P + ((size_t)bb * NPTS + i) * 64);

    // ---- layer 0 (deduped): y0 = b0 + rel.W0[0:3] + P[i] ----
    float x1[C0];
#pragma unroll
    for (int oc = 0; oc < 16; ++oc) {
        const float4 pv = prow[oc];
        const float4 bv = uld4(b0 + 4 * oc);
        const float4 wa = uld4(W0 + 0 * 64 + 4 * oc);
        const float4 wb = uld4(W0 + 1 * 64 + 4 * oc);
        const float4 wc = uld4(W0 + 2 * 64 + 4 * oc);
        x1[4*oc+0] = fmaf(r0, wa.x, fmaf(r1, wb.x, fmaf(r2, wc.x, bv.x + pv.x)));
        x1[4*oc+1] = fmaf(r0, wa.y, fmaf(r1, wb.y, fmaf(r2, wc.y, bv.y + pv.y)));
        x1[4*oc+2] = fmaf(r0, wa.z, fmaf(r1, wb.z, fmaf(r2, wc.z, bv.z + pv.z)));
        x1[4*oc+3] = fmaf(r0, wa.w, fmaf(r1, wb.w, fmaf(r2, wc.w, bv.w + pv.w)));
    }

    if constexpr (PHASE == 0) {
#pragma unroll
        for (int oc = 0; oc < 16; ++oc)
            stats4(x1[4*oc+0], x1[4*oc+1], x1[4*oc+2], x1[4*oc+3], &sacc[wv][8*oc], lane);
    } else {
        // bn0 + relu
#pragma unroll
        for (int o = 0; o < C0; ++o)
            x1[o] = fmaxf(0.f, fmaf(x1[o], ss0[o], ss0[64 + o]));

        // ---- layer 1 ----
        float y1[C1];
#pragma unroll
        for (int o = 0; o < C1; o += 4) {
            const float4 bv = uld4(b1 + o);
            y1[o] = bv.x; y1[o+1] = bv.y; y1[o+2] = bv.z; y1[o+3] = bv.w;
        }
#pragma unroll 2
        for (int k = 0; k < C0; ++k) {
            const float xk = x1[k];
#pragma unroll
            for (int oc = 0; oc < 16; ++oc) {
                const float4 w4 = uld4(W1 + k * 64 + 4 * oc);
                y1[4*oc+0] = fmaf(xk, w4.x, y1[4*oc+0]);
                y1[4*oc+1] = fmaf(xk, w4.y, y1[4*oc+1]);
                y1[4*oc+2] = fmaf(xk, w4.z, y1[4*oc+2]);
                y1[4*oc+3] = fmaf(xk, w4.w, y1[4*oc+3]);
            }
        }

        if constexpr (PHASE == 1) {
#pragma unroll
            for (int oc = 0; oc < 16; ++oc)
                stats4(y1[4*oc+0], y1[4*oc+1], y1[4*oc+2], y1[4*oc+3], &sacc[wv][8*oc], lane);
        } else {
            // bn1 + relu
#pragma unroll
            for (int o = 0; o < C1; ++o)
                y1[o] = fmaxf(0.f, fmaf(y1[o], ss1[o], ss1[64 + o]));

            // ---- layer 2 ----
            float a2[C2];
#pragma unroll
            for (int o = 0; o < C2; o += 4) {
                const float4 bv = uld4(b2 + o);
                a2[o] = bv.x; a2[o+1] = bv.y; a2[o+2] = bv.z; a2[o+3] = bv.w;
            }
#pragma unroll 2
            for (int k = 0; k < C1; ++k) {
                const float xk = y1[k];
#pragma unroll
                for (int o = 0; o < C2; o += 4) {
                    const float4 w4 = uld4(W2 + k * C2 + o);
                    a2[o+0] = fmaf(xk, w4.x, a2[o+0]);
                    a2[o+1] = fmaf(xk, w4.y, a2[o+1]);
                    a2[o+2] = fmaf(xk, w4.z, a2[o+2]);
                    a2[o+3] = fmaf(xk, w4.w, a2[o+3]);
                }
            }

            if constexpr (PHASE == 2) {
#pragma unroll
                for (int o = 0; o < C2; ++o) {
                    float s = a2[o];
                    float q = s * s;
#pragma unroll
                    for (int off = 32; off > 0; off >>= 1) {
                        s += __shfl_down(s, (unsigned)off, 64);
                        q += __shfl_down(q, (unsigned)off, 64);
                    }
                    if (lane == 0) { sacc[wv][2*o] += s; sacc[wv][2*o+1] += q; }
                }
            } else {
                const int g = r >> 5;
#pragma unroll
                for (int o = 0; o < C2; ++o) {
                    float v = fmaxf(0.f, fmaf(a2[o], ss2[o], ss2[C2 + o]));
#pragma unroll
                    for (int off = 16; off > 0; off >>= 1)
                        v = fmaxf(v, __shfl_down(v, (unsigned)off, 32));
                    if ((tid & 31) == 0) out_np[(size_t)g * C2 + o] = v;
                }
            }
        }
    }

    if constexpr (PHASE <= 2) {
        __syncthreads();
        for (int j = tid; j < 2 * CS; j += 128)
            atomicAdd(&gstats[j], sacc[0][j] + sacc[1][j]);
    }
}

// ---------------------------------------------------------------------------
// Fallback recompute pass (round-2 proven): used when ws_size < 16 MB.
// ---------------------------------------------------------------------------
template<int PHASE>
__global__ __launch_bounds__(128) void pass_kernel(
    const float* __restrict__ xyz, const float* __restrict__ points,
    const float* __restrict__ newxyz, const float* __restrict__ idxf,
    const float* __restrict__ W0, const float* __restrict__ b0,
    const float* __restrict__ W1, const float* __restrict__ b1,
    const float* __restrict__ W2, const float* __restrict__ b2,
    const float* __restrict__ ss0, const float* __restrict__ ss1,
    const float* __restrict__ ss2,
    float* __restrict__ gstats, float* __restrict__ out_np)
{
    constexpr int CS = (PHASE == 2) ? C2 : C0;
    __shared__ float xld[(PHASE >= 1) ? (64 * 128) : 1];
    __shared__ float sacc[2][2 * CS];

    const int tid  = threadIdx.x;
    const int lane = tid & 63;
    const int wv   = tid >> 6;

    if constexpr (PHASE <= 2) {
        for (int j = tid; j < 2 * 2 * CS; j += 128) (&sacc[0][0])[j] = 0.f;
        __syncthreads();
    }

    const int r  = blockIdx.x * 128 + tid;
    const int i  = (int)idxf[r];
    const int bb = r >> 15;
    const int pp = (r >> 5) & 1023;

    float x[CIN0];
    {
        const float* pz = xyz + ((size_t)bb * NPTS + i) * 3;
        const float* nz = newxyz + ((size_t)bb * NPOINTS + pp) * 3;
        x[0] = pz[0] - nz[0];
        x[1] = pz[1] - nz[1];
        x[2] = pz[2] - nz[2];
        const float4* p4 = (const float4*)(points + ((size_t)bb * NPTS + i) * 64);
#pragma unroll
        for (int j = 0; j < 16; ++j) {
            const float4 v = p4[j];
            x[3+4*j+0] = v.x; x[3+4*j+1] = v.y; x[3+4*j+2] = v.z; x[3+4*j+3] = v.w;
        }
    }

#pragma unroll 1
    for (int oc = 0; oc < 16; ++oc) {
        const float4 bv = uld4(b0 + 4*oc);
        float a0 = bv.x, a1 = bv.y, a2 = bv.z, a3 = bv.w;
#pragma unroll
        for (int k = 0; k < CIN0; ++k) {
            const float4 w4 = uld4(W0 + k*64 + 4*oc);
            a0 = fmaf(x[k], w4.x, a0); a1 = fmaf(x[k], w4.y, a1);
            a2 = fmaf(x[k], w4.z, a2); a3 = fmaf(x[k], w4.w, a3);
        }
        if constexpr (PHASE == 0) {
            stats4(a0, a1, a2, a3, &sacc[wv][8*oc], lane);
        } else {
            xld[(4*oc+0)*128 + tid] = fmaxf(0.f, fmaf(a0, ss0[4*oc+0], ss0[64+4*oc+0]));
            xld[(4*oc+1)*128 + tid] = fmaxf(0.f, fmaf(a1, ss0[4*oc+1], ss0[64+4*oc+1]));
            xld[(4*oc+2)*128 + tid] = fmaxf(0.f, fmaf(a2, ss0[4*oc+2], ss0[64+4*oc+2]));
            xld[(4*oc+3)*128 + tid] = fmaxf(0.f, fmaf(a3, ss0[4*oc+3], ss0[64+4*oc+3]));
        }
    }

    if constexpr (PHASE == 1) {
#pragma unroll 1
        for (int oc = 0; oc < 16; ++oc) {
            const float4 bv = uld4(b1 + 4*oc);
            float a0 = bv.x, a1 = bv.y, a2 = bv.z, a3 = bv.w;
#pragma unroll
            for (int k = 0; k < 64; ++k) {
                const float xk = xld[k*128 + tid];
                const float4 w4 = uld4(W1 + k*64 + 4*oc);
                a0 = fmaf(xk, w4.x, a0); a1 = fmaf(xk, w4.y, a1);
                a2 = fmaf(xk, w4.z, a2); a3 = fmaf(xk, w4.w, a3);
            }
            stats4(a0, a1, a2, a3, &sacc[wv][8*oc], lane);
        }
    }

    if constexpr (PHASE >= 2) {
        float acc2[C2];
#pragma unroll
        for (int o = 0; o < C2; o += 4) {
            const float4 bv = uld4(b2 + o);
            acc2[o] = bv.x; acc2[o+1] = bv.y; acc2[o+2] = bv.z; acc2[o+3] = bv.w;
        }
#pragma unroll 1
        for (int oc = 0; oc < 16; ++oc) {
            const float4 bv = uld4(b1 + 4*oc);
            float a0 = bv.x, a1 = bv.y, a2 = bv.z, a3 = bv.w;
#pragma unroll
            for (int k = 0; k < 64; ++k) {
                const float xk = xld[k*128 + tid];
                const float4 w4 = uld4(W1 + k*64 + 4*oc);
                a0 = fmaf(xk, w4.x, a0); a1 = fmaf(xk, w4.y, a1);
                a2 = fmaf(xk, w4.z, a2); a3 = fmaf(xk, w4.w, a3);
            }
            const float xc0 = fmaxf(0.f, fmaf(a0, ss1[4*oc+0], ss1[64+4*oc+0]));
            const float xc1 = fmaxf(0.f, fmaf(a1, ss1[4*oc+1], ss1[64+4*oc+1]));
            const float xc2 = fmaxf(0.f, fmaf(a2, ss1[4*oc+2], ss1[64+4*oc+2]));
            const float xc3 = fmaxf(0.f, fmaf(a3, ss1[4*oc+3], ss1[64+4*oc+3]));
#pragma unroll
            for (int o = 0; o < C2; o += 4) {
                const float4 wA = uld4(W2 + (4*oc+0)*C2 + o);
                const float4 wB = uld4(W2 + (4*oc+1)*C2 + o);
                const float4 wC = uld4(W2 + (4*oc+2)*C2 + o);
                const float4 wD = uld4(W2 + (4*oc+3)*C2 + o);
                acc2[o+0] = fmaf(xc0, wA.x, fmaf(xc1, wB.x, fmaf(xc2, wC.x, fmaf(xc3, wD.x, acc2[o+0]))));
                acc2[o+1] = fmaf(xc0, wA.y, fmaf(xc1, wB.y, fmaf(xc2, wC.y, fmaf(xc3, wD.y, acc2[o+1]))));
                acc2[o+2] = fmaf(xc0, wA.z, fmaf(xc1, wB.z, fmaf(xc2, wC.z, fmaf(xc3, wD.z, acc2[o+2]))));
                acc2[o+3] = fmaf(xc0, wA.w, fmaf(xc1, wB.w, fmaf(xc2, wC.w, fmaf(xc3, wD.w, acc2[o+3]))));
            }
        }

        if constexpr (PHASE == 2) {
#pragma unroll
            for (int o = 0; o < C2; ++o) {
                float s = acc2[o];
                float q = s * s;
#pragma unroll
                for (int off = 32; off > 0; off >>= 1) {
                    s += __shfl_down(s, (unsigned)off, 64);
                    q += __shfl_down(q, (unsigned)off, 64);
                }
                if (lane == 0) { sacc[wv][2*o] += s; sacc[wv][2*o+1] += q; }
            }
        } else {
            const int g = r >> 5;
#pragma unroll
            for (int o = 0; o < C2; ++o) {
                float v = fmaxf(0.f, fmaf(acc2[o], ss2[o], ss2[C2+o]));
#pragma unroll
                for (int off = 16; off > 0; off >>= 1)
                    v = fmaxf(v, __shfl_down(v, (unsigned)off, 32));
                if ((tid & 31) == 0) out_np[(size_t)g * C2 + o] = v;
            }
        }
    }

    if constexpr (PHASE <= 2) {
        __syncthreads();
        for (int j = tid; j < 2 * CS; j += 128)
            atomicAdd(&gstats[j], sacc[0][j] + sacc[1][j]);
    }
}

// ---------------------------------------------------------------------------
// BN scale/shift from raw sums.
// ---------------------------------------------------------------------------
template<int C>
__global__ void ss_kernel(const float* __restrict__ gs, const float* __restrict__ g,
                          const float* __restrict__ be, float* __restrict__ ss)
{
    const int o = threadIdx.x;
    const float inv  = 1.0f / (float)MROWS;
    const float mean = gs[2*o] * inv;
    const float var  = fmaxf(0.f, gs[2*o+1] * inv - mean * mean);
    const float sc   = g[o] / sqrtf(var + BN_EPS);
    ss[o]     = sc;
    ss[C + o] = fmaf(-mean, sc, be[o]);
}

__global__ void zero_kernel(float* __restrict__ p) { p[threadIdx.x] = 0.f; }

extern "C" void kernel_launch(void* const* d_in, const int* in_sizes, int n_in,
                              void* d_out, int out_size, void* d_ws, size_t ws_size,
                              hipStream_t stream)
{
    (void)in_sizes; (void)n_in; (void)out_size;
    const float* xyz    = (const float*)d_in[0];
    const float* points = (const float*)d_in[1];
    const float* W0  = (const float*)d_in[2];
    const float* b0  = (const float*)d_in[3];
    const float* g0  = (const float*)d_in[4];
    const float* be0 = (const float*)d_in[5];
    const float* W1  = (const float*)d_in[6];
    const float* b1  = (const float*)d_in[7];
    const float* g1  = (const float*)d_in[8];
    const float* be1 = (const float*)d_in[9];
    const float* W2  = (const float*)d_in[10];
    const float* b2  = (const float*)d_in[11];
    const float* g2  = (const float*)d_in[12];
    const float* be2 = (const float*)d_in[13];

    float* out = (float*)d_out;
    float* out_newxyz = out;                                    // 16*1024*3
    float* out_newpts = out + (size_t)NB * NPOINTS * 3;         // 16*1024*128
    float* out_idx    = out_newpts + (size_t)NB * NPOINTS * C2; // 16*1024*32 (float idx)

    float* wsf = (float*)d_ws;
    float* gs0 = wsf + 0;    // 128
    float* gs1 = wsf + 128;  // 128
    float* gs2 = wsf + 256;  // 256
    float* ss0 = wsf + 512;  // 128
    float* ss1 = wsf + 640;  // 128
    float* ss2 = wsf + 768;  // 256
    float* P   = (float*)((char*)d_ws + 65536);                 // 16 MB if available

    const bool haveP = ws_size >= ((size_t)NB * NPTS * C0 * 4 + 65536);

    zero_kernel<<<1, 512, 0, stream>>>(wsf);
    fps_kernel<<<NB, 256, 0, stream>>>(xyz, out_newxyz);
    ball_kernel<<<(NB * NPOINTS) / 4, 256, 0, stream>>>(xyz, out_newxyz, out_idx);

    const int grid = (int)(MROWS / 128);  // 4096

    if (haveP) {
        preP_kernel<<<NB * NPTS / 256, 256, 0, stream>>>(points, W0, P);
        passP_kernel<0><<<grid, 128, 0, stream>>>(xyz, P, out_newxyz, out_idx,
                                                  W0, b0, W1, b1, W2, b2,
                                                  ss0, ss1, ss2, gs0, nullptr);
        ss_kernel<C0><<<1, C0, 0, stream>>>(gs0, g0, be0, ss0);
        passP_kernel<1><<<grid, 128, 0, stream>>>(xyz, P, out_newxyz, out_idx,
                                                  W0, b0, W1, b1, W2, b2,
                                                  ss0, ss1, ss2, gs1, nullptr);
        ss_kernel<C1><<<1, C1, 0, stream>>>(gs1, g1, be1, ss1);
        passP_kernel<2><<<grid, 128, 0, stream>>>(xyz, P, out_newxyz, out_idx,
                                                  W0, b0, W1, b1, W2, b2,
                                                  ss0, ss1, ss2, gs2, nullptr);
        ss_kernel<C2><<<1, C2, 0, stream>>>(gs2, g2, be2, ss2);
        passP_kernel<3><<<grid, 128, 0, stream>>>(xyz, P, out_newxyz, out_idx,
                                                  W0, b0, W1, b1, W2, b2,
                                                  ss0, ss1, ss2, nullptr, out_newpts);
    } else {
        pass_kernel<0><<<grid, 128, 0, stream>>>(xyz, points, out_newxyz, out_idx,
                                                 W0, b0, W1, b1, W2, b2,
                                                 ss0, ss1, ss2, gs0, nullptr);
        ss_kernel<C0><<<1, C0, 0, stream>>>(gs0, g0, be0, ss0);
        pass_kernel<1><<<grid, 128, 0, stream>>>(xyz, points, out_newxyz, out_idx,
                                                 W0, b0, W1, b1, W2, b2,
                                                 ss0, ss1, ss2, gs1, nullptr);
        ss_kernel<C1><<<1, C1, 0, stream>>>(gs1, g1, be1, ss1);
        pass_kernel<2><<<grid, 128, 0, stream>>>(xyz, points, out_newxyz, out_idx,
                                                 W0, b0, W1, b1, W2, b2,
                                                 ss0, ss1, ss2, gs2, nullptr);
        ss_kernel<C2><<<1, C2, 0, stream>>>(gs2, g2, be2, ss2);
        pass_kernel<3><<<grid, 128, 0, stream>>>(xyz, points, out_newxyz, out_idx,
                                                 W0, b0, W1, b1, W2, b2,
                                                 ss0, ss1, ss2, nullptr, out_newpts);
    }
}

// Round 4
// 1954.784 us; speedup vs baseline: 1.6256x; 1.2008x over previous
//
#include <hip/hip_runtime.h>

static constexpr int NB      = 16;
static constexpr int NPTS    = 4096;
static constexpr int NPOINTS = 1024;
static constexpr int NSAMP   = 32;
static constexpr int CIN0    = 67;   // 3 + 64
static constexpr int C0      = 64;
static constexpr int C1      = 64;
static constexpr int C2      = 128;
static constexpr size_t MROWS = (size_t)NB * NPOINTS * NSAMP; // 524288
#define RAD2 0.16f
#define BN_EPS 0.001f

__device__ __forceinline__ float4 uld4(const float* __restrict__ p) {
    return *(const float4* __restrict__)p;
}

// DPP-based wave64 argmax step (VALU pipe, ~8 cyc vs ~100+ for ds_bpermute).
// old = self, bound_ctrl=false -> invalid source lanes combine with self (no-op).
template<int CTRL>
__device__ __forceinline__ void dpp_step(float& v, int& i) {
    const int nv = __builtin_amdgcn_update_dpp(__float_as_int(v), __float_as_int(v),
                                               CTRL, 0xF, 0xF, false);
    const int ni = __builtin_amdgcn_update_dpp(i, i, CTRL, 0xF, 0xF, false);
    const float fv = __int_as_float(nv);
    if (fv > v || (fv == v && ni < i)) { v = fv; i = ni; }
}

// ---------------------------------------------------------------------------
// FPS v3: 256 threads/block (one block per batch), 16 pts/thread in registers.
// Wave argmax via DPP (row_shr 1,2,4,8 + row_bcast15,31) -> lane 63 has wave
// winner -> slot write -> ONE barrier -> all threads redundantly combine the
// 4 slots (two b128 LDS reads) -> fetch winner coords.
// Non-contracted fp32 ops to match the NumPy reference bit-exactly on indices.
// ---------------------------------------------------------------------------
__global__ __launch_bounds__(256) void fps_kernel(const float* __restrict__ xyz,
                                                  float* __restrict__ out_newxyz)
{
    __shared__ float sx[NPTS], sy[NPTS], sz[NPTS];
    __shared__ __align__(16) float redv[2][4];
    __shared__ __align__(16) int   redi[2][4];

    const int b    = blockIdx.x;
    const int tid  = threadIdx.x;
    const int lane = tid & 63;
    const int wv   = tid >> 6;

    const float* base = xyz + (size_t)b * NPTS * 3;
    for (int i = tid; i < NPTS; i += 256) {
        sx[i] = base[i * 3 + 0];
        sy[i] = base[i * 3 + 1];
        sz[i] = base[i * 3 + 2];
    }
    __syncthreads();

    float px[16], py[16], pz[16], dd[16];
#pragma unroll
    for (int j = 0; j < 16; ++j) {
        const int i = tid + j * 256;
        px[j] = sx[i]; py[j] = sy[i]; pz[j] = sz[i];
        dd[j] = 1e10f;
    }

    float fx = sx[0], fy = sy[0], fz = sz[0];
#pragma unroll 1
    for (int it = 0; it < NPOINTS; ++it) {
        if (tid == 0) {
            float* o = out_newxyz + ((size_t)b * NPOINTS + it) * 3;
            o[0] = fx; o[1] = fy; o[2] = fz;
        }
        float bv = -1.0f; int bi = 0;
#pragma unroll
        for (int j = 0; j < 16; ++j) {
            const float dx = __fsub_rn(px[j], fx);
            const float dy = __fsub_rn(py[j], fy);
            const float dz = __fsub_rn(pz[j], fz);
            const float d  = __fadd_rn(__fadd_rn(__fmul_rn(dx, dx), __fmul_rn(dy, dy)),
                                       __fmul_rn(dz, dz));
            dd[j] = fminf(dd[j], d);
            if (dd[j] > bv) { bv = dd[j]; bi = tid + j * 256; } // j asc => idx asc
        }
        // wave64 argmax via DPP, smallest-index tie-break; lane 63 holds winner
        dpp_step<0x111>(bv, bi);   // row_shr:1
        dpp_step<0x112>(bv, bi);   // row_shr:2
        dpp_step<0x114>(bv, bi);   // row_shr:4
        dpp_step<0x118>(bv, bi);   // row_shr:8
        dpp_step<0x142>(bv, bi);   // row_bcast:15
        dpp_step<0x143>(bv, bi);   // row_bcast:31

        const int pb = it & 1;
        if (lane == 63) { redv[pb][wv] = bv; redi[pb][wv] = bi; }
        __syncthreads();
        // all threads redundantly combine 4 slots -> identical winner
        float cv = redv[pb][0]; int ci = redi[pb][0];
#pragma unroll
        for (int w = 1; w < 4; ++w) {
            const float ov = redv[pb][w]; const int oi = redi[pb][w];
            if (ov > cv || (ov == cv && oi < ci)) { cv = ov; ci = oi; }
        }
        fx = sx[ci]; fy = sy[ci]; fz = sz[ci];
    }
}

// ---------------------------------------------------------------------------
// Ball query: one wave per center. Ordered first-32 via ballot+prefix popcount.
// ---------------------------------------------------------------------------
__global__ __launch_bounds__(256) void ball_kernel(const float* __restrict__ xyz,
                                                   const float* __restrict__ newxyz,
                                                   float* __restrict__ out_idx_f)
{
    __shared__ int sel[4][NSAMP];
    const int tid  = threadIdx.x;
    const int lane = tid & 63;
    const int widx = tid >> 6;
    const int w = blockIdx.x * 4 + widx;   // center id, 0..16383
    const int b = w >> 10;

    const float cx = newxyz[(size_t)w * 3 + 0];
    const float cy = newxyz[(size_t)w * 3 + 1];
    const float cz = newxyz[(size_t)w * 3 + 2];
    const float* base = xyz + (size_t)b * NPTS * 3;

    int total = 0;
    for (int c = 0; c < NPTS / 64 && total < NSAMP; ++c) {
        const int n = c * 64 + lane;
        const float dx = __fsub_rn(cx, base[n * 3 + 0]);
        const float dy = __fsub_rn(cy, base[n * 3 + 1]);
        const float dz = __fsub_rn(cz, base[n * 3 + 2]);
        const float d2 = __fadd_rn(__fadd_rn(__fmul_rn(dx, dx), __fmul_rn(dy, dy)),
                                   __fmul_rn(dz, dz));
        const bool pred = d2 < RAD2;
        const unsigned long long mask = __ballot(pred);
        if (pred) {
            const int pos = total + (int)__popcll(mask & ((1ull << lane) - 1ull));
            if (pos < NSAMP) sel[widx][pos] = n;
        }
        total += (int)__popcll(mask);
    }
    __syncthreads();
    if (lane < NSAMP) {
        const int first = sel[widx][0];
        const int v = (lane < total) ? sel[widx][lane] : first;
        out_idx_f[(size_t)w * NSAMP + lane] = (float)v;
    }
}

// ---------------------------------------------------------------------------
// Wave reduce of 4 (sum, sumsq) pairs into a wave's LDS stats slot.
// ---------------------------------------------------------------------------
__device__ __forceinline__ void stats4(float a0, float a1, float a2, float a3,
                                       float* sa, int lane)
{
    float q0 = a0*a0, q1 = a1*a1, q2 = a2*a2, q3 = a3*a3;
#pragma unroll
    for (int off = 32; off > 0; off >>= 1) {
        a0 += __shfl_down(a0, (unsigned)off, 64); q0 += __shfl_down(q0, (unsigned)off, 64);
        a1 += __shfl_down(a1, (unsigned)off, 64); q1 += __shfl_down(q1, (unsigned)off, 64);
        a2 += __shfl_down(a2, (unsigned)off, 64); q2 += __shfl_down(q2, (unsigned)off, 64);
        a3 += __shfl_down(a3, (unsigned)off, 64); q3 += __shfl_down(q3, (unsigned)off, 64);
    }
    if (lane == 0) {
        sa[0] += a0; sa[1] += q0; sa[2] += a1; sa[3] += q1;
        sa[4] += a2; sa[5] += q2; sa[6] += a3; sa[7] += q3;
    }
}

// ---------------------------------------------------------------------------
// P precompute: P[b,n,:] = points[b,n,:] . W0[3:,:]  (layer-0 dedup).
// ---------------------------------------------------------------------------
__global__ __launch_bounds__(256) void preP_kernel(const float* __restrict__ points,
                                                   const float* __restrict__ W0,
                                                   float* __restrict__ P)
{
    const int r = blockIdx.x * 256 + threadIdx.x;   // 0..65535
    const float4* pr = (const float4*)(points + (size_t)r * 64);
    float x[64];
#pragma unroll
    for (int j = 0; j < 16; ++j) {
        const float4 v = pr[j];
        x[4*j+0] = v.x; x[4*j+1] = v.y; x[4*j+2] = v.z; x[4*j+3] = v.w;
    }
    float acc[64];
#pragma unroll
    for (int o = 0; o < 64; ++o) acc[o] = 0.f;
#pragma unroll 2
    for (int k = 0; k < 64; ++k) {
        const float xk = x[k];
#pragma unroll
        for (int oc = 0; oc < 16; ++oc) {
            const float4 w4 = uld4(W0 + (3 + k) * 64 + 4 * oc);
            acc[4*oc+0] = fmaf(xk, w4.x, acc[4*oc+0]);
            acc[4*oc+1] = fmaf(xk, w4.y, acc[4*oc+1]);
            acc[4*oc+2] = fmaf(xk, w4.z, acc[4*oc+2]);
            acc[4*oc+3] = fmaf(xk, w4.w, acc[4*oc+3]);
        }
    }
    float4* po = (float4*)(P + (size_t)r * 64);
#pragma unroll
    for (int oc = 0; oc < 16; ++oc)
        po[oc] = make_float4(acc[4*oc+0], acc[4*oc+1], acc[4*oc+2], acc[4*oc+3]);
}

// ---------------------------------------------------------------------------
// P-path pass. PHASE: 0 = stats y0, 1 = stats y1, 2 = stats y2, 3 = output.
// 256-thread blocks, launch_bounds(256,2): 2 blocks/CU -> 2 waves/SIMD.
// ---------------------------------------------------------------------------
template<int PHASE>
__global__ __launch_bounds__(256, 2) void passP_kernel(
    const float* __restrict__ xyz, const float* __restrict__ P,
    const float* __restrict__ newxyz, const float* __restrict__ idxf,
    const float* __restrict__ W0, const float* __restrict__ b0,
    const float* __restrict__ W1, const float* __restrict__ b1,
    const float* __restrict__ W2, const float* __restrict__ b2,
    const float* __restrict__ ss0, const float* __restrict__ ss1,
    const float* __restrict__ ss2,
    float* __restrict__ gstats, float* __restrict__ out_np)
{
    constexpr int CS = (PHASE == 2) ? C2 : C0;
    __shared__ float sacc[4][2 * CS];

    const int tid  = threadIdx.x;
    const int lane = tid & 63;
    const int wv   = tid >> 6;

    if constexpr (PHASE <= 2) {
        for (int j = tid; j < 8 * CS; j += 256) (&sacc[0][0])[j] = 0.f;
        __syncthreads();
    }

    const int r  = blockIdx.x * 256 + tid;
    const int i  = (int)idxf[r];
    const int bb = r >> 15;
    const int pp = (r >> 5) & 1023;

    const float* pz = xyz + ((size_t)bb * NPTS + i) * 3;
    const float* nz = newxyz + ((size_t)bb * NPOINTS + pp) * 3;
    const float r0 = pz[0] - nz[0];
    const float r1 = pz[1] - nz[1];
    const float r2 = pz[2] - nz[2];
    const float4* prow = (const float4*)(P + ((size_t)bb * NPTS + i) * 64);

    // ---- layer 0 (deduped): y0 = b0 + rel.W0[0:3] + P[i] ----
    float x1[C0];
#pragma unroll
    for (int oc = 0; oc < 16; ++oc) {
        const float4 pv = prow[oc];
        const float4 bv = uld4(b0 + 4 * oc);
        const float4 wa = uld4(W0 + 0 * 64 + 4 * oc);
        const float4 wb = uld4(W0 + 1 * 64 + 4 * oc);
        const float4 wc = uld4(W0 + 2 * 64 + 4 * oc);
        x1[4*oc+0] = fmaf(r0, wa.x, fmaf(r1, wb.x, fmaf(r2, wc.x, bv.x + pv.x)));
        x1[4*oc+1] = fmaf(r0, wa.y, fmaf(r1, wb.y, fmaf(r2, wc.y, bv.y + pv.y)));
        x1[4*oc+2] = fmaf(r0, wa.z, fmaf(r1, wb.z, fmaf(r2, wc.z, bv.z + pv.z)));
        x1[4*oc+3] = fmaf(r0, wa.w, fmaf(r1, wb.w, fmaf(r2, wc.w, bv.w + pv.w)));
    }

    if constexpr (PHASE == 0) {
#pragma unroll
        for (int oc = 0; oc < 16; ++oc)
            stats4(x1[4*oc+0], x1[4*oc+1], x1[4*oc+2], x1[4*oc+3], &sacc[wv][8*oc], lane);
    } else {
        // bn0 + relu
#pragma unroll
        for (int o = 0; o < C0; ++o)
            x1[o] = fmaxf(0.f, fmaf(x1[o], ss0[o], ss0[64 + o]));

        // ---- layer 1 ----
        float y1[C1];
#pragma unroll
        for (int o = 0; o < C1; o += 4) {
            const float4 bv = uld4(b1 + o);
            y1[o] = bv.x; y1[o+1] = bv.y; y1[o+2] = bv.z; y1[o+3] = bv.w;
        }
#pragma unroll 2
        for (int k = 0; k < C0; ++k) {
            const float xk = x1[k];
#pragma unroll
            for (int oc = 0; oc < 16; ++oc) {
                const float4 w4 = uld4(W1 + k * 64 + 4 * oc);
                y1[4*oc+0] = fmaf(xk, w4.x, y1[4*oc+0]);
                y1[4*oc+1] = fmaf(xk, w4.y, y1[4*oc+1]);
                y1[4*oc+2] = fmaf(xk, w4.z, y1[4*oc+2]);
                y1[4*oc+3] = fmaf(xk, w4.w, y1[4*oc+3]);
            }
        }

        if constexpr (PHASE == 1) {
#pragma unroll
            for (int oc = 0; oc < 16; ++oc)
                stats4(y1[4*oc+0], y1[4*oc+1], y1[4*oc+2], y1[4*oc+3], &sacc[wv][8*oc], lane);
        } else {
            // bn1 + relu
#pragma unroll
            for (int o = 0; o < C1; ++o)
                y1[o] = fmaxf(0.f, fmaf(y1[o], ss1[o], ss1[64 + o]));

            // ---- layer 2 ----
            float a2[C2];
#pragma unroll
            for (int o = 0; o < C2; o += 4) {
                const float4 bv = uld4(b2 + o);
                a2[o] = bv.x; a2[o+1] = bv.y; a2[o+2] = bv.z; a2[o+3] = bv.w;
            }
#pragma unroll 2
            for (int k = 0; k < C1; ++k) {
                const float xk = y1[k];
#pragma unroll
                for (int o = 0; o < C2; o += 4) {
                    const float4 w4 = uld4(W2 + k * C2 + o);
                    a2[o+0] = fmaf(xk, w4.x, a2[o+0]);
                    a2[o+1] = fmaf(xk, w4.y, a2[o+1]);
                    a2[o+2] = fmaf(xk, w4.z, a2[o+2]);
                    a2[o+3] = fmaf(xk, w4.w, a2[o+3]);
                }
            }

            if constexpr (PHASE == 2) {
#pragma unroll
                for (int o = 0; o < C2; ++o) {
                    float s = a2[o];
                    float q = s * s;
#pragma unroll
                    for (int off = 32; off > 0; off >>= 1) {
                        s += __shfl_down(s, (unsigned)off, 64);
                        q += __shfl_down(q, (unsigned)off, 64);
                    }
                    if (lane == 0) { sacc[wv][2*o] += s; sacc[wv][2*o+1] += q; }
                }
            } else {
                const int g = r >> 5;
#pragma unroll
                for (int o = 0; o < C2; ++o) {
                    float v = fmaxf(0.f, fmaf(a2[o], ss2[o], ss2[C2 + o]));
#pragma unroll
                    for (int off = 16; off > 0; off >>= 1)
                        v = fmaxf(v, __shfl_down(v, (unsigned)off, 32));
                    if ((tid & 31) == 0) out_np[(size_t)g * C2 + o] = v;
                }
            }
        }
    }

    if constexpr (PHASE <= 2) {
        __syncthreads();
        for (int j = tid; j < 2 * CS; j += 256)
            atomicAdd(&gstats[j], sacc[0][j] + sacc[1][j] + sacc[2][j] + sacc[3][j]);
    }
}

// ---------------------------------------------------------------------------
// Fallback recompute pass (round-2 proven): used when ws_size < 16 MB.
// ---------------------------------------------------------------------------
template<int PHASE>
__global__ __launch_bounds__(128) void pass_kernel(
    const float* __restrict__ xyz, const float* __restrict__ points,
    const float* __restrict__ newxyz, const float* __restrict__ idxf,
    const float* __restrict__ W0, const float* __restrict__ b0,
    const float* __restrict__ W1, const float* __restrict__ b1,
    const float* __restrict__ W2, const float* __restrict__ b2,
    const float* __restrict__ ss0, const float* __restrict__ ss1,
    const float* __restrict__ ss2,
    float* __restrict__ gstats, float* __restrict__ out_np)
{
    constexpr int CS = (PHASE == 2) ? C2 : C0;
    __shared__ float xld[(PHASE >= 1) ? (64 * 128) : 1];
    __shared__ float sacc[2][2 * CS];

    const int tid  = threadIdx.x;
    const int lane = tid & 63;
    const int wv   = tid >> 6;

    if constexpr (PHASE <= 2) {
        for (int j = tid; j < 2 * 2 * CS; j += 128) (&sacc[0][0])[j] = 0.f;
        __syncthreads();
    }

    const int r  = blockIdx.x * 128 + tid;
    const int i  = (int)idxf[r];
    const int bb = r >> 15;
    const int pp = (r >> 5) & 1023;

    float x[CIN0];
    {
        const float* pz = xyz + ((size_t)bb * NPTS + i) * 3;
        const float* nz = newxyz + ((size_t)bb * NPOINTS + pp) * 3;
        x[0] = pz[0] - nz[0];
        x[1] = pz[1] - nz[1];
        x[2] = pz[2] - nz[2];
        const float4* p4 = (const float4*)(points + ((size_t)bb * NPTS + i) * 64);
#pragma unroll
        for (int j = 0; j < 16; ++j) {
            const float4 v = p4[j];
            x[3+4*j+0] = v.x; x[3+4*j+1] = v.y; x[3+4*j+2] = v.z; x[3+4*j+3] = v.w;
        }
    }

#pragma unroll 1
    for (int oc = 0; oc < 16; ++oc) {
        const float4 bv = uld4(b0 + 4*oc);
        float a0 = bv.x, a1 = bv.y, a2 = bv.z, a3 = bv.w;
#pragma unroll
        for (int k = 0; k < CIN0; ++k) {
            const float4 w4 = uld4(W0 + k*64 + 4*oc);
            a0 = fmaf(x[k], w4.x, a0); a1 = fmaf(x[k], w4.y, a1);
            a2 = fmaf(x[k], w4.z, a2); a3 = fmaf(x[k], w4.w, a3);
        }
        if constexpr (PHASE == 0) {
            stats4(a0, a1, a2, a3, &sacc[wv][8*oc], lane);
        } else {
            xld[(4*oc+0)*128 + tid] = fmaxf(0.f, fmaf(a0, ss0[4*oc+0], ss0[64+4*oc+0]));
            xld[(4*oc+1)*128 + tid] = fmaxf(0.f, fmaf(a1, ss0[4*oc+1], ss0[64+4*oc+1]));
            xld[(4*oc+2)*128 + tid] = fmaxf(0.f, fmaf(a2, ss0[4*oc+2], ss0[64+4*oc+2]));
            xld[(4*oc+3)*128 + tid] = fmaxf(0.f, fmaf(a3, ss0[4*oc+3], ss0[64+4*oc+3]));
        }
    }

    if constexpr (PHASE == 1) {
#pragma unroll 1
        for (int oc = 0; oc < 16; ++oc) {
            const float4 bv = uld4(b1 + 4*oc);
            float a0 = bv.x, a1 = bv.y, a2 = bv.z, a3 = bv.w;
#pragma unroll
            for (int k = 0; k < 64; ++k) {
                const float xk = xld[k*128 + tid];
                const float4 w4 = uld4(W1 + k*64 + 4*oc);
                a0 = fmaf(xk, w4.x, a0); a1 = fmaf(xk, w4.y, a1);
                a2 = fmaf(xk, w4.z, a2); a3 = fmaf(xk, w4.w, a3);
            }
            stats4(a0, a1, a2, a3, &sacc[wv][8*oc], lane);
        }
    }

    if constexpr (PHASE >= 2) {
        float acc2[C2];
#pragma unroll
        for (int o = 0; o < C2; o += 4) {
            const float4 bv = uld4(b2 + o);
            acc2[o] = bv.x; acc2[o+1] = bv.y; acc2[o+2] = bv.z; acc2[o+3] = bv.w;
        }
#pragma unroll 1
        for (int oc = 0; oc < 16; ++oc) {
            const float4 bv = uld4(b1 + 4*oc);
            float a0 = bv.x, a1 = bv.y, a2 = bv.z, a3 = bv.w;
#pragma unroll
            for (int k = 0; k < 64; ++k) {
                const float xk = xld[k*128 + tid];
                const float4 w4 = uld4(W1 + k*64 + 4*oc);
                a0 = fmaf(xk, w4.x, a0); a1 = fmaf(xk, w4.y, a1);
                a2 = fmaf(xk, w4.z, a2); a3 = fmaf(xk, w4.w, a3);
            }
            const float xc0 = fmaxf(0.f, fmaf(a0, ss1[4*oc+0], ss1[64+4*oc+0]));
            const float xc1 = fmaxf(0.f, fmaf(a1, ss1[4*oc+1], ss1[64+4*oc+1]));
            const float xc2 = fmaxf(0.f, fmaf(a2, ss1[4*oc+2], ss1[64+4*oc+2]));
            const float xc3 = fmaxf(0.f, fmaf(a3, ss1[4*oc+3], ss1[64+4*oc+3]));
#pragma unroll
            for (int o = 0; o < C2; o += 4) {
                const float4 wA = uld4(W2 + (4*oc+0)*C2 + o);
                const float4 wB = uld4(W2 + (4*oc+1)*C2 + o);
                const float4 wC = uld4(W2 + (4*oc+2)*C2 + o);
                const float4 wD = uld4(W2 + (4*oc+3)*C2 + o);
                acc2[o+0] = fmaf(xc0, wA.x, fmaf(xc1, wB.x, fmaf(xc2, wC.x, fmaf(xc3, wD.x, acc2[o+0]))));
                acc2[o+1] = fmaf(xc0, wA.y, fmaf(xc1, wB.y, fmaf(xc2, wC.y, fmaf(xc3, wD.y, acc2[o+1]))));
                acc2[o+2] = fmaf(xc0, wA.z, fmaf(xc1, wB.z, fmaf(xc2, wC.z, fmaf(xc3, wD.z, acc2[o+2]))));
                acc2[o+3] = fmaf(xc0, wA.w, fmaf(xc1, wB.w, fmaf(xc2, wC.w, fmaf(xc3, wD.w, acc2[o+3]))));
            }
        }

        if constexpr (PHASE == 2) {
#pragma unroll
            for (int o = 0; o < C2; ++o) {
                float s = acc2[o];
                float q = s * s;
#pragma unroll
                for (int off = 32; off > 0; off >>= 1) {
                    s += __shfl_down(s, (unsigned)off, 64);
                    q += __shfl_down(q, (unsigned)off, 64);
                }
                if (lane == 0) { sacc[wv][2*o] += s; sacc[wv][2*o+1] += q; }
            }
        } else {
            const int g = r >> 5;
#pragma unroll
            for (int o = 0; o < C2; ++o) {
                float v = fmaxf(0.f, fmaf(acc2[o], ss2[o], ss2[C2+o]));
#pragma unroll
                for (int off = 16; off > 0; off >>= 1)
                    v = fmaxf(v, __shfl_down(v, (unsigned)off, 32));
                if ((tid & 31) == 0) out_np[(size_t)g * C2 + o] = v;
            }
        }
    }

    if constexpr (PHASE <= 2) {
        __syncthreads();
        for (int j = tid; j < 2 * CS; j += 128)
            atomicAdd(&gstats[j], sacc[0][j] + sacc[1][j]);
    }
}

// ---------------------------------------------------------------------------
// BN scale/shift from raw sums.
// ---------------------------------------------------------------------------
template<int C>
__global__ void ss_kernel(const float* __restrict__ gs, const float* __restrict__ g,
                          const float* __restrict__ be, float* __restrict__ ss)
{
    const int o = threadIdx.x;
    const float inv  = 1.0f / (float)MROWS;
    const float mean = gs[2*o] * inv;
    const float var  = fmaxf(0.f, gs[2*o+1] * inv - mean * mean);
    const float sc   = g[o] / sqrtf(var + BN_EPS);
    ss[o]     = sc;
    ss[C + o] = fmaf(-mean, sc, be[o]);
}

__global__ void zero_kernel(float* __restrict__ p) { p[threadIdx.x] = 0.f; }

extern "C" void kernel_launch(void* const* d_in, const int* in_sizes, int n_in,
                              void* d_out, int out_size, void* d_ws, size_t ws_size,
                              hipStream_t stream)
{
    (void)in_sizes; (void)n_in; (void)out_size;
    const float* xyz    = (const float*)d_in[0];
    const float* points = (const float*)d_in[1];
    const float* W0  = (const float*)d_in[2];
    const float* b0  = (const float*)d_in[3];
    const float* g0  = (const float*)d_in[4];
    const float* be0 = (const float*)d_in[5];
    const float* W1  = (const float*)d_in[6];
    const float* b1  = (const float*)d_in[7];
    const float* g1  = (const float*)d_in[8];
    const float* be1 = (const float*)d_in[9];
    const float* W2  = (const float*)d_in[10];
    const float* b2  = (const float*)d_in[11];
    const float* g2  = (const float*)d_in[12];
    const float* be2 = (const float*)d_in[13];

    float* out = (float*)d_out;
    float* out_newxyz = out;                                    // 16*1024*3
    float* out_newpts = out + (size_t)NB * NPOINTS * 3;         // 16*1024*128
    float* out_idx    = out_newpts + (size_t)NB * NPOINTS * C2; // 16*1024*32 (float idx)

    float* wsf = (float*)d_ws;
    float* gs0 = wsf + 0;    // 128
    float* gs1 = wsf + 128;  // 128
    float* gs2 = wsf + 256;  // 256
    float* ss0 = wsf + 512;  // 128
    float* ss1 = wsf + 640;  // 128
    float* ss2 = wsf + 768;  // 256
    float* P   = (float*)((char*)d_ws + 65536);                 // 16 MB if available

    const bool haveP = ws_size >= ((size_t)NB * NPTS * C0 * 4 + 65536);

    zero_kernel<<<1, 512, 0, stream>>>(wsf);
    fps_kernel<<<NB, 256, 0, stream>>>(xyz, out_newxyz);
    ball_kernel<<<(NB * NPOINTS) / 4, 256, 0, stream>>>(xyz, out_newxyz, out_idx);

    if (haveP) {
        const int grid = (int)(MROWS / 256);  // 2048
        preP_kernel<<<NB * NPTS / 256, 256, 0, stream>>>(points, W0, P);
        passP_kernel<0><<<grid, 256, 0, stream>>>(xyz, P, out_newxyz, out_idx,
                                                  W0, b0, W1, b1, W2, b2,
                                                  ss0, ss1, ss2, gs0, nullptr);
        ss_kernel<C0><<<1, C0, 0, stream>>>(gs0, g0, be0, ss0);
        passP_kernel<1><<<grid, 256, 0, stream>>>(xyz, P, out_newxyz, out_idx,
                                                  W0, b0, W1, b1, W2, b2,
                                                  ss0, ss1, ss2, gs1, nullptr);
        ss_kernel<C1><<<1, C1, 0, stream>>>(gs1, g1, be1, ss1);
        passP_kernel<2><<<grid, 256, 0, stream>>>(xyz, P, out_newxyz, out_idx,
                                                  W0, b0, W1, b1, W2, b2,
                                                  ss0, ss1, ss2, gs2, nullptr);
        ss_kernel<C2><<<1, C2, 0, stream>>>(gs2, g2, be2, ss2);
        passP_kernel<3><<<grid, 256, 0, stream>>>(xyz, P, out_newxyz, out_idx,
                                                  W0, b0, W1, b1, W2, b2,
                                                  ss0, ss1, ss2, nullptr, out_newpts);
    } else {
        const int grid = (int)(MROWS / 128);  // 4096
        pass_kernel<0><<<grid, 128, 0, stream>>>(xyz, points, out_newxyz, out_idx,
                                                 W0, b0, W1, b1, W2, b2,
                                                 ss0, ss1, ss2, gs0, nullptr);
        ss_kernel<C0><<<1, C0, 0, stream>>>(gs0, g0, be0, ss0);
        pass_kernel<1><<<grid, 128, 0, stream>>>(xyz, points, out_newxyz, out_idx,
                                                 W0, b0, W1, b1, W2, b2,
                                                 ss0, ss1, ss2, gs1, nullptr);
        ss_kernel<C1><<<1, C1, 0, stream>>>(gs1, g1, be1, ss1);
        pass_kernel<2><<<grid, 128, 0, stream>>>(xyz, points, out_newxyz, out_idx,
                                                 W0, b0, W1, b1, W2, b2,
                                                 ss0, ss1, ss2, gs2, nullptr);
        ss_kernel<C2><<<1, C2, 0, stream>>>(gs2, g2, be2, ss2);
        pass_kernel<3><<<grid, 128, 0, stream>>>(xyz, points, out_newxyz, out_idx,
                                                 W0, b0, W1, b1, W2, b2,
                                                 ss0, ss1, ss2, nullptr, out_newpts);
    }
}

// Round 5
// 1645.055 us; speedup vs baseline: 1.9317x; 1.1883x over previous
//
#include <hip/hip_runtime.h>

static constexpr int NB      = 16;
static constexpr int NPTS    = 4096;
static constexpr int NPOINTS = 1024;
static constexpr int NSAMP   = 32;
static constexpr int CIN0    = 67;   // 3 + 64
static constexpr int C0      = 64;
static constexpr int C1      = 64;
static constexpr int C2      = 128;
static constexpr size_t MROWS = (size_t)NB * NPOINTS * NSAMP; // 524288
#define RAD2 0.16f
#define BN_EPS 0.001f

__device__ __forceinline__ float4 uld4(const float* __restrict__ p) {
    return *(const float4* __restrict__)p;
}

// ---- DPP helpers (VALU pipe, ~2 cyc/op vs ~100+ cyc ds_bpermute) ----------
// dppf: invalid source lanes yield 0 (for sums). dpps: yield self (for min/max/argmax).
template<int CTRL>
__device__ __forceinline__ float dppf(float v) {
    return __int_as_float(__builtin_amdgcn_update_dpp(0, __float_as_int(v),
                                                      CTRL, 0xF, 0xF, false));
}
template<int CTRL>
__device__ __forceinline__ float dpps(float v) {
    return __int_as_float(__builtin_amdgcn_update_dpp(__float_as_int(v), __float_as_int(v),
                                                      CTRL, 0xF, 0xF, false));
}
// full-wave sum; result valid in lane 63
__device__ __forceinline__ float dpp_sum64(float v) {
    v += dppf<0x111>(v); v += dppf<0x112>(v); v += dppf<0x114>(v); v += dppf<0x118>(v);
    v += dppf<0x142>(v); v += dppf<0x143>(v);
    return v;
}
// 32-lane-group max/min; results valid in lanes 31 and 63
__device__ __forceinline__ float dpp_max32(float v) {
    v = fmaxf(v, dpps<0x111>(v)); v = fmaxf(v, dpps<0x112>(v));
    v = fmaxf(v, dpps<0x114>(v)); v = fmaxf(v, dpps<0x118>(v));
    v = fmaxf(v, dpps<0x142>(v));
    return v;
}
__device__ __forceinline__ float dpp_min32(float v) {
    v = fminf(v, dpps<0x111>(v)); v = fminf(v, dpps<0x112>(v));
    v = fminf(v, dpps<0x114>(v)); v = fminf(v, dpps<0x118>(v));
    v = fminf(v, dpps<0x142>(v));
    return v;
}
// argmax step (smallest-index tie-break)
template<int CTRL>
__device__ __forceinline__ void dpp_amax(float& v, int& i) {
    const int nv = __builtin_amdgcn_update_dpp(__float_as_int(v), __float_as_int(v),
                                               CTRL, 0xF, 0xF, false);
    const int ni = __builtin_amdgcn_update_dpp(i, i, CTRL, 0xF, 0xF, false);
    const float fv = __int_as_float(nv);
    if (fv > v || (fv == v && ni < i)) { v = fv; i = ni; }
}

// ---------------------------------------------------------------------------
// FPS v4: 256 threads/block, 16 pts/thread in registers. Winner indices are
// buffered in LDS (sidx) and new_xyz written once at the end — removes the
// per-iteration global-store vmcnt(0) drain at the barrier (the round-4 stall).
// Non-contracted fp32 ops to match the NumPy reference bit-exactly on indices.
// ---------------------------------------------------------------------------
__global__ __launch_bounds__(256) void fps_kernel(const float* __restrict__ xyz,
                                                  float* __restrict__ out_newxyz)
{
    __shared__ float sx[NPTS], sy[NPTS], sz[NPTS];
    __shared__ int   sidx[NPOINTS];
    __shared__ __align__(16) float redv[2][4];
    __shared__ __align__(16) int   redi[2][4];

    const int b    = blockIdx.x;
    const int tid  = threadIdx.x;
    const int lane = tid & 63;
    const int wv   = tid >> 6;

    const float* base = xyz + (size_t)b * NPTS * 3;
    for (int i = tid; i < NPTS; i += 256) {
        sx[i] = base[i * 3 + 0];
        sy[i] = base[i * 3 + 1];
        sz[i] = base[i * 3 + 2];
    }
    __syncthreads();

    float px[16], py[16], pz[16], dd[16];
#pragma unroll
    for (int j = 0; j < 16; ++j) {
        const int i = tid + j * 256;
        px[j] = sx[i]; py[j] = sy[i]; pz[j] = sz[i];
        dd[j] = 1e10f;
    }

    int   far = 0;
    float fx = sx[0], fy = sy[0], fz = sz[0];
#pragma unroll 1
    for (int it = 0; it < NPOINTS; ++it) {
        if (tid == 0) sidx[it] = far;    // LDS only — no vmcnt drain at barrier
        float bv = -1.0f; int bi = 0;
#pragma unroll
        for (int j = 0; j < 16; ++j) {
            const float dx = __fsub_rn(px[j], fx);
            const float dy = __fsub_rn(py[j], fy);
            const float dz = __fsub_rn(pz[j], fz);
            const float d  = __fadd_rn(__fadd_rn(__fmul_rn(dx, dx), __fmul_rn(dy, dy)),
                                       __fmul_rn(dz, dz));
            dd[j] = fminf(dd[j], d);
            if (dd[j] > bv) { bv = dd[j]; bi = tid + j * 256; } // j asc => idx asc
        }
        // wave64 argmax via DPP; lane 63 holds wave winner
        dpp_amax<0x111>(bv, bi);
        dpp_amax<0x112>(bv, bi);
        dpp_amax<0x114>(bv, bi);
        dpp_amax<0x118>(bv, bi);
        dpp_amax<0x142>(bv, bi);
        dpp_amax<0x143>(bv, bi);

        const int pb = it & 1;
        if (lane == 63) { redv[pb][wv] = bv; redi[pb][wv] = bi; }
        __syncthreads();
        const float4 rv = *(const float4*)&redv[pb][0];
        const int4   ri = *(const int4*)&redi[pb][0];
        float cv = rv.x; int ci = ri.x;
        if (rv.y > cv || (rv.y == cv && ri.y < ci)) { cv = rv.y; ci = ri.y; }
        if (rv.z > cv || (rv.z == cv && ri.z < ci)) { cv = rv.z; ci = ri.z; }
        if (rv.w > cv || (rv.w == cv && ri.w < ci)) { cv = rv.w; ci = ri.w; }
        far = ci;
        fx = sx[ci]; fy = sy[ci]; fz = sz[ci];
    }
    __syncthreads();
    for (int it = tid; it < NPOINTS; it += 256) {
        const int ii = sidx[it];
        float* o = out_newxyz + ((size_t)b * NPOINTS + it) * 3;
        o[0] = sx[ii]; o[1] = sy[ii]; o[2] = sz[ii];
    }
}

// ---------------------------------------------------------------------------
// Ball query: one wave per center. Ordered first-32 via ballot+prefix popcount.
// ---------------------------------------------------------------------------
__global__ __launch_bounds__(256) void ball_kernel(const float* __restrict__ xyz,
                                                   const float* __restrict__ newxyz,
                                                   float* __restrict__ out_idx_f)
{
    __shared__ int sel[4][NSAMP];
    const int tid  = threadIdx.x;
    const int lane = tid & 63;
    const int widx = tid >> 6;
    const int w = blockIdx.x * 4 + widx;   // center id, 0..16383
    const int b = w >> 10;

    const float cx = newxyz[(size_t)w * 3 + 0];
    const float cy = newxyz[(size_t)w * 3 + 1];
    const float cz = newxyz[(size_t)w * 3 + 2];
    const float* base = xyz + (size_t)b * NPTS * 3;

    int total = 0;
    for (int c = 0; c < NPTS / 64 && total < NSAMP; ++c) {
        const int n = c * 64 + lane;
        const float dx = __fsub_rn(cx, base[n * 3 + 0]);
        const float dy = __fsub_rn(cy, base[n * 3 + 1]);
        const float dz = __fsub_rn(cz, base[n * 3 + 2]);
        const float d2 = __fadd_rn(__fadd_rn(__fmul_rn(dx, dx), __fmul_rn(dy, dy)),
                                   __fmul_rn(dz, dz));
        const bool pred = d2 < RAD2;
        const unsigned long long mask = __ballot(pred);
        if (pred) {
            const int pos = total + (int)__popcll(mask & ((1ull << lane) - 1ull));
            if (pos < NSAMP) sel[widx][pos] = n;
        }
        total += (int)__popcll(mask);
    }
    __syncthreads();
    if (lane < NSAMP) {
        const int first = sel[widx][0];
        const int v = (lane < total) ? sel[widx][lane] : first;
        out_idx_f[(size_t)w * NSAMP + lane] = (float)v;
    }
}

// ---------------------------------------------------------------------------
// Wave reduce of 4 (sum, sumsq) pairs into a wave's LDS stats slot (DPP).
// ---------------------------------------------------------------------------
__device__ __forceinline__ void stats4(float a0, float a1, float a2, float a3,
                                       float* sa, int lane)
{
    float q0 = a0*a0, q1 = a1*a1, q2 = a2*a2, q3 = a3*a3;
    a0 = dpp_sum64(a0); q0 = dpp_sum64(q0);
    a1 = dpp_sum64(a1); q1 = dpp_sum64(q1);
    a2 = dpp_sum64(a2); q2 = dpp_sum64(q2);
    a3 = dpp_sum64(a3); q3 = dpp_sum64(q3);
    if (lane == 63) {
        sa[0] += a0; sa[1] += q0; sa[2] += a1; sa[3] += q1;
        sa[4] += a2; sa[5] += q2; sa[6] += a3; sa[7] += q3;
    }
}

// ---------------------------------------------------------------------------
// P precompute: P[b,n,:] = points[b,n,:] . W0[3:,:]  (layer-0 dedup).
// ---------------------------------------------------------------------------
__global__ __launch_bounds__(256) void preP_kernel(const float* __restrict__ points,
                                                   const float* __restrict__ W0,
                                                   float* __restrict__ P)
{
    const int r = blockIdx.x * 256 + threadIdx.x;   // 0..65535
    const float4* pr = (const float4*)(points + (size_t)r * 64);
    float x[64];
#pragma unroll
    for (int j = 0; j < 16; ++j) {
        const float4 v = pr[j];
        x[4*j+0] = v.x; x[4*j+1] = v.y; x[4*j+2] = v.z; x[4*j+3] = v.w;
    }
    float acc[64];
#pragma unroll
    for (int o = 0; o < 64; ++o) acc[o] = 0.f;
#pragma unroll 2
    for (int k = 0; k < 64; ++k) {
        const float xk = x[k];
#pragma unroll
        for (int oc = 0; oc < 16; ++oc) {
            const float4 w4 = uld4(W0 + (3 + k) * 64 + 4 * oc);
            acc[4*oc+0] = fmaf(xk, w4.x, acc[4*oc+0]);
            acc[4*oc+1] = fmaf(xk, w4.y, acc[4*oc+1]);
            acc[4*oc+2] = fmaf(xk, w4.z, acc[4*oc+2]);
            acc[4*oc+3] = fmaf(xk, w4.w, acc[4*oc+3]);
        }
    }
    float4* po = (float4*)(P + (size_t)r * 64);
#pragma unroll
    for (int oc = 0; oc < 16; ++oc)
        po[oc] = make_float4(acc[4*oc+0], acc[4*oc+1], acc[4*oc+2], acc[4*oc+3]);
}

// ---------------------------------------------------------------------------
// Shared device body: gather + deduped layer 0 (pre-BN y0 into x1[64]).
// ---------------------------------------------------------------------------
__device__ __forceinline__ void layer0_dedup(
    const float* __restrict__ xyz, const float* __restrict__ P,
    const float* __restrict__ newxyz, const float* __restrict__ idxf,
    const float* __restrict__ W0, const float* __restrict__ b0,
    int r, float* x1)
{
    const int i  = (int)idxf[r];
    const int bb = r >> 15;
    const int pp = (r >> 5) & 1023;
    const float* pz = xyz + ((size_t)bb * NPTS + i) * 3;
    const float* nz = newxyz + ((size_t)bb * NPOINTS + pp) * 3;
    const float r0 = pz[0] - nz[0];
    const float r1 = pz[1] - nz[1];
    const float r2 = pz[2] - nz[2];
    const float4* prow = (const float4*)(P + ((size_t)bb * NPTS + i) * 64);
#pragma unroll
    for (int oc = 0; oc < 16; ++oc) {
        const float4 pv = prow[oc];
        const float4 bv = uld4(b0 + 4 * oc);
        const float4 wa = uld4(W0 + 0 * 64 + 4 * oc);
        const float4 wb = uld4(W0 + 1 * 64 + 4 * oc);
        const float4 wc = uld4(W0 + 2 * 64 + 4 * oc);
        x1[4*oc+0] = fmaf(r0, wa.x, fmaf(r1, wb.x, fmaf(r2, wc.x, bv.x + pv.x)));
        x1[4*oc+1] = fmaf(r0, wa.y, fmaf(r1, wb.y, fmaf(r2, wc.y, bv.y + pv.y)));
        x1[4*oc+2] = fmaf(r0, wa.z, fmaf(r1, wb.z, fmaf(r2, wc.z, bv.z + pv.z)));
        x1[4*oc+3] = fmaf(r0, wa.w, fmaf(r1, wb.w, fmaf(r2, wc.w, bv.w + pv.w)));
    }
}

// ---------------------------------------------------------------------------
// P-path pass. PHASE: 0 = stats y0, 1 = stats y1, 2 = stats y2, 3 = output.
// ---------------------------------------------------------------------------
template<int PHASE>
__global__ __launch_bounds__(256, 2) void passP_kernel(
    const float* __restrict__ xyz, const float* __restrict__ P,
    const float* __restrict__ newxyz, const float* __restrict__ idxf,
    const float* __restrict__ W0, const float* __restrict__ b0,
    const float* __restrict__ W1, const float* __restrict__ b1,
    const float* __restrict__ W2, const float* __restrict__ b2,
    const float* __restrict__ ss0, const float* __restrict__ ss1,
    const float* __restrict__ ss2,
    float* __restrict__ gstats, float* __restrict__ out_np)
{
    constexpr int CS = (PHASE == 2) ? C2 : C0;
    __shared__ float sacc[4][2 * CS];

    const int tid  = threadIdx.x;
    const int lane = tid & 63;
    const int wv   = tid >> 6;

    if constexpr (PHASE <= 2) {
        for (int j = tid; j < 8 * CS; j += 256) (&sacc[0][0])[j] = 0.f;
        __syncthreads();
    }

    const int r = blockIdx.x * 256 + tid;
    float x1[C0];
    layer0_dedup(xyz, P, newxyz, idxf, W0, b0, r, x1);

    if constexpr (PHASE == 0) {
#pragma unroll
        for (int oc = 0; oc < 16; ++oc)
            stats4(x1[4*oc+0], x1[4*oc+1], x1[4*oc+2], x1[4*oc+3], &sacc[wv][8*oc], lane);
    } else {
#pragma unroll
        for (int o = 0; o < C0; ++o)
            x1[o] = fmaxf(0.f, fmaf(x1[o], ss0[o], ss0[64 + o]));

        float y1[C1];
#pragma unroll
        for (int o = 0; o < C1; o += 4) {
            const float4 bv = uld4(b1 + o);
            y1[o] = bv.x; y1[o+1] = bv.y; y1[o+2] = bv.z; y1[o+3] = bv.w;
        }
#pragma unroll 2
        for (int k = 0; k < C0; ++k) {
            const float xk = x1[k];
#pragma unroll
            for (int oc = 0; oc < 16; ++oc) {
                const float4 w4 = uld4(W1 + k * 64 + 4 * oc);
                y1[4*oc+0] = fmaf(xk, w4.x, y1[4*oc+0]);
                y1[4*oc+1] = fmaf(xk, w4.y, y1[4*oc+1]);
                y1[4*oc+2] = fmaf(xk, w4.z, y1[4*oc+2]);
                y1[4*oc+3] = fmaf(xk, w4.w, y1[4*oc+3]);
            }
        }

        if constexpr (PHASE == 1) {
#pragma unroll
            for (int oc = 0; oc < 16; ++oc)
                stats4(y1[4*oc+0], y1[4*oc+1], y1[4*oc+2], y1[4*oc+3], &sacc[wv][8*oc], lane);
        } else {
#pragma unroll
            for (int o = 0; o < C1; ++o)
                y1[o] = fmaxf(0.f, fmaf(y1[o], ss1[o], ss1[64 + o]));

            float a2[C2];
#pragma unroll
            for (int o = 0; o < C2; o += 4) {
                const float4 bv = uld4(b2 + o);
                a2[o] = bv.x; a2[o+1] = bv.y; a2[o+2] = bv.z; a2[o+3] = bv.w;
            }
#pragma unroll 2
            for (int k = 0; k < C1; ++k) {
                const float xk = y1[k];
#pragma unroll
                for (int o = 0; o < C2; o += 4) {
                    const float4 w4 = uld4(W2 + k * C2 + o);
                    a2[o+0] = fmaf(xk, w4.x, a2[o+0]);
                    a2[o+1] = fmaf(xk, w4.y, a2[o+1]);
                    a2[o+2] = fmaf(xk, w4.z, a2[o+2]);
                    a2[o+3] = fmaf(xk, w4.w, a2[o+3]);
                }
            }

            if constexpr (PHASE == 2) {
#pragma unroll
                for (int o = 0; o < C2; ++o) {
                    const float s = dpp_sum64(a2[o]);
                    const float q = dpp_sum64(a2[o] * a2[o]);
                    if (lane == 63) { sacc[wv][2*o] += s; sacc[wv][2*o+1] += q; }
                }
            } else {
                const int g = r >> 5;
#pragma unroll
                for (int o = 0; o < C2; ++o) {
                    float v = fmaxf(0.f, fmaf(a2[o], ss2[o], ss2[C2 + o]));
                    v = dpp_max32(v);
                    if (lane == 31 || lane == 63) out_np[(size_t)g * C2 + o] = v;
                }
            }
        }
    }

    if constexpr (PHASE <= 2) {
        __syncthreads();
        for (int j = tid; j < 2 * CS; j += 256)
            atomicAdd(&gstats[j], sacc[0][j] + sacc[1][j] + sacc[2][j] + sacc[3][j]);
    }
}

// ---------------------------------------------------------------------------
// Phase 2 + per-group min/max of pre-BN y2 (replaces phase 3 entirely).
// max_s relu(sc*y+sh) == relu(sc>=0 ? sc*max_s(y)+sh : sc*min_s(y)+sh).
// ---------------------------------------------------------------------------
__global__ __launch_bounds__(256, 2) void passP2mm_kernel(
    const float* __restrict__ xyz, const float* __restrict__ P,
    const float* __restrict__ newxyz, const float* __restrict__ idxf,
    const float* __restrict__ W0, const float* __restrict__ b0,
    const float* __restrict__ W1, const float* __restrict__ b1,
    const float* __restrict__ W2, const float* __restrict__ b2,
    const float* __restrict__ ss0, const float* __restrict__ ss1,
    float* __restrict__ gstats, float* __restrict__ mnmx)
{
    __shared__ float sacc[4][2 * C2];

    const int tid  = threadIdx.x;
    const int lane = tid & 63;
    const int wv   = tid >> 6;

    for (int j = tid; j < 8 * C2; j += 256) (&sacc[0][0])[j] = 0.f;
    __syncthreads();

    const int r = blockIdx.x * 256 + tid;
    float x1[C0];
    layer0_dedup(xyz, P, newxyz, idxf, W0, b0, r, x1);

#pragma unroll
    for (int o = 0; o < C0; ++o)
        x1[o] = fmaxf(0.f, fmaf(x1[o], ss0[o], ss0[64 + o]));

    float y1[C1];
#pragma unroll
    for (int o = 0; o < C1; o += 4) {
        const float4 bv = uld4(b1 + o);
        y1[o] = bv.x; y1[o+1] = bv.y; y1[o+2] = bv.z; y1[o+3] = bv.w;
    }
#pragma unroll 2
    for (int k = 0; k < C0; ++k) {
        const float xk = x1[k];
#pragma unroll
        for (int oc = 0; oc < 16; ++oc) {
            const float4 w4 = uld4(W1 + k * 64 + 4 * oc);
            y1[4*oc+0] = fmaf(xk, w4.x, y1[4*oc+0]);
            y1[4*oc+1] = fmaf(xk, w4.y, y1[4*oc+1]);
            y1[4*oc+2] = fmaf(xk, w4.z, y1[4*oc+2]);
            y1[4*oc+3] = fmaf(xk, w4.w, y1[4*oc+3]);
        }
    }
#pragma unroll
    for (int o = 0; o < C1; ++o)
        y1[o] = fmaxf(0.f, fmaf(y1[o], ss1[o], ss1[64 + o]));

    float a2[C2];
#pragma unroll
    for (int o = 0; o < C2; o += 4) {
        const float4 bv = uld4(b2 + o);
        a2[o] = bv.x; a2[o+1] = bv.y; a2[o+2] = bv.z; a2[o+3] = bv.w;
    }
#pragma unroll 2
    for (int k = 0; k < C1; ++k) {
        const float xk = y1[k];
#pragma unroll
        for (int o = 0; o < C2; o += 4) {
            const float4 w4 = uld4(W2 + k * C2 + o);
            a2[o+0] = fmaf(xk, w4.x, a2[o+0]);
            a2[o+1] = fmaf(xk, w4.y, a2[o+1]);
            a2[o+2] = fmaf(xk, w4.z, a2[o+2]);
            a2[o+3] = fmaf(xk, w4.w, a2[o+3]);
        }
    }

    // epilogue: per-channel stats (64-lane sum) + per-group (32-lane) min/max
    const int gbase = blockIdx.x * 8 + 2 * wv;   // lane31 -> gbase, lane63 -> gbase+1
    float* mb = mnmx + ((size_t)gbase + (lane >> 5)) * 256;
#pragma unroll
    for (int o = 0; o < C2; ++o) {
        const float v = a2[o];
        const float s = dpp_sum64(v);
        const float q = dpp_sum64(v * v);
        const float mn = dpp_min32(v);
        const float mx = dpp_max32(v);
        if (lane == 63) { sacc[wv][2*o] += s; sacc[wv][2*o+1] += q; }
        if (lane == 31 || lane == 63) { mb[o] = mn; mb[128 + o] = mx; }
    }

    __syncthreads();
    for (int j = tid; j < 2 * C2; j += 256)
        atomicAdd(&gstats[j], sacc[0][j] + sacc[1][j] + sacc[2][j] + sacc[3][j]);
}

// ---------------------------------------------------------------------------
// Finalize: out[g,o] = relu(sc>=0 ? sc*max+sh : sc*min+sh).
// ---------------------------------------------------------------------------
__global__ __launch_bounds__(256) void fin_kernel(const float* __restrict__ mnmx,
                                                  const float* __restrict__ ss2,
                                                  float* __restrict__ out_np)
{
    const int t = blockIdx.x * 256 + threadIdx.x;   // 0 .. 16384*128-1
    const int g = t >> 7;
    const int o = t & 127;
    const float sc = ss2[o], sh = ss2[C2 + o];
    const float y  = (sc >= 0.f) ? mnmx[(size_t)g * 256 + 128 + o]
                                 : mnmx[(size_t)g * 256 + o];
    out_np[t] = fmaxf(0.f, fmaf(y, sc, sh));
}

// ---------------------------------------------------------------------------
// Fallback recompute pass (round-2 proven): used when ws_size < 16 MB.
// ---------------------------------------------------------------------------
template<int PHASE>
__global__ __launch_bounds__(128) void pass_kernel(
    const float* __restrict__ xyz, const float* __restrict__ points,
    const float* __restrict__ newxyz, const float* __restrict__ idxf,
    const float* __restrict__ W0, const float* __restrict__ b0,
    const float* __restrict__ W1, const float* __restrict__ b1,
    const float* __restrict__ W2, const float* __restrict__ b2,
    const float* __restrict__ ss0, const float* __restrict__ ss1,
    const float* __restrict__ ss2,
    float* __restrict__ gstats, float* __restrict__ out_np)
{
    constexpr int CS = (PHASE == 2) ? C2 : C0;
    __shared__ float xld[(PHASE >= 1) ? (64 * 128) : 1];
    __shared__ float sacc[2][2 * CS];

    const int tid  = threadIdx.x;
    const int lane = tid & 63;
    const int wv   = tid >> 6;

    if constexpr (PHASE <= 2) {
        for (int j = tid; j < 2 * 2 * CS; j += 128) (&sacc[0][0])[j] = 0.f;
        __syncthreads();
    }

    const int r  = blockIdx.x * 128 + tid;
    const int i  = (int)idxf[r];
    const int bb = r >> 15;
    const int pp = (r >> 5) & 1023;

    float x[CIN0];
    {
        const float* pz = xyz + ((size_t)bb * NPTS + i) * 3;
        const float* nz = newxyz + ((size_t)bb * NPOINTS + pp) * 3;
        x[0] = pz[0] - nz[0];
        x[1] = pz[1] - nz[1];
        x[2] = pz[2] - nz[2];
        const float4* p4 = (const float4*)(points + ((size_t)bb * NPTS + i) * 64);
#pragma unroll
        for (int j = 0; j < 16; ++j) {
            const float4 v = p4[j];
            x[3+4*j+0] = v.x; x[3+4*j+1] = v.y; x[3+4*j+2] = v.z; x[3+4*j+3] = v.w;
        }
    }

#pragma unroll 1
    for (int oc = 0; oc < 16; ++oc) {
        const float4 bv = uld4(b0 + 4*oc);
        float a0 = bv.x, a1 = bv.y, a2 = bv.z, a3 = bv.w;
#pragma unroll
        for (int k = 0; k < CIN0; ++k) {
            const float4 w4 = uld4(W0 + k*64 + 4*oc);
            a0 = fmaf(x[k], w4.x, a0); a1 = fmaf(x[k], w4.y, a1);
            a2 = fmaf(x[k], w4.z, a2); a3 = fmaf(x[k], w4.w, a3);
        }
        if constexpr (PHASE == 0) {
            stats4(a0, a1, a2, a3, &sacc[wv][8*oc], lane);
        } else {
            xld[(4*oc+0)*128 + tid] = fmaxf(0.f, fmaf(a0, ss0[4*oc+0], ss0[64+4*oc+0]));
            xld[(4*oc+1)*128 + tid] = fmaxf(0.f, fmaf(a1, ss0[4*oc+1], ss0[64+4*oc+1]));
            xld[(4*oc+2)*128 + tid] = fmaxf(0.f, fmaf(a2, ss0[4*oc+2], ss0[64+4*oc+2]));
            xld[(4*oc+3)*128 + tid] = fmaxf(0.f, fmaf(a3, ss0[4*oc+3], ss0[64+4*oc+3]));
        }
    }

    if constexpr (PHASE == 1) {
#pragma unroll 1
        for (int oc = 0; oc < 16; ++oc) {
            const float4 bv = uld4(b1 + 4*oc);
            float a0 = bv.x, a1 = bv.y, a2 = bv.z, a3 = bv.w;
#pragma unroll
            for (int k = 0; k < 64; ++k) {
                const float xk = xld[k*128 + tid];
                const float4 w4 = uld4(W1 + k*64 + 4*oc);
                a0 = fmaf(xk, w4.x, a0); a1 = fmaf(xk, w4.y, a1);
                a2 = fmaf(xk, w4.z, a2); a3 = fmaf(xk, w4.w, a3);
            }
            stats4(a0, a1, a2, a3, &sacc[wv][8*oc], lane);
        }
    }

    if constexpr (PHASE >= 2) {
        float acc2[C2];
#pragma unroll
        for (int o = 0; o < C2; o += 4) {
            const float4 bv = uld4(b2 + o);
            acc2[o] = bv.x; acc2[o+1] = bv.y; acc2[o+2] = bv.z; acc2[o+3] = bv.w;
        }
#pragma unroll 1
        for (int oc = 0; oc < 16; ++oc) {
            const float4 bv = uld4(b1 + 4*oc);
            float a0 = bv.x, a1 = bv.y, a2 = bv.z, a3 = bv.w;
#pragma unroll
            for (int k = 0; k < 64; ++k) {
                const float xk = xld[k*128 + tid];
                const float4 w4 = uld4(W1 + k*64 + 4*oc);
                a0 = fmaf(xk, w4.x, a0); a1 = fmaf(xk, w4.y, a1);
                a2 = fmaf(xk, w4.z, a2); a3 = fmaf(xk, w4.w, a3);
            }
            const float xc0 = fmaxf(0.f, fmaf(a0, ss1[4*oc+0], ss1[64+4*oc+0]));
            const float xc1 = fmaxf(0.f, fmaf(a1, ss1[4*oc+1], ss1[64+4*oc+1]));
            const float xc2 = fmaxf(0.f, fmaf(a2, ss1[4*oc+2], ss1[64+4*oc+2]));
            const float xc3 = fmaxf(0.f, fmaf(a3, ss1[4*oc+3], ss1[64+4*oc+3]));
#pragma unroll
            for (int o = 0; o < C2; o += 4) {
                const float4 wA = uld4(W2 + (4*oc+0)*C2 + o);
                const float4 wB = uld4(W2 + (4*oc+1)*C2 + o);
                const float4 wC = uld4(W2 + (4*oc+2)*C2 + o);
                const float4 wD = uld4(W2 + (4*oc+3)*C2 + o);
                acc2[o+0] = fmaf(xc0, wA.x, fmaf(xc1, wB.x, fmaf(xc2, wC.x, fmaf(xc3, wD.x, acc2[o+0]))));
                acc2[o+1] = fmaf(xc0, wA.y, fmaf(xc1, wB.y, fmaf(xc2, wC.y, fmaf(xc3, wD.y, acc2[o+1]))));
                acc2[o+2] = fmaf(xc0, wA.z, fmaf(xc1, wB.z, fmaf(xc2, wC.z, fmaf(xc3, wD.z, acc2[o+2]))));
                acc2[o+3] = fmaf(xc0, wA.w, fmaf(xc1, wB.w, fmaf(xc2, wC.w, fmaf(xc3, wD.w, acc2[o+3]))));
            }
        }

        if constexpr (PHASE == 2) {
#pragma unroll
            for (int o = 0; o < C2; ++o) {
                const float s = dpp_sum64(acc2[o]);
                const float q = dpp_sum64(acc2[o] * acc2[o]);
                if (lane == 63) { sacc[wv][2*o] += s; sacc[wv][2*o+1] += q; }
            }
        } else {
            const int g = r >> 5;
#pragma unroll
            for (int o = 0; o < C2; ++o) {
                float v = fmaxf(0.f, fmaf(acc2[o], ss2[o], ss2[C2+o]));
                v = dpp_max32(v);
                if (lane == 31 || lane == 63) out_np[(size_t)g * C2 + o] = v;
            }
        }
    }

    if constexpr (PHASE <= 2) {
        __syncthreads();
        for (int j = tid; j < 2 * CS; j += 128)
            atomicAdd(&gstats[j], sacc[0][j] + sacc[1][j]);
    }
}

// ---------------------------------------------------------------------------
// BN scale/shift from raw sums.
// ---------------------------------------------------------------------------
template<int C>
__global__ void ss_kernel(const float* __restrict__ gs, const float* __restrict__ g,
                          const float* __restrict__ be, float* __restrict__ ss)
{
    const int o = threadIdx.x;
    const float inv  = 1.0f / (float)MROWS;
    const float mean = gs[2*o] * inv;
    const float var  = fmaxf(0.f, gs[2*o+1] * inv - mean * mean);
    const float sc   = g[o] / sqrtf(var + BN_EPS);
    ss[o]     = sc;
    ss[C + o] = fmaf(-mean, sc, be[o]);
}

__global__ void zero_kernel(float* __restrict__ p) { p[threadIdx.x] = 0.f; }

extern "C" void kernel_launch(void* const* d_in, const int* in_sizes, int n_in,
                              void* d_out, int out_size, void* d_ws, size_t ws_size,
                              hipStream_t stream)
{
    (void)in_sizes; (void)n_in; (void)out_size;
    const float* xyz    = (const float*)d_in[0];
    const float* points = (const float*)d_in[1];
    const float* W0  = (const float*)d_in[2];
    const float* b0  = (const float*)d_in[3];
    const float* g0  = (const float*)d_in[4];
    const float* be0 = (const float*)d_in[5];
    const float* W1  = (const float*)d_in[6];
    const float* b1  = (const float*)d_in[7];
    const float* g1  = (const float*)d_in[8];
    const float* be1 = (const float*)d_in[9];
    const float* W2  = (const float*)d_in[10];
    const float* b2  = (const float*)d_in[11];
    const float* g2  = (const float*)d_in[12];
    const float* be2 = (const float*)d_in[13];

    float* out = (float*)d_out;
    float* out_newxyz = out;                                    // 16*1024*3
    float* out_newpts = out + (size_t)NB * NPOINTS * 3;         // 16*1024*128
    float* out_idx    = out_newpts + (size_t)NB * NPOINTS * C2; // 16*1024*32 (float idx)

    float* wsf = (float*)d_ws;
    float* gs0 = wsf + 0;    // 128
    float* gs1 = wsf + 128;  // 128
    float* gs2 = wsf + 256;  // 256
    float* ss0 = wsf + 512;  // 128
    float* ss1 = wsf + 640;  // 128
    float* ss2 = wsf + 768;  // 256
    const size_t PBYTES = (size_t)NB * NPTS * C0 * 4;           // 16 MB
    const size_t MMBYTES = (size_t)NB * NPOINTS * 2 * C2 * 4;   // 16 MB
    float* P    = (float*)((char*)d_ws + 65536);
    float* mnmx = (float*)((char*)d_ws + 65536 + PBYTES);

    const bool haveP  = ws_size >= (65536 + PBYTES);
    const bool haveMM = ws_size >= (65536 + PBYTES + MMBYTES);

    zero_kernel<<<1, 512, 0, stream>>>(wsf);
    fps_kernel<<<NB, 256, 0, stream>>>(xyz, out_newxyz);
    ball_kernel<<<(NB * NPOINTS) / 4, 256, 0, stream>>>(xyz, out_newxyz, out_idx);

    if (haveP) {
        const int grid = (int)(MROWS / 256);  // 2048
        preP_kernel<<<NB * NPTS / 256, 256, 0, stream>>>(points, W0, P);
        passP_kernel<0><<<grid, 256, 0, stream>>>(xyz, P, out_newxyz, out_idx,
                                                  W0, b0, W1, b1, W2, b2,
                                                  ss0, ss1, ss2, gs0, nullptr);
        ss_kernel<C0><<<1, C0, 0, stream>>>(gs0, g0, be0, ss0);
        passP_kernel<1><<<grid, 256, 0, stream>>>(xyz, P, out_newxyz, out_idx,
                                                  W0, b0, W1, b1, W2, b2,
                                                  ss0, ss1, ss2, gs1, nullptr);
        ss_kernel<C1><<<1, C1, 0, stream>>>(gs1, g1, be1, ss1);
        if (haveMM) {
            passP2mm_kernel<<<grid, 256, 0, stream>>>(xyz, P, out_newxyz, out_idx,
                                                      W0, b0, W1, b1, W2, b2,
                                                      ss0, ss1, gs2, mnmx);
            ss_kernel<C2><<<1, C2, 0, stream>>>(gs2, g2, be2, ss2);
            fin_kernel<<<NB * NPOINTS * C2 / 256, 256, 0, stream>>>(mnmx, ss2, out_newpts);
        } else {
            passP_kernel<2><<<grid, 256, 0, stream>>>(xyz, P, out_newxyz, out_idx,
                                                      W0, b0, W1, b1, W2, b2,
                                                      ss0, ss1, ss2, gs2, nullptr);
            ss_kernel<C2><<<1, C2, 0, stream>>>(gs2, g2, be2, ss2);
            passP_kernel<3><<<grid, 256, 0, stream>>>(xyz, P, out_newxyz, out_idx,
                                                      W0, b0, W1, b1, W2, b2,
                                                      ss0, ss1, ss2, nullptr, out_newpts);
        }
    } else {
        const int grid = (int)(MROWS / 128);  // 4096
        pass_kernel<0><<<grid, 128, 0, stream>>>(xyz, points, out_newxyz, out_idx,
                                                 W0, b0, W1, b1, W2, b2,
                                                 ss0, ss1, ss2, gs0, nullptr);
        ss_kernel<C0><<<1, C0, 0, stream>>>(gs0, g0, be0, ss0);
        pass_kernel<1><<<grid, 128, 0, stream>>>(xyz, points, out_newxyz, out_idx,
                                                 W0, b0, W1, b1, W2, b2,
                                                 ss0, ss1, ss2, gs1, nullptr);
        ss_kernel<C1><<<1, C1, 0, stream>>>(gs1, g1, be1, ss1);
        pass_kernel<2><<<grid, 128, 0, stream>>>(xyz, points, out_newxyz, out_idx,
                                                 W0, b0, W1, b1, W2, b2,
                                                 ss0, ss1, ss2, gs2, nullptr);
        ss_kernel<C2><<<1, C2, 0, stream>>>(gs2, g2, be2, ss2);
        pass_kernel<3><<<grid, 128, 0, stream>>>(xyz, points, out_newxyz, out_idx,
                                                 W0, b0, W1, b1, W2, b2,
                                                 ss0, ss1, ss2, nullptr, out_newpts);
    }
}

// Round 6
// 1286.472 us; speedup vs baseline: 2.4701x; 1.2787x over previous
//
#include <hip/hip_runtime.h>

static constexpr int NB      = 16;
static constexpr int NPTS    = 4096;
static constexpr int NPOINTS = 1024;
static constexpr int NSAMP   = 32;
static constexpr int CIN0    = 67;   // 3 + 64
static constexpr int C0      = 64;
static constexpr int C1      = 64;
static constexpr int C2      = 128;
static constexpr size_t MROWS = (size_t)NB * NPOINTS * NSAMP; // 524288
#define RAD2 0.16f
#define BN_EPS 0.001f

__device__ __forceinline__ float4 uld4(const float* __restrict__ p) {
    return *(const float4* __restrict__)p;
}

// bf16 RNE pack/unpack (self-contained)
__device__ __forceinline__ unsigned short f2bf(float f) {
    const unsigned u = __float_as_uint(f);
    return (unsigned short)((u + 0x7fffu + ((u >> 16) & 1u)) >> 16);
}
__device__ __forceinline__ float bf2f(unsigned short h) {
    return __uint_as_float((unsigned)h << 16);
}

// ---- DPP helpers (VALU pipe) ----------------------------------------------
template<int CTRL>
__device__ __forceinline__ float dppf(float v) {
    return __int_as_float(__builtin_amdgcn_update_dpp(0, __float_as_int(v),
                                                      CTRL, 0xF, 0xF, false));
}
template<int CTRL>
__device__ __forceinline__ float dpps(float v) {
    return __int_as_float(__builtin_amdgcn_update_dpp(__float_as_int(v), __float_as_int(v),
                                                      CTRL, 0xF, 0xF, false));
}
__device__ __forceinline__ float dpp_sum64(float v) {
    v += dppf<0x111>(v); v += dppf<0x112>(v); v += dppf<0x114>(v); v += dppf<0x118>(v);
    v += dppf<0x142>(v); v += dppf<0x143>(v);
    return v;   // lane 63
}
__device__ __forceinline__ float dpp_max32(float v) {
    v = fmaxf(v, dpps<0x111>(v)); v = fmaxf(v, dpps<0x112>(v));
    v = fmaxf(v, dpps<0x114>(v)); v = fmaxf(v, dpps<0x118>(v));
    v = fmaxf(v, dpps<0x142>(v));
    return v;   // lanes 31, 63
}
__device__ __forceinline__ float dpp_min32(float v) {
    v = fminf(v, dpps<0x111>(v)); v = fminf(v, dpps<0x112>(v));
    v = fminf(v, dpps<0x114>(v)); v = fminf(v, dpps<0x118>(v));
    v = fminf(v, dpps<0x142>(v));
    return v;   // lanes 31, 63
}
// u64-key argmax step: key = (f32bits(d) << 32) | (4095 - idx); d >= 0 so
// fp32 bit pattern is order-monotone; ties -> larger low word = smaller idx.
template<int CTRL>
__device__ __forceinline__ void kstep(unsigned long long& k) {
    const unsigned hi = (unsigned)(k >> 32);
    const unsigned lo = (unsigned)(k & 0xffffffffull);
    const unsigned ohi = (unsigned)__builtin_amdgcn_update_dpp((int)hi, (int)hi, CTRL, 0xF, 0xF, false);
    const unsigned olo = (unsigned)__builtin_amdgcn_update_dpp((int)lo, (int)lo, CTRL, 0xF, 0xF, false);
    const unsigned long long ok = ((unsigned long long)ohi << 32) | olo;
    if (ok > k) k = ok;
}

// ---------------------------------------------------------------------------
// FPS v5: 512 threads (8 waves -> 2 waves/SIMD for latency hiding), 8 pts/
// thread, u64-key DPP argmax, one barrier/iter, coalesced output at end.
// Non-contracted fp32 ops to match the NumPy reference bit-exactly on indices.
// ---------------------------------------------------------------------------
__global__ __launch_bounds__(512) void fps_kernel(const float* __restrict__ xyz,
                                                  float* __restrict__ out_newxyz)
{
    __shared__ float sx[NPTS], sy[NPTS], sz[NPTS];
    __shared__ int   sidx[NPOINTS];
    __shared__ __align__(16) unsigned long long redk[2][8];

    const int b    = blockIdx.x;
    const int tid  = threadIdx.x;
    const int lane = tid & 63;
    const int wv   = tid >> 6;

    const float* base = xyz + (size_t)b * NPTS * 3;
    for (int i = tid; i < NPTS; i += 512) {
        sx[i] = base[i * 3 + 0];
        sy[i] = base[i * 3 + 1];
        sz[i] = base[i * 3 + 2];
    }
    __syncthreads();

    float px[8], py[8], pz[8], dd[8];
#pragma unroll
    for (int j = 0; j < 8; ++j) {
        const int i = tid + j * 512;
        px[j] = sx[i]; py[j] = sy[i]; pz[j] = sz[i];
        dd[j] = 1e10f;
    }

    int   far = 0;
    float fx = sx[0], fy = sy[0], fz = sz[0];
#pragma unroll 1
    for (int it = 0; it < NPOINTS; ++it) {
        if (tid == 0) sidx[it] = far;
        float bv = -1.0f; int bi = 0;
#pragma unroll
        for (int j = 0; j < 8; ++j) {
            const float dx = __fsub_rn(px[j], fx);
            const float dy = __fsub_rn(py[j], fy);
            const float dz = __fsub_rn(pz[j], fz);
            const float d  = __fadd_rn(__fadd_rn(__fmul_rn(dx, dx), __fmul_rn(dy, dy)),
                                       __fmul_rn(dz, dz));
            dd[j] = fminf(dd[j], d);
            if (dd[j] > bv) { bv = dd[j]; bi = tid + j * 512; } // j asc => idx asc
        }
        unsigned long long k = ((unsigned long long)__float_as_uint(bv) << 32)
                             | (unsigned)(4095 - bi);
        kstep<0x111>(k);   // row_shr:1
        kstep<0x112>(k);   // row_shr:2
        kstep<0x114>(k);   // row_shr:4
        kstep<0x118>(k);   // row_shr:8
        kstep<0x142>(k);   // row_bcast:15
        kstep<0x143>(k);   // row_bcast:31

        const int pb = it & 1;
        if (lane == 63) redk[pb][wv] = k;
        __syncthreads();
        unsigned long long ck = redk[pb][0];
#pragma unroll
        for (int w = 1; w < 8; ++w) {
            const unsigned long long ok = redk[pb][w];
            if (ok > ck) ck = ok;
        }
        const int ci = 4095 - (int)(unsigned)(ck & 0xffffffffull);
        far = ci;
        fx = sx[ci]; fy = sy[ci]; fz = sz[ci];
    }
    __syncthreads();
    for (int it = tid; it < NPOINTS; it += 512) {
        const int ii = sidx[it];
        float* o = out_newxyz + ((size_t)b * NPOINTS + it) * 3;
        o[0] = sx[ii]; o[1] = sy[ii]; o[2] = sz[ii];
    }
}

// ---------------------------------------------------------------------------
// Ball query: one wave per center. Ordered first-32 via ballot+prefix popcount.
// ---------------------------------------------------------------------------
__global__ __launch_bounds__(256) void ball_kernel(const float* __restrict__ xyz,
                                                   const float* __restrict__ newxyz,
                                                   float* __restrict__ out_idx_f)
{
    __shared__ int sel[4][NSAMP];
    const int tid  = threadIdx.x;
    const int lane = tid & 63;
    const int widx = tid >> 6;
    const int w = blockIdx.x * 4 + widx;   // center id, 0..16383
    const int b = w >> 10;

    const float cx = newxyz[(size_t)w * 3 + 0];
    const float cy = newxyz[(size_t)w * 3 + 1];
    const float cz = newxyz[(size_t)w * 3 + 2];
    const float* base = xyz + (size_t)b * NPTS * 3;

    int total = 0;
    for (int c = 0; c < NPTS / 64 && total < NSAMP; ++c) {
        const int n = c * 64 + lane;
        const float dx = __fsub_rn(cx, base[n * 3 + 0]);
        const float dy = __fsub_rn(cy, base[n * 3 + 1]);
        const float dz = __fsub_rn(cz, base[n * 3 + 2]);
        const float d2 = __fadd_rn(__fadd_rn(__fmul_rn(dx, dx), __fmul_rn(dy, dy)),
                                   __fmul_rn(dz, dz));
        const bool pred = d2 < RAD2;
        const unsigned long long mask = __ballot(pred);
        if (pred) {
            const int pos = total + (int)__popcll(mask & ((1ull << lane) - 1ull));
            if (pos < NSAMP) sel[widx][pos] = n;
        }
        total += (int)__popcll(mask);
    }
    __syncthreads();
    if (lane < NSAMP) {
        const int first = sel[widx][0];
        const int v = (lane < total) ? sel[widx][lane] : first;
        out_idx_f[(size_t)w * NSAMP + lane] = (float)v;
    }
}

// ---------------------------------------------------------------------------
// Wave reduce of 4 (sum, sumsq) pairs into a wave's LDS stats slot (DPP).
// ---------------------------------------------------------------------------
__device__ __forceinline__ void stats4(float a0, float a1, float a2, float a3,
                                       float* sa, int lane)
{
    float q0 = a0*a0, q1 = a1*a1, q2 = a2*a2, q3 = a3*a3;
    a0 = dpp_sum64(a0); q0 = dpp_sum64(q0);
    a1 = dpp_sum64(a1); q1 = dpp_sum64(q1);
    a2 = dpp_sum64(a2); q2 = dpp_sum64(q2);
    a3 = dpp_sum64(a3); q3 = dpp_sum64(q3);
    if (lane == 63) {
        sa[0] += a0; sa[1] += q0; sa[2] += a1; sa[3] += q1;
        sa[4] += a2; sa[5] += q2; sa[6] += a3; sa[7] += q3;
    }
}

// ---------------------------------------------------------------------------
// P precompute: P[b,n,:] = points[b,n,:] . W0[3:,:]  (layer-0 dedup).
// ---------------------------------------------------------------------------
__global__ __launch_bounds__(256) void preP_kernel(const float* __restrict__ points,
                                                   const float* __restrict__ W0,
                                                   float* __restrict__ P)
{
    const int r = blockIdx.x * 256 + threadIdx.x;   // 0..65535
    const float4* pr = (const float4*)(points + (size_t)r * 64);
    float x[64];
#pragma unroll
    for (int j = 0; j < 16; ++j) {
        const float4 v = pr[j];
        x[4*j+0] = v.x; x[4*j+1] = v.y; x[4*j+2] = v.z; x[4*j+3] = v.w;
    }
    float acc[64];
#pragma unroll
    for (int o = 0; o < 64; ++o) acc[o] = 0.f;
#pragma unroll 2
    for (int k = 0; k < 64; ++k) {
        const float xk = x[k];
#pragma unroll
        for (int oc = 0; oc < 16; ++oc) {
            const float4 w4 = uld4(W0 + (3 + k) * 64 + 4 * oc);
            acc[4*oc+0] = fmaf(xk, w4.x, acc[4*oc+0]);
            acc[4*oc+1] = fmaf(xk, w4.y, acc[4*oc+1]);
            acc[4*oc+2] = fmaf(xk, w4.z, acc[4*oc+2]);
            acc[4*oc+3] = fmaf(xk, w4.w, acc[4*oc+3]);
        }
    }
    float4* po = (float4*)(P + (size_t)r * 64);
#pragma unroll
    for (int oc = 0; oc < 16; ++oc)
        po[oc] = make_float4(acc[4*oc+0], acc[4*oc+1], acc[4*oc+2], acc[4*oc+3]);
}

// ---------------------------------------------------------------------------
// Shared device body: gather + deduped layer 0 (pre-BN y0 into x1[64]).
// ---------------------------------------------------------------------------
__device__ __forceinline__ void layer0_dedup(
    const float* __restrict__ xyz, const float* __restrict__ P,
    const float* __restrict__ newxyz, const float* __restrict__ idxf,
    const float* __restrict__ W0, const float* __restrict__ b0,
    int r, float* x1)
{
    const int i  = (int)idxf[r];
    const int bb = r >> 15;
    const int pp = (r >> 5) & 1023;
    const float* pz = xyz + ((size_t)bb * NPTS + i) * 3;
    const float* nz = newxyz + ((size_t)bb * NPOINTS + pp) * 3;
    const float r0 = pz[0] - nz[0];
    const float r1 = pz[1] - nz[1];
    const float r2 = pz[2] - nz[2];
    const float4* prow = (const float4*)(P + ((size_t)bb * NPTS + i) * 64);
#pragma unroll
    for (int oc = 0; oc < 16; ++oc) {
        const float4 pv = prow[oc];
        const float4 bv = uld4(b0 + 4 * oc);
        const float4 wa = uld4(W0 + 0 * 64 + 4 * oc);
        const float4 wb = uld4(W0 + 1 * 64 + 4 * oc);
        const float4 wc = uld4(W0 + 2 * 64 + 4 * oc);
        x1[4*oc+0] = fmaf(r0, wa.x, fmaf(r1, wb.x, fmaf(r2, wc.x, bv.x + pv.x)));
        x1[4*oc+1] = fmaf(r0, wa.y, fmaf(r1, wb.y, fmaf(r2, wc.y, bv.y + pv.y)));
        x1[4*oc+2] = fmaf(r0, wa.z, fmaf(r1, wb.z, fmaf(r2, wc.z, bv.z + pv.z)));
        x1[4*oc+3] = fmaf(r0, wa.w, fmaf(r1, wb.w, fmaf(r2, wc.w, bv.w + pv.w)));
    }
}

// ---------------------------------------------------------------------------
// P-path pass. PHASE: 0 = stats y0, 1 = stats y1, 2 = stats y2, 3 = output.
// ---------------------------------------------------------------------------
template<int PHASE>
__global__ __launch_bounds__(256, 2) void passP_kernel(
    const float* __restrict__ xyz, const float* __restrict__ P,
    const float* __restrict__ newxyz, const float* __restrict__ idxf,
    const float* __restrict__ W0, const float* __restrict__ b0,
    const float* __restrict__ W1, const float* __restrict__ b1,
    const float* __restrict__ W2, const float* __restrict__ b2,
    const float* __restrict__ ss0, const float* __restrict__ ss1,
    const float* __restrict__ ss2,
    float* __restrict__ gstats, float* __restrict__ out_np)
{
    constexpr int CS = (PHASE == 2) ? C2 : C0;
    __shared__ float sacc[4][2 * CS];

    const int tid  = threadIdx.x;
    const int lane = tid & 63;
    const int wv   = tid >> 6;

    if constexpr (PHASE <= 2) {
        for (int j = tid; j < 8 * CS; j += 256) (&sacc[0][0])[j] = 0.f;
        __syncthreads();
    }

    const int r = blockIdx.x * 256 + tid;
    float x1[C0];
    layer0_dedup(xyz, P, newxyz, idxf, W0, b0, r, x1);

    if constexpr (PHASE == 0) {
#pragma unroll
        for (int oc = 0; oc < 16; ++oc)
            stats4(x1[4*oc+0], x1[4*oc+1], x1[4*oc+2], x1[4*oc+3], &sacc[wv][8*oc], lane);
    } else {
#pragma unroll
        for (int o = 0; o < C0; ++o)
            x1[o] = fmaxf(0.f, fmaf(x1[o], ss0[o], ss0[64 + o]));

        float y1[C1];
#pragma unroll
        for (int o = 0; o < C1; o += 4) {
            const float4 bv = uld4(b1 + o);
            y1[o] = bv.x; y1[o+1] = bv.y; y1[o+2] = bv.z; y1[o+3] = bv.w;
        }
#pragma unroll 2
        for (int k = 0; k < C0; ++k) {
            const float xk = x1[k];
#pragma unroll
            for (int oc = 0; oc < 16; ++oc) {
                const float4 w4 = uld4(W1 + k * 64 + 4 * oc);
                y1[4*oc+0] = fmaf(xk, w4.x, y1[4*oc+0]);
                y1[4*oc+1] = fmaf(xk, w4.y, y1[4*oc+1]);
                y1[4*oc+2] = fmaf(xk, w4.z, y1[4*oc+2]);
                y1[4*oc+3] = fmaf(xk, w4.w, y1[4*oc+3]);
            }
        }

        if constexpr (PHASE == 1) {
#pragma unroll
            for (int oc = 0; oc < 16; ++oc)
                stats4(y1[4*oc+0], y1[4*oc+1], y1[4*oc+2], y1[4*oc+3], &sacc[wv][8*oc], lane);
        } else {
#pragma unroll
            for (int o = 0; o < C1; ++o)
                y1[o] = fmaxf(0.f, fmaf(y1[o], ss1[o], ss1[64 + o]));

            float a2[C2];
#pragma unroll
            for (int o = 0; o < C2; o += 4) {
                const float4 bv = uld4(b2 + o);
                a2[o] = bv.x; a2[o+1] = bv.y; a2[o+2] = bv.z; a2[o+3] = bv.w;
            }
#pragma unroll 2
            for (int k = 0; k < C1; ++k) {
                const float xk = y1[k];
#pragma unroll
                for (int o = 0; o < C2; o += 4) {
                    const float4 w4 = uld4(W2 + k * C2 + o);
                    a2[o+0] = fmaf(xk, w4.x, a2[o+0]);
                    a2[o+1] = fmaf(xk, w4.y, a2[o+1]);
                    a2[o+2] = fmaf(xk, w4.z, a2[o+2]);
                    a2[o+3] = fmaf(xk, w4.w, a2[o+3]);
                }
            }

            if constexpr (PHASE == 2) {
#pragma unroll
                for (int o = 0; o < C2; ++o) {
                    const float s = dpp_sum64(a2[o]);
                    const float q = dpp_sum64(a2[o] * a2[o]);
                    if (lane == 63) { sacc[wv][2*o] += s; sacc[wv][2*o+1] += q; }
                }
            } else {
                const int g = r >> 5;
#pragma unroll
                for (int o = 0; o < C2; ++o) {
                    float v = fmaxf(0.f, fmaf(a2[o], ss2[o], ss2[C2 + o]));
                    v = dpp_max32(v);
                    if (lane == 31 || lane == 63) out_np[(size_t)g * C2 + o] = v;
                }
            }
        }
    }

    if constexpr (PHASE <= 2) {
        __syncthreads();
        for (int j = tid; j < 2 * CS; j += 256)
            atomicAdd(&gstats[j], sacc[0][j] + sacc[1][j] + sacc[2][j] + sacc[3][j]);
    }
}

// ---------------------------------------------------------------------------
// Pass 1 + store pre-BN y1 as bf16 (Y-tier).
// ---------------------------------------------------------------------------
__global__ __launch_bounds__(256, 2) void pass1Y_kernel(
    const float* __restrict__ xyz, const float* __restrict__ P,
    const float* __restrict__ newxyz, const float* __restrict__ idxf,
    const float* __restrict__ W0, const float* __restrict__ b0,
    const float* __restrict__ W1, const float* __restrict__ b1,
    const float* __restrict__ ss0,
    float* __restrict__ gstats, unsigned short* __restrict__ y1b)
{
    __shared__ float sacc[4][2 * C0];

    const int tid  = threadIdx.x;
    const int lane = tid & 63;
    const int wv   = tid >> 6;

    for (int j = tid; j < 8 * C0; j += 256) (&sacc[0][0])[j] = 0.f;
    __syncthreads();

    const int r = blockIdx.x * 256 + tid;
    float x1[C0];
    layer0_dedup(xyz, P, newxyz, idxf, W0, b0, r, x1);
#pragma unroll
    for (int o = 0; o < C0; ++o)
        x1[o] = fmaxf(0.f, fmaf(x1[o], ss0[o], ss0[64 + o]));

    float y1[C1];
#pragma unroll
    for (int o = 0; o < C1; o += 4) {
        const float4 bv = uld4(b1 + o);
        y1[o] = bv.x; y1[o+1] = bv.y; y1[o+2] = bv.z; y1[o+3] = bv.w;
    }
#pragma unroll 2
    for (int k = 0; k < C0; ++k) {
        const float xk = x1[k];
#pragma unroll
        for (int oc = 0; oc < 16; ++oc) {
            const float4 w4 = uld4(W1 + k * 64 + 4 * oc);
            y1[4*oc+0] = fmaf(xk, w4.x, y1[4*oc+0]);
            y1[4*oc+1] = fmaf(xk, w4.y, y1[4*oc+1]);
            y1[4*oc+2] = fmaf(xk, w4.z, y1[4*oc+2]);
            y1[4*oc+3] = fmaf(xk, w4.w, y1[4*oc+3]);
        }
    }

#pragma unroll
    for (int oc = 0; oc < 16; ++oc)
        stats4(y1[4*oc+0], y1[4*oc+1], y1[4*oc+2], y1[4*oc+3], &sacc[wv][8*oc], lane);

    // store pre-BN y1 as bf16 (8 x 16B per row)
    uint4* yo = (uint4*)(y1b + (size_t)r * 64);
#pragma unroll
    for (int gq = 0; gq < 8; ++gq) {
        union { unsigned short u[8]; uint4 v; } pk;
#pragma unroll
        for (int e = 0; e < 8; ++e) pk.u[e] = f2bf(y1[8*gq+e]);
        yo[gq] = pk.v;
    }

    __syncthreads();
    for (int j = tid; j < 2 * C0; j += 256)
        atomicAdd(&gstats[j], sacc[0][j] + sacc[1][j] + sacc[2][j] + sacc[3][j]);
}

// ---------------------------------------------------------------------------
// Y-tier phase 2: load y1 (bf16), bn1+relu, L2, stats2 + per-group min/max.
// ---------------------------------------------------------------------------
__global__ __launch_bounds__(256, 2) void p2Y_kernel(
    const unsigned short* __restrict__ y1b,
    const float* __restrict__ W2, const float* __restrict__ b2,
    const float* __restrict__ ss1,
    float* __restrict__ gstats, float* __restrict__ mnmx)
{
    __shared__ float sacc[4][2 * C2];

    const int tid  = threadIdx.x;
    const int lane = tid & 63;
    const int wv   = tid >> 6;

    for (int j = tid; j < 8 * C2; j += 256) (&sacc[0][0])[j] = 0.f;
    __syncthreads();

    const int r = blockIdx.x * 256 + tid;

    float y1[C1];
    {
        const uint4* yi = (const uint4*)(y1b + (size_t)r * 64);
#pragma unroll
        for (int gq = 0; gq < 8; ++gq) {
            union { uint4 v; unsigned short u[8]; } pk;
            pk.v = yi[gq];
#pragma unroll
            for (int e = 0; e < 8; ++e)
                y1[8*gq+e] = bf2f(pk.u[e]);
        }
    }
#pragma unroll
    for (int o = 0; o < C1; ++o)
        y1[o] = fmaxf(0.f, fmaf(y1[o], ss1[o], ss1[64 + o]));

    float a2[C2];
#pragma unroll
    for (int o = 0; o < C2; o += 4) {
        const float4 bv = uld4(b2 + o);
        a2[o] = bv.x; a2[o+1] = bv.y; a2[o+2] = bv.z; a2[o+3] = bv.w;
    }
#pragma unroll 2
    for (int k = 0; k < C1; ++k) {
        const float xk = y1[k];
#pragma unroll
        for (int o = 0; o < C2; o += 4) {
            const float4 w4 = uld4(W2 + k * C2 + o);
            a2[o+0] = fmaf(xk, w4.x, a2[o+0]);
            a2[o+1] = fmaf(xk, w4.y, a2[o+1]);
            a2[o+2] = fmaf(xk, w4.z, a2[o+2]);
            a2[o+3] = fmaf(xk, w4.w, a2[o+3]);
        }
    }

    const int gbase = blockIdx.x * 8 + 2 * wv;
    float* mb = mnmx + ((size_t)gbase + (lane >> 5)) * 256;
#pragma unroll
    for (int o = 0; o < C2; ++o) {
        const float v = a2[o];
        const float s = dpp_sum64(v);
        const float q = dpp_sum64(v * v);
        const float mn = dpp_min32(v);
        const float mx = dpp_max32(v);
        if (lane == 63) { sacc[wv][2*o] += s; sacc[wv][2*o+1] += q; }
        if (lane == 31 || lane == 63) { mb[o] = mn; mb[128 + o] = mx; }
    }

    __syncthreads();
    for (int j = tid; j < 2 * C2; j += 256)
        atomicAdd(&gstats[j], sacc[0][j] + sacc[1][j] + sacc[2][j] + sacc[3][j]);
}

// ---------------------------------------------------------------------------
// Phase 2 + per-group min/max, recompute variant (MM-tier).
// ---------------------------------------------------------------------------
__global__ __launch_bounds__(256, 2) void passP2mm_kernel(
    const float* __restrict__ xyz, const float* __restrict__ P,
    const float* __restrict__ newxyz, const float* __restrict__ idxf,
    const float* __restrict__ W0, const float* __restrict__ b0,
    const float* __restrict__ W1, const float* __restrict__ b1,
    const float* __restrict__ W2, const float* __restrict__ b2,
    const float* __restrict__ ss0, const float* __restrict__ ss1,
    float* __restrict__ gstats, float* __restrict__ mnmx)
{
    __shared__ float sacc[4][2 * C2];

    const int tid  = threadIdx.x;
    const int lane = tid & 63;
    const int wv   = tid >> 6;

    for (int j = tid; j < 8 * C2; j += 256) (&sacc[0][0])[j] = 0.f;
    __syncthreads();

    const int r = blockIdx.x * 256 + tid;
    float x1[C0];
    layer0_dedup(xyz, P, newxyz, idxf, W0, b0, r, x1);
#pragma unroll
    for (int o = 0; o < C0; ++o)
        x1[o] = fmaxf(0.f, fmaf(x1[o], ss0[o], ss0[64 + o]));

    float y1[C1];
#pragma unroll
    for (int o = 0; o < C1; o += 4) {
        const float4 bv = uld4(b1 + o);
        y1[o] = bv.x; y1[o+1] = bv.y; y1[o+2] = bv.z; y1[o+3] = bv.w;
    }
#pragma unroll 2
    for (int k = 0; k < C0; ++k) {
        const float xk = x1[k];
#pragma unroll
        for (int oc = 0; oc < 16; ++oc) {
            const float4 w4 = uld4(W1 + k * 64 + 4 * oc);
            y1[4*oc+0] = fmaf(xk, w4.x, y1[4*oc+0]);
            y1[4*oc+1] = fmaf(xk, w4.y, y1[4*oc+1]);
            y1[4*oc+2] = fmaf(xk, w4.z, y1[4*oc+2]);
            y1[4*oc+3] = fmaf(xk, w4.w, y1[4*oc+3]);
        }
    }
#pragma unroll
    for (int o = 0; o < C1; ++o)
        y1[o] = fmaxf(0.f, fmaf(y1[o], ss1[o], ss1[64 + o]));

    float a2[C2];
#pragma unroll
    for (int o = 0; o < C2; o += 4) {
        const float4 bv = uld4(b2 + o);
        a2[o] = bv.x; a2[o+1] = bv.y; a2[o+2] = bv.z; a2[o+3] = bv.w;
    }
#pragma unroll 2
    for (int k = 0; k < C1; ++k) {
        const float xk = y1[k];
#pragma unroll
        for (int o = 0; o < C2; o += 4) {
            const float4 w4 = uld4(W2 + k * C2 + o);
            a2[o+0] = fmaf(xk, w4.x, a2[o+0]);
            a2[o+1] = fmaf(xk, w4.y, a2[o+1]);
            a2[o+2] = fmaf(xk, w4.z, a2[o+2]);
            a2[o+3] = fmaf(xk, w4.w, a2[o+3]);
        }
    }

    const int gbase = blockIdx.x * 8 + 2 * wv;
    float* mb = mnmx + ((size_t)gbase + (lane >> 5)) * 256;
#pragma unroll
    for (int o = 0; o < C2; ++o) {
        const float v = a2[o];
        const float s = dpp_sum64(v);
        const float q = dpp_sum64(v * v);
        const float mn = dpp_min32(v);
        const float mx = dpp_max32(v);
        if (lane == 63) { sacc[wv][2*o] += s; sacc[wv][2*o+1] += q; }
        if (lane == 31 || lane == 63) { mb[o] = mn; mb[128 + o] = mx; }
    }

    __syncthreads();
    for (int j = tid; j < 2 * C2; j += 256)
        atomicAdd(&gstats[j], sacc[0][j] + sacc[1][j] + sacc[2][j] + sacc[3][j]);
}

// ---------------------------------------------------------------------------
// Finalize: out[g,o] = relu(sc>=0 ? sc*max+sh : sc*min+sh).
// ---------------------------------------------------------------------------
__global__ __launch_bounds__(256) void fin_kernel(const float* __restrict__ mnmx,
                                                  const float* __restrict__ ss2,
                                                  float* __restrict__ out_np)
{
    const int t = blockIdx.x * 256 + threadIdx.x;
    const int g = t >> 7;
    const int o = t & 127;
    const float sc = ss2[o], sh = ss2[C2 + o];
    const float y  = (sc >= 0.f) ? mnmx[(size_t)g * 256 + 128 + o]
                                 : mnmx[(size_t)g * 256 + o];
    out_np[t] = fmaxf(0.f, fmaf(y, sc, sh));
}

// ---------------------------------------------------------------------------
// Fallback recompute pass (round-2 proven): used when ws_size < 16 MB.
// ---------------------------------------------------------------------------
template<int PHASE>
__global__ __launch_bounds__(128) void pass_kernel(
    const float* __restrict__ xyz, const float* __restrict__ points,
    const float* __restrict__ newxyz, const float* __restrict__ idxf,
    const float* __restrict__ W0, const float* __restrict__ b0,
    const float* __restrict__ W1, const float* __restrict__ b1,
    const float* __restrict__ W2, const float* __restrict__ b2,
    const float* __restrict__ ss0, const float* __restrict__ ss1,
    const float* __restrict__ ss2,
    float* __restrict__ gstats, float* __restrict__ out_np)
{
    constexpr int CS = (PHASE == 2) ? C2 : C0;
    __shared__ float xld[(PHASE >= 1) ? (64 * 128) : 1];
    __shared__ float sacc[2][2 * CS];

    const int tid  = threadIdx.x;
    const int lane = tid & 63;
    const int wv   = tid >> 6;

    if constexpr (PHASE <= 2) {
        for (int j = tid; j < 2 * 2 * CS; j += 128) (&sacc[0][0])[j] = 0.f;
        __syncthreads();
    }

    const int r  = blockIdx.x * 128 + tid;
    const int i  = (int)idxf[r];
    const int bb = r >> 15;
    const int pp = (r >> 5) & 1023;

    float x[CIN0];
    {
        const float* pz = xyz + ((size_t)bb * NPTS + i) * 3;
        const float* nz = newxyz + ((size_t)bb * NPOINTS + pp) * 3;
        x[0] = pz[0] - nz[0];
        x[1] = pz[1] - nz[1];
        x[2] = pz[2] - nz[2];
        const float4* p4 = (const float4*)(points + ((size_t)bb * NPTS + i) * 64);
#pragma unroll
        for (int j = 0; j < 16; ++j) {
            const float4 v = p4[j];
            x[3+4*j+0] = v.x; x[3+4*j+1] = v.y; x[3+4*j+2] = v.z; x[3+4*j+3] = v.w;
        }
    }

#pragma unroll 1
    for (int oc = 0; oc < 16; ++oc) {
        const float4 bv = uld4(b0 + 4*oc);
        float a0 = bv.x, a1 = bv.y, a2 = bv.z, a3 = bv.w;
#pragma unroll
        for (int k = 0; k < CIN0; ++k) {
            const float4 w4 = uld4(W0 + k*64 + 4*oc);
            a0 = fmaf(x[k], w4.x, a0); a1 = fmaf(x[k], w4.y, a1);
            a2 = fmaf(x[k], w4.z, a2); a3 = fmaf(x[k], w4.w, a3);
        }
        if constexpr (PHASE == 0) {
            stats4(a0, a1, a2, a3, &sacc[wv][8*oc], lane);
        } else {
            xld[(4*oc+0)*128 + tid] = fmaxf(0.f, fmaf(a0, ss0[4*oc+0], ss0[64+4*oc+0]));
            xld[(4*oc+1)*128 + tid] = fmaxf(0.f, fmaf(a1, ss0[4*oc+1], ss0[64+4*oc+1]));
            xld[(4*oc+2)*128 + tid] = fmaxf(0.f, fmaf(a2, ss0[4*oc+2], ss0[64+4*oc+2]));
            xld[(4*oc+3)*128 + tid] = fmaxf(0.f, fmaf(a3, ss0[4*oc+3], ss0[64+4*oc+3]));
        }
    }

    if constexpr (PHASE == 1) {
#pragma unroll 1
        for (int oc = 0; oc < 16; ++oc) {
            const float4 bv = uld4(b1 + 4*oc);
            float a0 = bv.x, a1 = bv.y, a2 = bv.z, a3 = bv.w;
#pragma unroll
            for (int k = 0; k < 64; ++k) {
                const float xk = xld[k*128 + tid];
                const float4 w4 = uld4(W1 + k*64 + 4*oc);
                a0 = fmaf(xk, w4.x, a0); a1 = fmaf(xk, w4.y, a1);
                a2 = fmaf(xk, w4.z, a2); a3 = fmaf(xk, w4.w, a3);
            }
            stats4(a0, a1, a2, a3, &sacc[wv][8*oc], lane);
        }
    }

    if constexpr (PHASE >= 2) {
        float acc2[C2];
#pragma unroll
        for (int o = 0; o < C2; o += 4) {
            const float4 bv = uld4(b2 + o);
            acc2[o] = bv.x; acc2[o+1] = bv.y; acc2[o+2] = bv.z; acc2[o+3] = bv.w;
        }
#pragma unroll 1
        for (int oc = 0; oc < 16; ++oc) {
            const float4 bv = uld4(b1 + 4*oc);
            float a0 = bv.x, a1 = bv.y, a2 = bv.z, a3 = bv.w;
#pragma unroll
            for (int k = 0; k < 64; ++k) {
                const float xk = xld[k*128 + tid];
                const float4 w4 = uld4(W1 + k*64 + 4*oc);
                a0 = fmaf(xk, w4.x, a0); a1 = fmaf(xk, w4.y, a1);
                a2 = fmaf(xk, w4.z, a2); a3 = fmaf(xk, w4.w, a3);
            }
            const float xc0 = fmaxf(0.f, fmaf(a0, ss1[4*oc+0], ss1[64+4*oc+0]));
            const float xc1 = fmaxf(0.f, fmaf(a1, ss1[4*oc+1], ss1[64+4*oc+1]));
            const float xc2 = fmaxf(0.f, fmaf(a2, ss1[4*oc+2], ss1[64+4*oc+2]));
            const float xc3 = fmaxf(0.f, fmaf(a3, ss1[4*oc+3], ss1[64+4*oc+3]));
#pragma unroll
            for (int o = 0; o < C2; o += 4) {
                const float4 wA = uld4(W2 + (4*oc+0)*C2 + o);
                const float4 wB = uld4(W2 + (4*oc+1)*C2 + o);
                const float4 wC = uld4(W2 + (4*oc+2)*C2 + o);
                const float4 wD = uld4(W2 + (4*oc+3)*C2 + o);
                acc2[o+0] = fmaf(xc0, wA.x, fmaf(xc1, wB.x, fmaf(xc2, wC.x, fmaf(xc3, wD.x, acc2[o+0]))));
                acc2[o+1] = fmaf(xc0, wA.y, fmaf(xc1, wB.y, fmaf(xc2, wC.y, fmaf(xc3, wD.y, acc2[o+1]))));
                acc2[o+2] = fmaf(xc0, wA.z, fmaf(xc1, wB.z, fmaf(xc2, wC.z, fmaf(xc3, wD.z, acc2[o+2]))));
                acc2[o+3] = fmaf(xc0, wA.w, fmaf(xc1, wB.w, fmaf(xc2, wC.w, fmaf(xc3, wD.w, acc2[o+3]))));
            }
        }

        if constexpr (PHASE == 2) {
#pragma unroll
            for (int o = 0; o < C2; ++o) {
                const float s = dpp_sum64(acc2[o]);
                const float q = dpp_sum64(acc2[o] * acc2[o]);
                if (lane == 63) { sacc[wv][2*o] += s; sacc[wv][2*o+1] += q; }
            }
        } else {
            const int g = r >> 5;
#pragma unroll
            for (int o = 0; o < C2; ++o) {
                float v = fmaxf(0.f, fmaf(acc2[o], ss2[o], ss2[C2+o]));
                v = dpp_max32(v);
                if (lane == 31 || lane == 63) out_np[(size_t)g * C2 + o] = v;
            }
        }
    }

    if constexpr (PHASE <= 2) {
        __syncthreads();
        for (int j = tid; j < 2 * CS; j += 128)
            atomicAdd(&gstats[j], sacc[0][j] + sacc[1][j]);
    }
}

// ---------------------------------------------------------------------------
// BN scale/shift from raw sums.
// ---------------------------------------------------------------------------
template<int C>
__global__ void ss_kernel(const float* __restrict__ gs, const float* __restrict__ g,
                          const float* __restrict__ be, float* __restrict__ ss)
{
    const int o = threadIdx.x;
    const float inv  = 1.0f / (float)MROWS;
    const float mean = gs[2*o] * inv;
    const float var  = fmaxf(0.f, gs[2*o+1] * inv - mean * mean);
    const float sc   = g[o] / sqrtf(var + BN_EPS);
    ss[o]     = sc;
    ss[C + o] = fmaf(-mean, sc, be[o]);
}

__global__ void zero_kernel(float* __restrict__ p) { p[threadIdx.x] = 0.f; }

extern "C" void kernel_launch(void* const* d_in, const int* in_sizes, int n_in,
                              void* d_out, int out_size, void* d_ws, size_t ws_size,
                              hipStream_t stream)
{
    (void)in_sizes; (void)n_in; (void)out_size;
    const float* xyz    = (const float*)d_in[0];
    const float* points = (const float*)d_in[1];
    const float* W0  = (const float*)d_in[2];
    const float* b0  = (const float*)d_in[3];
    const float* g0  = (const float*)d_in[4];
    const float* be0 = (const float*)d_in[5];
    const float* W1  = (const float*)d_in[6];
    const float* b1  = (const float*)d_in[7];
    const float* g1  = (const float*)d_in[8];
    const float* be1 = (const float*)d_in[9];
    const float* W2  = (const float*)d_in[10];
    const float* b2  = (const float*)d_in[11];
    const float* g2  = (const float*)d_in[12];
    const float* be2 = (const float*)d_in[13];

    float* out = (float*)d_out;
    float* out_newxyz = out;                                    // 16*1024*3
    float* out_newpts = out + (size_t)NB * NPOINTS * 3;         // 16*1024*128
    float* out_idx    = out_newpts + (size_t)NB * NPOINTS * C2; // 16*1024*32 (float idx)

    float* wsf = (float*)d_ws;
    float* gs0 = wsf + 0;    // 128
    float* gs1 = wsf + 128;  // 128
    float* gs2 = wsf + 256;  // 256
    float* ss0 = wsf + 512;  // 128
    float* ss1 = wsf + 640;  // 128
    float* ss2 = wsf + 768;  // 256
    const size_t PBYTES  = (size_t)NB * NPTS * C0 * 4;            // 16 MB
    const size_t MMBYTES = (size_t)NB * NPOINTS * 2 * C2 * 4;     // 16 MB
    const size_t YBYTES  = MROWS * C1 * 2;                        // 64 MB (bf16)
    float* P    = (float*)((char*)d_ws + 65536);
    float* mnmx = (float*)((char*)d_ws + 65536 + PBYTES);
    unsigned short* y1b = (unsigned short*)((char*)d_ws + 65536 + PBYTES + MMBYTES);

    const bool haveP  = ws_size >= (65536 + PBYTES);
    const bool haveMM = ws_size >= (65536 + PBYTES + MMBYTES);
    const bool haveY  = ws_size >= (65536 + PBYTES + MMBYTES + YBYTES);

    zero_kernel<<<1, 512, 0, stream>>>(wsf);
    fps_kernel<<<NB, 512, 0, stream>>>(xyz, out_newxyz);
    ball_kernel<<<(NB * NPOINTS) / 4, 256, 0, stream>>>(xyz, out_newxyz, out_idx);

    if (haveP) {
        const int grid = (int)(MROWS / 256);  // 2048
        preP_kernel<<<NB * NPTS / 256, 256, 0, stream>>>(points, W0, P);
        passP_kernel<0><<<grid, 256, 0, stream>>>(xyz, P, out_newxyz, out_idx,
                                                  W0, b0, W1, b1, W2, b2,
                                                  ss0, ss1, ss2, gs0, nullptr);
        ss_kernel<C0><<<1, C0, 0, stream>>>(gs0, g0, be0, ss0);
        if (haveY) {
            pass1Y_kernel<<<grid, 256, 0, stream>>>(xyz, P, out_newxyz, out_idx,
                                                    W0, b0, W1, b1, ss0, gs1, y1b);
            ss_kernel<C1><<<1, C1, 0, stream>>>(gs1, g1, be1, ss1);
            p2Y_kernel<<<grid, 256, 0, stream>>>(y1b, W2, b2, ss1, gs2, mnmx);
            ss_kernel<C2><<<1, C2, 0, stream>>>(gs2, g2, be2, ss2);
            fin_kernel<<<NB * NPOINTS * C2 / 256, 256, 0, stream>>>(mnmx, ss2, out_newpts);
        } else if (haveMM) {
            passP_kernel<1><<<grid, 256, 0, stream>>>(xyz, P, out_newxyz, out_idx,
                                                      W0, b0, W1, b1, W2, b2,
                                                      ss0, ss1, ss2, gs1, nullptr);
            ss_kernel<C1><<<1, C1, 0, stream>>>(gs1, g1, be1, ss1);
            passP2mm_kernel<<<grid, 256, 0, stream>>>(xyz, P, out_newxyz, out_idx,
                                                      W0, b0, W1, b1, W2, b2,
                                                      ss0, ss1, gs2, mnmx);
            ss_kernel<C2><<<1, C2, 0, stream>>>(gs2, g2, be2, ss2);
            fin_kernel<<<NB * NPOINTS * C2 / 256, 256, 0, stream>>>(mnmx, ss2, out_newpts);
        } else {
            passP_kernel<1><<<grid, 256, 0, stream>>>(xyz, P, out_newxyz, out_idx,
                                                      W0, b0, W1, b1, W2, b2,
                                                      ss0, ss1, ss2, gs1, nullptr);
            ss_kernel<C1><<<1, C1, 0, stream>>>(gs1, g1, be1, ss1);
            passP_kernel<2><<<grid, 256, 0, stream>>>(xyz, P, out_newxyz, out_idx,
                                                      W0, b0, W1, b1, W2, b2,
                                                      ss0, ss1, ss2, gs2, nullptr);
            ss_kernel<C2><<<1, C2, 0, stream>>>(gs2, g2, be2, ss2);
            passP_kernel<3><<<grid, 256, 0, stream>>>(xyz, P, out_newxyz, out_idx,
                                                      W0, b0, W1, b1, W2, b2,
                                                      ss0, ss1, ss2, nullptr, out_newpts);
        }
    } else {
        const int grid = (int)(MROWS / 128);  // 4096
        pass_kernel<0><<<grid, 128, 0, stream>>>(xyz, points, out_newxyz, out_idx,
                                                 W0, b0, W1, b1, W2, b2,
                                                 ss0, ss1, ss2, gs0, nullptr);
        ss_kernel<C0><<<1, C0, 0, stream>>>(gs0, g0, be0, ss0);
        pass_kernel<1><<<grid, 128, 0, stream>>>(xyz, points, out_newxyz, out_idx,
                                                 W0, b0, W1, b1, W2, b2,
                                                 ss0, ss1, ss2, gs1, nullptr);
        ss_kernel<C1><<<1, C1, 0, stream>>>(gs1, g1, be1, ss1);
        pass_kernel<2><<<grid, 128, 0, stream>>>(xyz, points, out_newxyz, out_idx,
                                                 W0, b0, W1, b1, W2, b2,
                                                 ss0, ss1, ss2, gs2, nullptr);
        ss_kernel<C2><<<1, C2, 0, stream>>>(gs2, g2, be2, ss2);
        pass_kernel<3><<<grid, 128, 0, stream>>>(xyz, points, out_newxyz, out_idx,
                                                 W0, b0, W1, b1, W2, b2,
                                                 ss0, ss1, ss2, nullptr, out_newpts);
    }
}

// Round 7
// 1227.445 us; speedup vs baseline: 2.5889x; 1.0481x over previous
//
#include <hip/hip_runtime.h>

static constexpr int NB      = 16;
static constexpr int NPTS    = 4096;
static constexpr int NPOINTS = 1024;
static constexpr int NSAMP   = 32;
static constexpr int CIN0    = 67;   // 3 + 64
static constexpr int C0      = 64;
static constexpr int C1      = 64;
static constexpr int C2      = 128;
static constexpr size_t MROWS = (size_t)NB * NPOINTS * NSAMP; // 524288
#define RAD2 0.16f
#define BN_EPS 0.001f

__device__ __forceinline__ float4 uld4(const float* __restrict__ p) {
    return *(const float4* __restrict__)p;
}

// bf16 RNE pack/unpack (self-contained)
__device__ __forceinline__ unsigned short f2bf(float f) {
    const unsigned u = __float_as_uint(f);
    return (unsigned short)((u + 0x7fffu + ((u >> 16) & 1u)) >> 16);
}
__device__ __forceinline__ float bf2f(unsigned short h) {
    return __uint_as_float((unsigned)h << 16);
}

// ---- DPP helpers (VALU pipe) ----------------------------------------------
template<int CTRL>
__device__ __forceinline__ float dppf(float v) {
    return __int_as_float(__builtin_amdgcn_update_dpp(0, __float_as_int(v),
                                                      CTRL, 0xF, 0xF, false));
}
template<int CTRL>
__device__ __forceinline__ float dpps(float v) {
    return __int_as_float(__builtin_amdgcn_update_dpp(__float_as_int(v), __float_as_int(v),
                                                      CTRL, 0xF, 0xF, false));
}
__device__ __forceinline__ float dpp_sum64(float v) {
    v += dppf<0x111>(v); v += dppf<0x112>(v); v += dppf<0x114>(v); v += dppf<0x118>(v);
    v += dppf<0x142>(v); v += dppf<0x143>(v);
    return v;   // lane 63
}
// 16-lane partial sums; valid at lanes 15, 31, 47, 63
__device__ __forceinline__ float dpp_psum16(float v) {
    v += dppf<0x111>(v); v += dppf<0x112>(v); v += dppf<0x114>(v); v += dppf<0x118>(v);
    return v;
}
__device__ __forceinline__ float dpp_max32(float v) {
    v = fmaxf(v, dpps<0x111>(v)); v = fmaxf(v, dpps<0x112>(v));
    v = fmaxf(v, dpps<0x114>(v)); v = fmaxf(v, dpps<0x118>(v));
    v = fmaxf(v, dpps<0x142>(v));
    return v;   // lanes 31, 63
}
__device__ __forceinline__ float dpp_min32(float v) {
    v = fminf(v, dpps<0x111>(v)); v = fminf(v, dpps<0x112>(v));
    v = fminf(v, dpps<0x114>(v)); v = fminf(v, dpps<0x118>(v));
    v = fminf(v, dpps<0x142>(v));
    return v;   // lanes 31, 63
}
// u64-key argmax step: key = (f32bits(d) << 32) | (4095 - idx)
template<int CTRL>
__device__ __forceinline__ void kstep(unsigned long long& k) {
    const unsigned hi = (unsigned)(k >> 32);
    const unsigned lo = (unsigned)(k & 0xffffffffull);
    const unsigned ohi = (unsigned)__builtin_amdgcn_update_dpp((int)hi, (int)hi, CTRL, 0xF, 0xF, false);
    const unsigned olo = (unsigned)__builtin_amdgcn_update_dpp((int)lo, (int)lo, CTRL, 0xF, 0xF, false);
    const unsigned long long ok = ((unsigned long long)ohi << 32) | olo;
    if (ok > k) k = ok;
}

// ---------------------------------------------------------------------------
// FPS v5 (unchanged structure; near its structural floor ~1500 cyc/iter).
// Block 16 zeroes the stats workspace (folded launch).
// ---------------------------------------------------------------------------
__global__ __launch_bounds__(512) void fps_kernel(const float* __restrict__ xyz,
                                                  float* __restrict__ out_newxyz,
                                                  float* __restrict__ wsz)
{
    if (blockIdx.x == NB) {
        for (int i = threadIdx.x; i < 1024; i += 512) wsz[i] = 0.f;
        return;
    }
    __shared__ float sx[NPTS], sy[NPTS], sz[NPTS];
    __shared__ int   sidx[NPOINTS];
    __shared__ __align__(16) unsigned long long redk[2][8];

    const int b    = blockIdx.x;
    const int tid  = threadIdx.x;
    const int lane = tid & 63;
    const int wv   = tid >> 6;

    const float* base = xyz + (size_t)b * NPTS * 3;
    for (int i = tid; i < NPTS; i += 512) {
        sx[i] = base[i * 3 + 0];
        sy[i] = base[i * 3 + 1];
        sz[i] = base[i * 3 + 2];
    }
    __syncthreads();

    float px[8], py[8], pz[8], dd[8];
#pragma unroll
    for (int j = 0; j < 8; ++j) {
        const int i = tid + j * 512;
        px[j] = sx[i]; py[j] = sy[i]; pz[j] = sz[i];
        dd[j] = 1e10f;
    }

    int   far = 0;
    float fx = sx[0], fy = sy[0], fz = sz[0];
#pragma unroll 1
    for (int it = 0; it < NPOINTS; ++it) {
        if (tid == 0) sidx[it] = far;
        float bv = -1.0f; int bi = 0;
#pragma unroll
        for (int j = 0; j < 8; ++j) {
            const float dx = __fsub_rn(px[j], fx);
            const float dy = __fsub_rn(py[j], fy);
            const float dz = __fsub_rn(pz[j], fz);
            const float d  = __fadd_rn(__fadd_rn(__fmul_rn(dx, dx), __fmul_rn(dy, dy)),
                                       __fmul_rn(dz, dz));
            dd[j] = fminf(dd[j], d);
            if (dd[j] > bv) { bv = dd[j]; bi = tid + j * 512; }
        }
        unsigned long long k = ((unsigned long long)__float_as_uint(bv) << 32)
                             | (unsigned)(4095 - bi);
        kstep<0x111>(k);
        kstep<0x112>(k);
        kstep<0x114>(k);
        kstep<0x118>(k);
        kstep<0x142>(k);
        kstep<0x143>(k);

        const int pb = it & 1;
        if (lane == 63) redk[pb][wv] = k;
        __syncthreads();
        unsigned long long ck = redk[pb][0];
#pragma unroll
        for (int w = 1; w < 8; ++w) {
            const unsigned long long ok = redk[pb][w];
            if (ok > ck) ck = ok;
        }
        const int ci = 4095 - (int)(unsigned)(ck & 0xffffffffull);
        far = ci;
        fx = sx[ci]; fy = sy[ci]; fz = sz[ci];
    }
    __syncthreads();
    for (int it = tid; it < NPOINTS; it += 512) {
        const int ii = sidx[it];
        float* o = out_newxyz + ((size_t)b * NPOINTS + it) * 3;
        o[0] = sx[ii]; o[1] = sy[ii]; o[2] = sz[ii];
    }
}

// ---------------------------------------------------------------------------
// Ball query: one wave per center. Ordered first-32 via ballot+prefix popcount.
// ---------------------------------------------------------------------------
__global__ __launch_bounds__(256) void ball_kernel(const float* __restrict__ xyz,
                                                   const float* __restrict__ newxyz,
                                                   float* __restrict__ out_idx_f)
{
    __shared__ int sel[4][NSAMP];
    const int tid  = threadIdx.x;
    const int lane = tid & 63;
    const int widx = tid >> 6;
    const int w = blockIdx.x * 4 + widx;
    const int b = w >> 10;

    const float cx = newxyz[(size_t)w * 3 + 0];
    const float cy = newxyz[(size_t)w * 3 + 1];
    const float cz = newxyz[(size_t)w * 3 + 2];
    const float* base = xyz + (size_t)b * NPTS * 3;

    int total = 0;
    for (int c = 0; c < NPTS / 64 && total < NSAMP; ++c) {
        const int n = c * 64 + lane;
        const float dx = __fsub_rn(cx, base[n * 3 + 0]);
        const float dy = __fsub_rn(cy, base[n * 3 + 1]);
        const float dz = __fsub_rn(cz, base[n * 3 + 2]);
        const float d2 = __fadd_rn(__fadd_rn(__fmul_rn(dx, dx), __fmul_rn(dy, dy)),
                                   __fmul_rn(dz, dz));
        const bool pred = d2 < RAD2;
        const unsigned long long mask = __ballot(pred);
        if (pred) {
            const int pos = total + (int)__popcll(mask & ((1ull << lane) - 1ull));
            if (pos < NSAMP) sel[widx][pos] = n;
        }
        total += (int)__popcll(mask);
    }
    __syncthreads();
    if (lane < NSAMP) {
        const int first = sel[widx][0];
        const int v = (lane < total) ? sel[widx][lane] : first;
        out_idx_f[(size_t)w * NSAMP + lane] = (float)v;
    }
}

// ---------------------------------------------------------------------------
// Quad-slot stats: 16-lane partial sums, writers at lanes 15/31/47/63 into
// slot (wv*4 + lane/16). ~19 ops/ch vs 27 for the 6-step full-wave reduce.
// ---------------------------------------------------------------------------
__device__ __forceinline__ void stats4q(float a0, float a1, float a2, float a3,
                                        float* sa, bool wr)
{
    float q0 = a0*a0, q1 = a1*a1, q2 = a2*a2, q3 = a3*a3;
    a0 = dpp_psum16(a0); q0 = dpp_psum16(q0);
    a1 = dpp_psum16(a1); q1 = dpp_psum16(q1);
    a2 = dpp_psum16(a2); q2 = dpp_psum16(q2);
    a3 = dpp_psum16(a3); q3 = dpp_psum16(q3);
    if (wr) {
        sa[0] += a0; sa[1] += q0; sa[2] += a1; sa[3] += q1;
        sa[4] += a2; sa[5] += q2; sa[6] += a3; sa[7] += q3;
    }
}

// legacy full-wave stats (fallback tiers)
__device__ __forceinline__ void stats4(float a0, float a1, float a2, float a3,
                                       float* sa, int lane)
{
    float q0 = a0*a0, q1 = a1*a1, q2 = a2*a2, q3 = a3*a3;
    a0 = dpp_sum64(a0); q0 = dpp_sum64(q0);
    a1 = dpp_sum64(a1); q1 = dpp_sum64(q1);
    a2 = dpp_sum64(a2); q2 = dpp_sum64(q2);
    a3 = dpp_sum64(a3); q3 = dpp_sum64(q3);
    if (lane == 63) {
        sa[0] += a0; sa[1] += q0; sa[2] += a1; sa[3] += q1;
        sa[4] += a2; sa[5] += q2; sa[6] += a3; sa[7] += q3;
    }
}

// ---------------------------------------------------------------------------
// P precompute: P[b,n,:] = points[b,n,:] . W0[3:,:]
// ---------------------------------------------------------------------------
__global__ __launch_bounds__(256) void preP_kernel(const float* __restrict__ points,
                                                   const float* __restrict__ W0,
                                                   float* __restrict__ P)
{
    const int r = blockIdx.x * 256 + threadIdx.x;
    const float4* pr = (const float4*)(points + (size_t)r * 64);
    float x[64];
#pragma unroll
    for (int j = 0; j < 16; ++j) {
        const float4 v = pr[j];
        x[4*j+0] = v.x; x[4*j+1] = v.y; x[4*j+2] = v.z; x[4*j+3] = v.w;
    }
    float acc[64];
#pragma unroll
    for (int o = 0; o < 64; ++o) acc[o] = 0.f;
#pragma unroll 2
    for (int k = 0; k < 64; ++k) {
        const float xk = x[k];
#pragma unroll
        for (int oc = 0; oc < 16; ++oc) {
            const float4 w4 = uld4(W0 + (3 + k) * 64 + 4 * oc);
            acc[4*oc+0] = fmaf(xk, w4.x, acc[4*oc+0]);
            acc[4*oc+1] = fmaf(xk, w4.y, acc[4*oc+1]);
            acc[4*oc+2] = fmaf(xk, w4.z, acc[4*oc+2]);
            acc[4*oc+3] = fmaf(xk, w4.w, acc[4*oc+3]);
        }
    }
    float4* po = (float4*)(P + (size_t)r * 64);
#pragma unroll
    for (int oc = 0; oc < 16; ++oc)
        po[oc] = make_float4(acc[4*oc+0], acc[4*oc+1], acc[4*oc+2], acc[4*oc+3]);
}

// ---------------------------------------------------------------------------
// Shared body: gather + deduped layer 0 (pre-BN y0 into x1[64]).
// ---------------------------------------------------------------------------
__device__ __forceinline__ void layer0_dedup(
    const float* __restrict__ xyz, const float* __restrict__ P,
    const float* __restrict__ newxyz, const float* __restrict__ idxf,
    const float* __restrict__ W0, const float* __restrict__ b0,
    int r, float* x1)
{
    const int i  = (int)idxf[r];
    const int bb = r >> 15;
    const int pp = (r >> 5) & 1023;
    const float* pz = xyz + ((size_t)bb * NPTS + i) * 3;
    const float* nz = newxyz + ((size_t)bb * NPOINTS + pp) * 3;
    const float r0 = pz[0] - nz[0];
    const float r1 = pz[1] - nz[1];
    const float r2 = pz[2] - nz[2];
    const float4* prow = (const float4*)(P + ((size_t)bb * NPTS + i) * 64);
#pragma unroll
    for (int oc = 0; oc < 16; ++oc) {
        const float4 pv = prow[oc];
        const float4 bv = uld4(b0 + 4 * oc);
        const float4 wa = uld4(W0 + 0 * 64 + 4 * oc);
        const float4 wb = uld4(W0 + 1 * 64 + 4 * oc);
        const float4 wc = uld4(W0 + 2 * 64 + 4 * oc);
        x1[4*oc+0] = fmaf(r0, wa.x, fmaf(r1, wb.x, fmaf(r2, wc.x, bv.x + pv.x)));
        x1[4*oc+1] = fmaf(r0, wa.y, fmaf(r1, wb.y, fmaf(r2, wc.y, bv.y + pv.y)));
        x1[4*oc+2] = fmaf(r0, wa.z, fmaf(r1, wb.z, fmaf(r2, wc.z, bv.z + pv.z)));
        x1[4*oc+3] = fmaf(r0, wa.w, fmaf(r1, wb.w, fmaf(r2, wc.w, bv.w + pv.w)));
    }
}

// ---------------------------------------------------------------------------
// Pass 0: stats of y0 only. High occupancy (4 waves/EU), quad-slot stats.
// ---------------------------------------------------------------------------
__global__ __launch_bounds__(256, 4) void pass0_kernel(
    const float* __restrict__ xyz, const float* __restrict__ P,
    const float* __restrict__ newxyz, const float* __restrict__ idxf,
    const float* __restrict__ W0, const float* __restrict__ b0,
    float* __restrict__ gstats)
{
    __shared__ float sacc[16][2 * C0];
    const int tid  = threadIdx.x;
    const int lane = tid & 63;
    const int wv   = tid >> 6;
    const int slot = wv * 4 + (lane >> 4);
    const bool wr  = (lane & 15) == 15;

    for (int j = tid; j < 16 * 2 * C0; j += 256) (&sacc[0][0])[j] = 0.f;
    __syncthreads();

    const int r = blockIdx.x * 256 + tid;
    float x1[C0];
    layer0_dedup(xyz, P, newxyz, idxf, W0, b0, r, x1);

#pragma unroll
    for (int oc = 0; oc < 16; ++oc)
        stats4q(x1[4*oc+0], x1[4*oc+1], x1[4*oc+2], x1[4*oc+3], &sacc[slot][8*oc], wr);

    __syncthreads();
    for (int j = tid; j < 2 * C0; j += 256) {
        float s = 0.f;
#pragma unroll
        for (int q = 0; q < 16; ++q) s += sacc[q][j];
        atomicAdd(&gstats[j], s);
    }
}

// ---------------------------------------------------------------------------
// Pass 1 + store pre-BN y1 as bf16 (Y-tier). 3 waves/EU, quad-slot stats.
// ---------------------------------------------------------------------------
__global__ __launch_bounds__(256, 3) void pass1Y_kernel(
    const float* __restrict__ xyz, const float* __restrict__ P,
    const float* __restrict__ newxyz, const float* __restrict__ idxf,
    const float* __restrict__ W0, const float* __restrict__ b0,
    const float* __restrict__ W1, const float* __restrict__ b1,
    const float* __restrict__ ss0,
    float* __restrict__ gstats, unsigned short* __restrict__ y1b)
{
    __shared__ float sacc[16][2 * C0];
    const int tid  = threadIdx.x;
    const int lane = tid & 63;
    const int wv   = tid >> 6;
    const int slot = wv * 4 + (lane >> 4);
    const bool wr  = (lane & 15) == 15;

    for (int j = tid; j < 16 * 2 * C0; j += 256) (&sacc[0][0])[j] = 0.f;
    __syncthreads();

    const int r = blockIdx.x * 256 + tid;
    float x1[C0];
    layer0_dedup(xyz, P, newxyz, idxf, W0, b0, r, x1);
#pragma unroll
    for (int o = 0; o < C0; ++o)
        x1[o] = fmaxf(0.f, fmaf(x1[o], ss0[o], ss0[64 + o]));

    float y1[C1];
#pragma unroll
    for (int o = 0; o < C1; o += 4) {
        const float4 bv = uld4(b1 + o);
        y1[o] = bv.x; y1[o+1] = bv.y; y1[o+2] = bv.z; y1[o+3] = bv.w;
    }
#pragma unroll 2
    for (int k = 0; k < C0; ++k) {
        const float xk = x1[k];
#pragma unroll
        for (int oc = 0; oc < 16; ++oc) {
            const float4 w4 = uld4(W1 + k * 64 + 4 * oc);
            y1[4*oc+0] = fmaf(xk, w4.x, y1[4*oc+0]);
            y1[4*oc+1] = fmaf(xk, w4.y, y1[4*oc+1]);
            y1[4*oc+2] = fmaf(xk, w4.z, y1[4*oc+2]);
            y1[4*oc+3] = fmaf(xk, w4.w, y1[4*oc+3]);
        }
    }

#pragma unroll
    for (int oc = 0; oc < 16; ++oc)
        stats4q(y1[4*oc+0], y1[4*oc+1], y1[4*oc+2], y1[4*oc+3], &sacc[slot][8*oc], wr);

    uint4* yo = (uint4*)(y1b + (size_t)r * 64);
#pragma unroll
    for (int gq = 0; gq < 8; ++gq) {
        union { unsigned short u[8]; uint4 v; } pk;
#pragma unroll
        for (int e = 0; e < 8; ++e) pk.u[e] = f2bf(y1[8*gq+e]);
        yo[gq] = pk.v;
    }

    __syncthreads();
    for (int j = tid; j < 2 * C0; j += 256) {
        float s = 0.f;
#pragma unroll
        for (int q = 0; q < 16; ++q) s += sacc[q][j];
        atomicAdd(&gstats[j], s);
    }
}

// ---------------------------------------------------------------------------
// Y-tier phase 2: o-tiled (2x64 regs) for occupancy, quad-slot sums,
// per-tile per-group min/max.
// ---------------------------------------------------------------------------
__global__ __launch_bounds__(256, 3) void p2Y_kernel(
    const unsigned short* __restrict__ y1b,
    const float* __restrict__ W2, const float* __restrict__ b2,
    const float* __restrict__ ss1,
    float* __restrict__ gstats, float* __restrict__ mnmx)
{
    __shared__ float sacc[16][2 * C2];
    const int tid  = threadIdx.x;
    const int lane = tid & 63;
    const int wv   = tid >> 6;
    const int slot = wv * 4 + (lane >> 4);
    const bool wr  = (lane & 15) == 15;

    for (int j = tid; j < 16 * 2 * C2; j += 256) (&sacc[0][0])[j] = 0.f;
    __syncthreads();

    const int r = blockIdx.x * 256 + tid;

    float y1[C1];
    {
        const uint4* yi = (const uint4*)(y1b + (size_t)r * 64);
#pragma unroll
        for (int gq = 0; gq < 8; ++gq) {
            union { uint4 v; unsigned short u[8]; } pk;
            pk.v = yi[gq];
#pragma unroll
            for (int e = 0; e < 8; ++e)
                y1[8*gq+e] = bf2f(pk.u[e]);
        }
    }
#pragma unroll
    for (int o = 0; o < C1; ++o)
        y1[o] = fmaxf(0.f, fmaf(y1[o], ss1[o], ss1[64 + o]));

    const int gbase = blockIdx.x * 8 + 2 * wv;
    float* mb = mnmx + ((size_t)gbase + (lane >> 5)) * 256;

#pragma unroll 1
    for (int to = 0; to < 2; ++to) {
        const int ob = to * 64;
        float a2[64];
#pragma unroll
        for (int o = 0; o < 64; o += 4) {
            const float4 bv = uld4(b2 + ob + o);
            a2[o] = bv.x; a2[o+1] = bv.y; a2[o+2] = bv.z; a2[o+3] = bv.w;
        }
#pragma unroll 2
        for (int k = 0; k < C1; ++k) {
            const float xk = y1[k];
#pragma unroll
            for (int o = 0; o < 64; o += 4) {
                const float4 w4 = uld4(W2 + k * C2 + ob + o);
                a2[o+0] = fmaf(xk, w4.x, a2[o+0]);
                a2[o+1] = fmaf(xk, w4.y, a2[o+1]);
                a2[o+2] = fmaf(xk, w4.z, a2[o+2]);
                a2[o+3] = fmaf(xk, w4.w, a2[o+3]);
            }
        }

#pragma unroll
        for (int o = 0; o < 64; ++o) {
            const float v = a2[o];
            const float s  = dpp_psum16(v);
            const float q  = dpp_psum16(v * v);
            const float mn = dpp_min32(v);
            const float mx = dpp_max32(v);
            if (wr) { sacc[slot][2*(ob+o)] += s; sacc[slot][2*(ob+o)+1] += q; }
            if (lane == 31 || lane == 63) { mb[ob+o] = mn; mb[128 + ob + o] = mx; }
        }
    }

    __syncthreads();
    for (int j = tid; j < 2 * C2; j += 256) {
        float s = 0.f;
#pragma unroll
        for (int q = 0; q < 16; ++q) s += sacc[q][j];
        atomicAdd(&gstats[j], s);
    }
}

// ---------------------------------------------------------------------------
// Finalize: out[g,o] = relu(sc>=0 ? sc*max+sh : sc*min+sh).
// ---------------------------------------------------------------------------
__global__ __launch_bounds__(256) void fin_kernel(const float* __restrict__ mnmx,
                                                  const float* __restrict__ ss2,
                                                  float* __restrict__ out_np)
{
    const int t = blockIdx.x * 256 + threadIdx.x;
    const int g = t >> 7;
    const int o = t & 127;
    const float sc = ss2[o], sh = ss2[C2 + o];
    const float y  = (sc >= 0.f) ? mnmx[(size_t)g * 256 + 128 + o]
                                 : mnmx[(size_t)g * 256 + o];
    out_np[t] = fmaxf(0.f, fmaf(y, sc, sh));
}

// ---------------------------------------------------------------------------
// Fallback P-path pass (MM / P tiers).
// ---------------------------------------------------------------------------
template<int PHASE>
__global__ __launch_bounds__(256, 2) void passP_kernel(
    const float* __restrict__ xyz, const float* __restrict__ P,
    const float* __restrict__ newxyz, const float* __restrict__ idxf,
    const float* __restrict__ W0, const float* __restrict__ b0,
    const float* __restrict__ W1, const float* __restrict__ b1,
    const float* __restrict__ W2, const float* __restrict__ b2,
    const float* __restrict__ ss0, const float* __restrict__ ss1,
    const float* __restrict__ ss2,
    float* __restrict__ gstats, float* __restrict__ out_np)
{
    constexpr int CS = (PHASE == 2) ? C2 : C0;
    __shared__ float sacc[4][2 * CS];

    const int tid  = threadIdx.x;
    const int lane = tid & 63;
    const int wv   = tid >> 6;

    if constexpr (PHASE <= 2) {
        for (int j = tid; j < 8 * CS; j += 256) (&sacc[0][0])[j] = 0.f;
        __syncthreads();
    }

    const int r = blockIdx.x * 256 + tid;
    float x1[C0];
    layer0_dedup(xyz, P, newxyz, idxf, W0, b0, r, x1);

    if constexpr (PHASE == 0) {
#pragma unroll
        for (int oc = 0; oc < 16; ++oc)
            stats4(x1[4*oc+0], x1[4*oc+1], x1[4*oc+2], x1[4*oc+3], &sacc[wv][8*oc], lane);
    } else {
#pragma unroll
        for (int o = 0; o < C0; ++o)
            x1[o] = fmaxf(0.f, fmaf(x1[o], ss0[o], ss0[64 + o]));

        float y1[C1];
#pragma unroll
        for (int o = 0; o < C1; o += 4) {
            const float4 bv = uld4(b1 + o);
            y1[o] = bv.x; y1[o+1] = bv.y; y1[o+2] = bv.z; y1[o+3] = bv.w;
        }
#pragma unroll 2
        for (int k = 0; k < C0; ++k) {
            const float xk = x1[k];
#pragma unroll
            for (int oc = 0; oc < 16; ++oc) {
                const float4 w4 = uld4(W1 + k * 64 + 4 * oc);
                y1[4*oc+0] = fmaf(xk, w4.x, y1[4*oc+0]);
                y1[4*oc+1] = fmaf(xk, w4.y, y1[4*oc+1]);
                y1[4*oc+2] = fmaf(xk, w4.z, y1[4*oc+2]);
                y1[4*oc+3] = fmaf(xk, w4.w, y1[4*oc+3]);
            }
        }

        if constexpr (PHASE == 1) {
#pragma unroll
            for (int oc = 0; oc < 16; ++oc)
                stats4(y1[4*oc+0], y1[4*oc+1], y1[4*oc+2], y1[4*oc+3], &sacc[wv][8*oc], lane);
        } else {
#pragma unroll
            for (int o = 0; o < C1; ++o)
                y1[o] = fmaxf(0.f, fmaf(y1[o], ss1[o], ss1[64 + o]));

            float a2[C2];
#pragma unroll
            for (int o = 0; o < C2; o += 4) {
                const float4 bv = uld4(b2 + o);
                a2[o] = bv.x; a2[o+1] = bv.y; a2[o+2] = bv.z; a2[o+3] = bv.w;
            }
#pragma unroll 2
            for (int k = 0; k < C1; ++k) {
                const float xk = y1[k];
#pragma unroll
                for (int o = 0; o < C2; o += 4) {
                    const float4 w4 = uld4(W2 + k * C2 + o);
                    a2[o+0] = fmaf(xk, w4.x, a2[o+0]);
                    a2[o+1] = fmaf(xk, w4.y, a2[o+1]);
                    a2[o+2] = fmaf(xk, w4.z, a2[o+2]);
                    a2[o+3] = fmaf(xk, w4.w, a2[o+3]);
                }
            }

            if constexpr (PHASE == 2) {
#pragma unroll
                for (int o = 0; o < C2; ++o) {
                    const float s = dpp_sum64(a2[o]);
                    const float q = dpp_sum64(a2[o] * a2[o]);
                    if (lane == 63) { sacc[wv][2*o] += s; sacc[wv][2*o+1] += q; }
                }
            } else {
                const int g = r >> 5;
#pragma unroll
                for (int o = 0; o < C2; ++o) {
                    float v = fmaxf(0.f, fmaf(a2[o], ss2[o], ss2[C2 + o]));
                    v = dpp_max32(v);
                    if (lane == 31 || lane == 63) out_np[(size_t)g * C2 + o] = v;
                }
            }
        }
    }

    if constexpr (PHASE <= 2) {
        __syncthreads();
        for (int j = tid; j < 2 * CS; j += 256)
            atomicAdd(&gstats[j], sacc[0][j] + sacc[1][j] + sacc[2][j] + sacc[3][j]);
    }
}

// ---------------------------------------------------------------------------
// MM-tier phase 2 (recompute variant) — fallback.
// ---------------------------------------------------------------------------
__global__ __launch_bounds__(256, 2) void passP2mm_kernel(
    const float* __restrict__ xyz, const float* __restrict__ P,
    const float* __restrict__ newxyz, const float* __restrict__ idxf,
    const float* __restrict__ W0, const float* __restrict__ b0,
    const float* __restrict__ W1, const float* __restrict__ b1,
    const float* __restrict__ W2, const float* __restrict__ b2,
    const float* __restrict__ ss0, const float* __restrict__ ss1,
    float* __restrict__ gstats, float* __restrict__ mnmx)
{
    __shared__ float sacc[4][2 * C2];

    const int tid  = threadIdx.x;
    const int lane = tid & 63;
    const int wv   = tid >> 6;

    for (int j = tid; j < 8 * C2; j += 256) (&sacc[0][0])[j] = 0.f;
    __syncthreads();

    const int r = blockIdx.x * 256 + tid;
    float x1[C0];
    layer0_dedup(xyz, P, newxyz, idxf, W0, b0, r, x1);
#pragma unroll
    for (int o = 0; o < C0; ++o)
        x1[o] = fmaxf(0.f, fmaf(x1[o], ss0[o], ss0[64 + o]));

    float y1[C1];
#pragma unroll
    for (int o = 0; o < C1; o += 4) {
        const float4 bv = uld4(b1 + o);
        y1[o] = bv.x; y1[o+1] = bv.y; y1[o+2] = bv.z; y1[o+3] = bv.w;
    }
#pragma unroll 2
    for (int k = 0; k < C0; ++k) {
        const float xk = x1[k];
#pragma unroll
        for (int oc = 0; oc < 16; ++oc) {
            const float4 w4 = uld4(W1 + k * 64 + 4 * oc);
            y1[4*oc+0] = fmaf(xk, w4.x, y1[4*oc+0]);
            y1[4*oc+1] = fmaf(xk, w4.y, y1[4*oc+1]);
            y1[4*oc+2] = fmaf(xk, w4.z, y1[4*oc+2]);
            y1[4*oc+3] = fmaf(xk, w4.w, y1[4*oc+3]);
        }
    }
#pragma unroll
    for (int o = 0; o < C1; ++o)
        y1[o] = fmaxf(0.f, fmaf(y1[o], ss1[o], ss1[64 + o]));

    float a2[C2];
#pragma unroll
    for (int o = 0; o < C2; o += 4) {
        const float4 bv = uld4(b2 + o);
        a2[o] = bv.x; a2[o+1] = bv.y; a2[o+2] = bv.z; a2[o+3] = bv.w;
    }
#pragma unroll 2
    for (int k = 0; k < C1; ++k) {
        const float xk = y1[k];
#pragma unroll
        for (int o = 0; o < C2; o += 4) {
            const float4 w4 = uld4(W2 + k * C2 + o);
            a2[o+0] = fmaf(xk, w4.x, a2[o+0]);
            a2[o+1] = fmaf(xk, w4.y, a2[o+1]);
            a2[o+2] = fmaf(xk, w4.z, a2[o+2]);
            a2[o+3] = fmaf(xk, w4.w, a2[o+3]);
        }
    }

    const int gbase = blockIdx.x * 8 + 2 * wv;
    float* mb = mnmx + ((size_t)gbase + (lane >> 5)) * 256;
#pragma unroll
    for (int o = 0; o < C2; ++o) {
        const float v = a2[o];
        const float s = dpp_sum64(v);
        const float q = dpp_sum64(v * v);
        const float mn = dpp_min32(v);
        const float mx = dpp_max32(v);
        if (lane == 63) { sacc[wv][2*o] += s; sacc[wv][2*o+1] += q; }
        if (lane == 31 || lane == 63) { mb[o] = mn; mb[128 + o] = mx; }
    }

    __syncthreads();
    for (int j = tid; j < 2 * C2; j += 256)
        atomicAdd(&gstats[j], sacc[0][j] + sacc[1][j] + sacc[2][j] + sacc[3][j]);
}

// ---------------------------------------------------------------------------
// Lowest-tier fallback (round-2 proven, ws < 16 MB).
// ---------------------------------------------------------------------------
template<int PHASE>
__global__ __launch_bounds__(128) void pass_kernel(
    const float* __restrict__ xyz, const float* __restrict__ points,
    const float* __restrict__ newxyz, const float* __restrict__ idxf,
    const float* __restrict__ W0, const float* __restrict__ b0,
    const float* __restrict__ W1, const float* __restrict__ b1,
    const float* __restrict__ W2, const float* __restrict__ b2,
    const float* __restrict__ ss0, const float* __restrict__ ss1,
    const float* __restrict__ ss2,
    float* __restrict__ gstats, float* __restrict__ out_np)
{
    constexpr int CS = (PHASE == 2) ? C2 : C0;
    __shared__ float xld[(PHASE >= 1) ? (64 * 128) : 1];
    __shared__ float sacc[2][2 * CS];

    const int tid  = threadIdx.x;
    const int lane = tid & 63;
    const int wv   = tid >> 6;

    if constexpr (PHASE <= 2) {
        for (int j = tid; j < 2 * 2 * CS; j += 128) (&sacc[0][0])[j] = 0.f;
        __syncthreads();
    }

    const int r  = blockIdx.x * 128 + tid;
    const int i  = (int)idxf[r];
    const int bb = r >> 15;
    const int pp = (r >> 5) & 1023;

    float x[CIN0];
    {
        const float* pz = xyz + ((size_t)bb * NPTS + i) * 3;
        const float* nz = newxyz + ((size_t)bb * NPOINTS + pp) * 3;
        x[0] = pz[0] - nz[0];
        x[1] = pz[1] - nz[1];
        x[2] = pz[2] - nz[2];
        const float4* p4 = (const float4*)(points + ((size_t)bb * NPTS + i) * 64);
#pragma unroll
        for (int j = 0; j < 16; ++j) {
            const float4 v = p4[j];
            x[3+4*j+0] = v.x; x[3+4*j+1] = v.y; x[3+4*j+2] = v.z; x[3+4*j+3] = v.w;
        }
    }

#pragma unroll 1
    for (int oc = 0; oc < 16; ++oc) {
        const float4 bv = uld4(b0 + 4*oc);
        float a0 = bv.x, a1 = bv.y, a2 = bv.z, a3 = bv.w;
#pragma unroll
        for (int k = 0; k < CIN0; ++k) {
            const float4 w4 = uld4(W0 + k*64 + 4*oc);
            a0 = fmaf(x[k], w4.x, a0); a1 = fmaf(x[k], w4.y, a1);
            a2 = fmaf(x[k], w4.z, a2); a3 = fmaf(x[k], w4.w, a3);
        }
        if constexpr (PHASE == 0) {
            stats4(a0, a1, a2, a3, &sacc[wv][8*oc], lane);
        } else {
            xld[(4*oc+0)*128 + tid] = fmaxf(0.f, fmaf(a0, ss0[4*oc+0], ss0[64+4*oc+0]));
            xld[(4*oc+1)*128 + tid] = fmaxf(0.f, fmaf(a1, ss0[4*oc+1], ss0[64+4*oc+1]));
            xld[(4*oc+2)*128 + tid] = fmaxf(0.f, fmaf(a2, ss0[4*oc+2], ss0[64+4*oc+2]));
            xld[(4*oc+3)*128 + tid] = fmaxf(0.f, fmaf(a3, ss0[4*oc+3], ss0[64+4*oc+3]));
        }
    }

    if constexpr (PHASE == 1) {
#pragma unroll 1
        for (int oc = 0; oc < 16; ++oc) {
            const float4 bv = uld4(b1 + 4*oc);
            float a0 = bv.x, a1 = bv.y, a2 = bv.z, a3 = bv.w;
#pragma unroll
            for (int k = 0; k < 64; ++k) {
                const float xk = xld[k*128 + tid];
                const float4 w4 = uld4(W1 + k*64 + 4*oc);
                a0 = fmaf(xk, w4.x, a0); a1 = fmaf(xk, w4.y, a1);
                a2 = fmaf(xk, w4.z, a2); a3 = fmaf(xk, w4.w, a3);
            }
            stats4(a0, a1, a2, a3, &sacc[wv][8*oc], lane);
        }
    }

    if constexpr (PHASE >= 2) {
        float acc2[C2];
#pragma unroll
        for (int o = 0; o < C2; o += 4) {
            const float4 bv = uld4(b2 + o);
            acc2[o] = bv.x; acc2[o+1] = bv.y; acc2[o+2] = bv.z; acc2[o+3] = bv.w;
        }
#pragma unroll 1
        for (int oc = 0; oc < 16; ++oc) {
            const float4 bv = uld4(b1 + 4*oc);
            float a0 = bv.x, a1 = bv.y, a2 = bv.z, a3 = bv.w;
#pragma unroll
            for (int k = 0; k < 64; ++k) {
                const float xk = xld[k*128 + tid];
                const float4 w4 = uld4(W1 + k*64 + 4*oc);
                a0 = fmaf(xk, w4.x, a0); a1 = fmaf(xk, w4.y, a1);
                a2 = fmaf(xk, w4.z, a2); a3 = fmaf(xk, w4.w, a3);
            }
            const float xc0 = fmaxf(0.f, fmaf(a0, ss1[4*oc+0], ss1[64+4*oc+0]));
            const float xc1 = fmaxf(0.f, fmaf(a1, ss1[4*oc+1], ss1[64+4*oc+1]));
            const float xc2 = fmaxf(0.f, fmaf(a2, ss1[4*oc+2], ss1[64+4*oc+2]));
            const float xc3 = fmaxf(0.f, fmaf(a3, ss1[4*oc+3], ss1[64+4*oc+3]));
#pragma unroll
            for (int o = 0; o < C2; o += 4) {
                const float4 wA = uld4(W2 + (4*oc+0)*C2 + o);
                const float4 wB = uld4(W2 + (4*oc+1)*C2 + o);
                const float4 wC = uld4(W2 + (4*oc+2)*C2 + o);
                const float4 wD = uld4(W2 + (4*oc+3)*C2 + o);
                acc2[o+0] = fmaf(xc0, wA.x, fmaf(xc1, wB.x, fmaf(xc2, wC.x, fmaf(xc3, wD.x, acc2[o+0]))));
                acc2[o+1] = fmaf(xc0, wA.y, fmaf(xc1, wB.y, fmaf(xc2, wC.y, fmaf(xc3, wD.y, acc2[o+1]))));
                acc2[o+2] = fmaf(xc0, wA.z, fmaf(xc1, wB.z, fmaf(xc2, wC.z, fmaf(xc3, wD.z, acc2[o+2]))));
                acc2[o+3] = fmaf(xc0, wA.w, fmaf(xc1, wB.w, fmaf(xc2, wC.w, fmaf(xc3, wD.w, acc2[o+3]))));
            }
        }

        if constexpr (PHASE == 2) {
#pragma unroll
            for (int o = 0; o < C2; ++o) {
                const float s = dpp_sum64(acc2[o]);
                const float q = dpp_sum64(acc2[o] * acc2[o]);
                if (lane == 63) { sacc[wv][2*o] += s; sacc[wv][2*o+1] += q; }
            }
        } else {
            const int g = r >> 5;
#pragma unroll
            for (int o = 0; o < C2; ++o) {
                float v = fmaxf(0.f, fmaf(acc2[o], ss2[o], ss2[C2+o]));
                v = dpp_max32(v);
                if (lane == 31 || lane == 63) out_np[(size_t)g * C2 + o] = v;
            }
        }
    }

    if constexpr (PHASE <= 2) {
        __syncthreads();
        for (int j = tid; j < 2 * CS; j += 128)
            atomicAdd(&gstats[j], sacc[0][j] + sacc[1][j]);
    }
}

// ---------------------------------------------------------------------------
// BN scale/shift from raw sums.
// ---------------------------------------------------------------------------
template<int C>
__global__ void ss_kernel(const float* __restrict__ gs, const float* __restrict__ g,
                          const float* __restrict__ be, float* __restrict__ ss)
{
    const int o = threadIdx.x;
    const float inv  = 1.0f / (float)MROWS;
    const float mean = gs[2*o] * inv;
    const float var  = fmaxf(0.f, gs[2*o+1] * inv - mean * mean);
    const float sc   = g[o] / sqrtf(var + BN_EPS);
    ss[o]     = sc;
    ss[C + o] = fmaf(-mean, sc, be[o]);
}

extern "C" void kernel_launch(void* const* d_in, const int* in_sizes, int n_in,
                              void* d_out, int out_size, void* d_ws, size_t ws_size,
                              hipStream_t stream)
{
    (void)in_sizes; (void)n_in; (void)out_size;
    const float* xyz    = (const float*)d_in[0];
    const float* points = (const float*)d_in[1];
    const float* W0  = (const float*)d_in[2];
    const float* b0  = (const float*)d_in[3];
    const float* g0  = (const float*)d_in[4];
    const float* be0 = (const float*)d_in[5];
    const float* W1  = (const float*)d_in[6];
    const float* b1  = (const float*)d_in[7];
    const float* g1  = (const float*)d_in[8];
    const float* be1 = (const float*)d_in[9];
    const float* W2  = (const float*)d_in[10];
    const float* b2  = (const float*)d_in[11];
    const float* g2  = (const float*)d_in[12];
    const float* be2 = (const float*)d_in[13];

    float* out = (float*)d_out;
    float* out_newxyz = out;                                    // 16*1024*3
    float* out_newpts = out + (size_t)NB * NPOINTS * 3;         // 16*1024*128
    float* out_idx    = out_newpts + (size_t)NB * NPOINTS * C2; // 16*1024*32 (float idx)

    float* wsf = (float*)d_ws;
    float* gs0 = wsf + 0;    // 128
    float* gs1 = wsf + 128;  // 128
    float* gs2 = wsf + 256;  // 256
    float* ss0 = wsf + 512;  // 128
    float* ss1 = wsf + 640;  // 128
    float* ss2 = wsf + 768;  // 256
    const size_t PBYTES  = (size_t)NB * NPTS * C0 * 4;            // 16 MB
    const size_t MMBYTES = (size_t)NB * NPOINTS * 2 * C2 * 4;     // 16 MB
    const size_t YBYTES  = MROWS * C1 * 2;                        // 64 MB (bf16)
    float* P    = (float*)((char*)d_ws + 65536);
    float* mnmx = (float*)((char*)d_ws + 65536 + PBYTES);
    unsigned short* y1b = (unsigned short*)((char*)d_ws + 65536 + PBYTES + MMBYTES);

    const bool haveP  = ws_size >= (65536 + PBYTES);
    const bool haveMM = ws_size >= (65536 + PBYTES + MMBYTES);
    const bool haveY  = ws_size >= (65536 + PBYTES + MMBYTES + YBYTES);

    fps_kernel<<<NB + 1, 512, 0, stream>>>(xyz, out_newxyz, wsf);
    ball_kernel<<<(NB * NPOINTS) / 4, 256, 0, stream>>>(xyz, out_newxyz, out_idx);

    if (haveP) {
        const int grid = (int)(MROWS / 256);  // 2048
        preP_kernel<<<NB * NPTS / 256, 256, 0, stream>>>(points, W0, P);
        if (haveY) {
            pass0_kernel<<<grid, 256, 0, stream>>>(xyz, P, out_newxyz, out_idx,
                                                   W0, b0, gs0);
            ss_kernel<C0><<<1, C0, 0, stream>>>(gs0, g0, be0, ss0);
            pass1Y_kernel<<<grid, 256, 0, stream>>>(xyz, P, out_newxyz, out_idx,
                                                    W0, b0, W1, b1, ss0, gs1, y1b);
            ss_kernel<C1><<<1, C1, 0, stream>>>(gs1, g1, be1, ss1);
            p2Y_kernel<<<grid, 256, 0, stream>>>(y1b, W2, b2, ss1, gs2, mnmx);
            ss_kernel<C2><<<1, C2, 0, stream>>>(gs2, g2, be2, ss2);
            fin_kernel<<<NB * NPOINTS * C2 / 256, 256, 0, stream>>>(mnmx, ss2, out_newpts);
        } else if (haveMM) {
            passP_kernel<0><<<grid, 256, 0, stream>>>(xyz, P, out_newxyz, out_idx,
                                                      W0, b0, W1, b1, W2, b2,
                                                      ss0, ss1, ss2, gs0, nullptr);
            ss_kernel<C0><<<1, C0, 0, stream>>>(gs0, g0, be0, ss0);
            passP_kernel<1><<<grid, 256, 0, stream>>>(xyz, P, out_newxyz, out_idx,
                                                      W0, b0, W1, b1, W2, b2,
                                                      ss0, ss1, ss2, gs1, nullptr);
            ss_kernel<C1><<<1, C1, 0, stream>>>(gs1, g1, be1, ss1);
            passP2mm_kernel<<<grid, 256, 0, stream>>>(xyz, P, out_newxyz, out_idx,
                                                      W0, b0, W1, b1, W2, b2,
                                                      ss0, ss1, gs2, mnmx);
            ss_kernel<C2><<<1, C2, 0, stream>>>(gs2, g2, be2, ss2);
            fin_kernel<<<NB * NPOINTS * C2 / 256, 256, 0, stream>>>(mnmx, ss2, out_newpts);
        } else {
            passP_kernel<0><<<grid, 256, 0, stream>>>(xyz, P, out_newxyz, out_idx,
                                                      W0, b0, W1, b1, W2, b2,
                                                      ss0, ss1, ss2, gs0, nullptr);
            ss_kernel<C0><<<1, C0, 0, stream>>>(gs0, g0, be0, ss0);
            passP_kernel<1><<<grid, 256, 0, stream>>>(xyz, P, out_newxyz, out_idx,
                                                      W0, b0, W1, b1, W2, b2,
                                                      ss0, ss1, ss2, gs1, nullptr);
            ss_kernel<C1><<<1, C1, 0, stream>>>(gs1, g1, be1, ss1);
            passP_kernel<2><<<grid, 256, 0, stream>>>(xyz, P, out_newxyz, out_idx,
                                                      W0, b0, W1, b1, W2, b2,
                                                      ss0, ss1, ss2, gs2, nullptr);
            ss_kernel<C2><<<1, C2, 0, stream>>>(gs2, g2, be2, ss2);
            passP_kernel<3><<<grid, 256, 0, stream>>>(xyz, P, out_newxyz, out_idx,
                                                      W0, b0, W1, b1, W2, b2,
                                                      ss0, ss1, ss2, nullptr, out_newpts);
        }
    } else {
        const int grid = (int)(MROWS / 128);  // 4096
        pass_kernel<0><<<grid, 128, 0, stream>>>(xyz, points, out_newxyz, out_idx,
                                                 W0, b0, W1, b1, W2, b2,
                                                 ss0, ss1, ss2, gs0, nullptr);
        ss_kernel<C0><<<1, C0, 0, stream>>>(gs0, g0, be0, ss0);
        pass_kernel<1><<<grid, 128, 0, stream>>>(xyz, points, out_newxyz, out_idx,
                                                 W0, b0, W1, b1, W2, b2,
                                                 ss0, ss1, ss2, gs1, nullptr);
        ss_kernel<C1><<<1, C1, 0, stream>>>(gs1, g1, be1, ss1);
        pass_kernel<2><<<grid, 128, 0, stream>>>(xyz, points, out_newxyz, out_idx,
                                                 W0, b0, W1, b1, W2, b2,
                                                 ss0, ss1, ss2, gs2, nullptr);
        ss_kernel<C2><<<1, C2, 0, stream>>>(gs2, g2, be2, ss2);
        pass_kernel<3><<<grid, 128, 0, stream>>>(xyz, points, out_newxyz, out_idx,
                                                 W0, b0, W1, b1, W2, b2,
                                                 ss0, ss1, ss2, nullptr, out_newpts);
    }
}